// Round 8
// baseline (562.311 us; speedup 1.0000x reference)
//
#include <hip/hip_runtime.h>
#include <hip/hip_bf16.h>
#include <math.h>

// Problem constants
#define LL 512
#define BB 8
#define DD 768
#define HH 12
#define DHH 64
#define PP 128

typedef unsigned char u8;
typedef unsigned short u16;
typedef unsigned int u32;
typedef __attribute__((ext_vector_type(8))) short bf16x8;
typedef __attribute__((ext_vector_type(4))) float f32x4;

__device__ __forceinline__ u16 f2bf(float f) {
  u32 u = __float_as_uint(f);
  u32 r = (u + 0x7fffu + ((u >> 16) & 1u)) >> 16;
  return (u16)r;
}
__device__ __forceinline__ float bf2f(u16 u) {
  return __uint_as_float((u32)u << 16);
}

#define GLDS(g, l)                                                             \
  __builtin_amdgcn_global_load_lds(                                            \
      (const __attribute__((address_space(1))) void*)(g),                      \
      (__attribute__((address_space(3))) void*)(l), 16, 0, 0)

// ---------------------------------------------------------------------------
__device__ __forceinline__ void block_reduce2(float& a, float& b, float* sbuf) {
#pragma unroll
  for (int off = 32; off > 0; off >>= 1) {
    a += __shfl_down(a, off, 64);
    b += __shfl_down(b, off, 64);
  }
  int wid = threadIdx.x >> 6, lane = threadIdx.x & 63;
  __syncthreads();
  if (lane == 0) { sbuf[wid] = a; sbuf[4 + wid] = b; }
  __syncthreads();
  a = sbuf[0] + sbuf[1] + sbuf[2] + sbuf[3];
  b = sbuf[4] + sbuf[5] + sbuf[6] + sbuf[7];
}

// LayerNorm over D=768, one block per row, bf16 output
__global__ __launch_bounds__(256) void ln_bf16(const float* __restrict__ x,
                                               const float* __restrict__ w,
                                               const float* __restrict__ bb,
                                               u16* __restrict__ out) {
  __shared__ float sbuf[8];
  size_t row = blockIdx.x;
  const float* xr = x + row * DD;
  int t = threadIdx.x;
  float v0 = xr[t], v1 = xr[t + 256], v2 = xr[t + 512];
  float s = v0 + v1 + v2;
  float ss = v0 * v0 + v1 * v1 + v2 * v2;
  block_reduce2(s, ss, sbuf);
  float mu = s * (1.0f / DD);
  float var = ss * (1.0f / DD) - mu * mu;
  float r = rsqrtf(var + 1e-5f);
  u16* orow = out + row * DD;
  orow[t]       = f2bf((v0 - mu) * r * w[t]       + bb[t]);
  orow[t + 256] = f2bf((v1 - mu) * r * w[t + 256] + bb[t + 256]);
  orow[t + 512] = f2bf((v2 - mu) * r * w[t + 512] + bb[t + 512]);
}

// fp32 -> bf16, 4 elements/thread
__global__ __launch_bounds__(256) void f2b_kernel(const float* __restrict__ in,
                                                  u16* __restrict__ out) {
  int idx = blockIdx.x * 256 + threadIdx.x;
  float4 v = *(const float4*)(in + (size_t)idx * 4);
  u32 lo = (u32)f2bf(v.x) | ((u32)f2bf(v.y) << 16);
  u32 hi = (u32)f2bf(v.z) | ((u32)f2bf(v.w) << 16);
  *(uint2*)(out + (size_t)idx * 4) = make_uint2(lo, hi);
}

// bdist [L,L,B] int32 -> bdistT [B,L,L] u8 (values < 128)
__global__ __launch_bounds__(256) void bdist_t(const int* __restrict__ bd,
                                               u8* __restrict__ out) {
  int t = blockIdx.x * 256 + threadIdx.x;  // 2,097,152 items, read-coalesced
  int b = t & 7, jj = (t >> 3) & 511, ii = t >> 12;
  out[((size_t)b << 18) + ((size_t)ii << 9) + jj] = (u8)bd[t];
}

// ---------------------------------------------------------------------------
// bf16 MFMA GEMM (round-3-proven): C = act(A * B^T + bias) [+ residual].
// 128x128 tile, BK=32, 4 waves 2x2. Requires 128 | grid-covered M,N; 32 | K.
template <int ACT, int OBF, int RES>
__global__ __launch_bounds__(256) void gemm_mfma(
    const u16* __restrict__ A, int lda, const u16* __restrict__ B, int ldb,
    void* __restrict__ Cv, int ldc, const float* __restrict__ bias,
    const float* __restrict__ residual, int K) {
  __shared__ __align__(16) u16 Asl[128 * 32];
  __shared__ __align__(16) u16 Bsl[128 * 32];
  int t = threadIdx.x;
  int m0 = blockIdx.y * 128, n0 = blockIdx.x * 128;
  int lane = t & 63, w = t >> 6;
  int wr = w >> 1, wc = w & 1;
  int lr = lane & 15, lg = lane >> 4;

  f32x4 acc[4][4] = {};

  const u16* Ag0 = A + (size_t)(m0 + (t >> 2)) * lda + (t & 3) * 8;
  const u16* Ag1 = A + (size_t)(m0 + 64 + (t >> 2)) * lda + (t & 3) * 8;
  const u16* Bg0 = B + (size_t)(n0 + (t >> 2)) * ldb + (t & 3) * 8;
  const u16* Bg1 = B + (size_t)(n0 + 64 + (t >> 2)) * ldb + (t & 3) * 8;
  u16* Ad0 = &Asl[t * 8];
  u16* Ad1 = &Asl[2048 + t * 8];
  u16* Bd0 = &Bsl[t * 8];
  u16* Bd1 = &Bsl[2048 + t * 8];

  for (int k0 = 0; k0 < K; k0 += 32) {
    GLDS(Ag0 + k0, Ad0);
    GLDS(Ag1 + k0, Ad1);
    GLDS(Bg0 + k0, Bd0);
    GLDS(Bg1 + k0, Bd1);
    __syncthreads();
    bf16x8 a[4], b[4];
#pragma unroll
    for (int i = 0; i < 4; i++)
      a[i] = *(const bf16x8*)&Asl[(wr * 64 + i * 16 + lr) * 32 + lg * 8];
#pragma unroll
    for (int j = 0; j < 4; j++)
      b[j] = *(const bf16x8*)&Bsl[(wc * 64 + j * 16 + lr) * 32 + lg * 8];
#pragma unroll
    for (int i = 0; i < 4; i++)
#pragma unroll
      for (int j = 0; j < 4; j++)
        asm volatile("v_mfma_f32_16x16x32_bf16 %0, %1, %2, %0"
                     : "+v"(acc[i][j])
                     : "v"(a[i]), "v"(b[j]));
    __syncthreads();
  }
  asm volatile("s_nop 7\n\ts_nop 7" ::);

  float* Cf = (float*)Cv;
  u16* Cb = (u16*)Cv;
#pragma unroll
  for (int i = 0; i < 4; i++) {
#pragma unroll
    for (int r = 0; r < 4; r++) {
      int row = m0 + wr * 64 + i * 16 + lg * 4 + r;
#pragma unroll
      for (int j = 0; j < 4; j++) {
        int col = n0 + wc * 64 + j * 16 + lr;
        float vv = acc[i][j][r];
        if (bias) vv += bias[col];
        if (ACT) vv = 0.5f * vv * (1.0f + erff(vv * 0.70710678118654752f));
        if (RES) vv += residual[(size_t)row * ldc + col];
        if (OBF) Cb[(size_t)row * ldc + col] = f2bf(vv);
        else     Cf[(size_t)row * ldc + col] = vv;
      }
    }
  }
}

// ---------------------------------------------------------------------------
// Generic fp32 GEMM (round-3-proven): C = A*B^T (+bias); OBF=1 -> bf16 store.
template <int OBF>
__global__ __launch_bounds__(256) void gemm_kernel(
    const float* __restrict__ A, int lda, long sAo, long sAi,
    const float* __restrict__ B, int ldb, long sBo, long sBi,
    void* __restrict__ Cv, int ldc, long sCo, long sCi,
    const float* __restrict__ bias,
    const float* __restrict__ residual,
    int K, int act) {
  int z = blockIdx.z;
  int zo = z / HH, zi = z - zo * HH;
  A += (size_t)zo * sAo + (size_t)zi * sAi;
  B += (size_t)zo * sBo + (size_t)zi * sBi;
  size_t coff = (size_t)zo * sCo + (size_t)zi * sCi;

  __shared__ float As[16][68];
  __shared__ float Bs[16][68];
  int tid = threadIdx.x;
  int tx = tid & 15, ty = tid >> 4;
  int m0 = blockIdx.y * 64, n0 = blockIdx.x * 64;
  float acc[4][4] = {};
  int r = tid >> 2, kq = (tid & 3) * 4;

  for (int k0 = 0; k0 < K; k0 += 16) {
    float4 av = *(const float4*)(A + (size_t)(m0 + r) * lda + (k0 + kq));
    float4 bv = *(const float4*)(B + (size_t)(n0 + r) * ldb + (k0 + kq));
    As[kq + 0][r] = av.x; As[kq + 1][r] = av.y; As[kq + 2][r] = av.z; As[kq + 3][r] = av.w;
    Bs[kq + 0][r] = bv.x; Bs[kq + 1][r] = bv.y; Bs[kq + 2][r] = bv.z; Bs[kq + 3][r] = bv.w;
    __syncthreads();
#pragma unroll
    for (int kk = 0; kk < 16; kk++) {
      float4 a4 = *(const float4*)&As[kk][ty * 4];
      float4 b4 = *(const float4*)&Bs[kk][tx * 4];
      float ar[4] = {a4.x, a4.y, a4.z, a4.w};
      float br[4] = {b4.x, b4.y, b4.z, b4.w};
#pragma unroll
      for (int i2 = 0; i2 < 4; i2++)
#pragma unroll
        for (int j2 = 0; j2 < 4; j2++)
          acc[i2][j2] += ar[i2] * br[j2];
    }
    __syncthreads();
  }

  float bs[4] = {0.f, 0.f, 0.f, 0.f};
  if (bias) {
    float4 b4 = *(const float4*)&bias[n0 + tx * 4];
    bs[0] = b4.x; bs[1] = b4.y; bs[2] = b4.z; bs[3] = b4.w;
  }
  float* Cf = (float*)Cv;
  u16* Cb = (u16*)Cv;
#pragma unroll
  for (int i2 = 0; i2 < 4; i2++) {
    size_t m = (size_t)(m0 + ty * 4 + i2);
    float vout[4];
#pragma unroll
    for (int j2 = 0; j2 < 4; j2++) vout[j2] = acc[i2][j2] + bs[j2];
    if (residual) {
      const float4 r4 = *(const float4*)&residual[coff + m * ldc + n0 + tx * 4];
      vout[0] += r4.x; vout[1] += r4.y; vout[2] += r4.z; vout[3] += r4.w;
    }
    if (OBF) {
      u32 lo = (u32)f2bf(vout[0]) | ((u32)f2bf(vout[1]) << 16);
      u32 hi = (u32)f2bf(vout[2]) | ((u32)f2bf(vout[3]) << 16);
      *(uint2*)&Cb[coff + m * ldc + n0 + tx * 4] = make_uint2(lo, hi);
    } else {
      *(float4*)&Cf[coff + m * ldc + n0 + tx * 4] =
          make_float4(vout[0], vout[1], vout[2], vout[3]);
    }
  }
}

// ---------------------------------------------------------------------------
// qkv fp32 [L*B, 3D] -> q,k fp32 [B,H,L,Dh] + vb bf16 [B,H,L,Dh]
__global__ __launch_bounds__(256) void split_qkv3(const float* __restrict__ qkv,
                                                  float* __restrict__ q,
                                                  float* __restrict__ k,
                                                  u16* __restrict__ vb) {
  int idx = blockIdx.x * 256 + threadIdx.x;  // over 3,145,728
  int d = idx & 63;
  int l = (idx >> 6) & 511;
  int bh = idx >> 15;
  int b = bh / HH, h = bh - b * HH;
  size_t src = ((size_t)(l * BB + b)) * (3 * DD) + h * 64 + d;
  q[idx] = qkv[src];
  k[idx] = qkv[src + DD];
  vb[idx] = f2bf(qkv[src + 2 * DD]);
}

// ---------------------------------------------------------------------------
// Fully fused attention tail: per (bh, 64-row i-tile) block.
// Phase 1 (round-7-proven): loop 8 j-tiles {fp32 QK^T + LDS bf16 kp/qp
//   gathers + scale + edge -> eout tile write + per-tile row stats -> LDS}.
// Combine stats in-block, then Phase 2 (round-2-proven PV): loop 8 j-tiles
//   {read back own eout tile (L2-hot) -> P, stage V, 4x4 FMA} -> O bf16
//   in [L,B,D] layout. LDS phase-aliased: P1 41.5KB / P2 35KB in one 41.5KB
//   region + 4.5KB stats = 46KB -> 3 blocks/CU; grid 768 = exactly 3*256.
__global__ __launch_bounds__(256) void attn_fused(
    const float* __restrict__ q, const float* __restrict__ k,
    const u16* __restrict__ kp, const u16* __restrict__ qp,
    const u8* __restrict__ bdT, const float* __restrict__ edge,
    const u16* __restrict__ vb_, float* __restrict__ eout,
    u16* __restrict__ olbd) {
  __shared__ __align__(16) char smem[41472];
  __shared__ float stat_m[8][64];
  __shared__ float stat_s[8][64];
  __shared__ float smax[64], srs[64];
  // Phase-1 aliases
  float (*As)[68]  = (float(*)[68])(smem);
  float (*Bs)[68]  = (float(*)[68])(smem + 4352);
  u16   (*kpl)[PP] = (u16(*)[PP])(smem + 8704);
  u16   (*qpl)[PP] = (u16(*)[PP])(smem + 25088);
  // Phase-2 aliases (same region, used strictly after phase 1)
  float (*Pt)[66]  = (float(*)[66])(smem);
  float (*Vt)[72]  = (float(*)[72])(smem + 16896);

  int bh = blockIdx.y, b = bh / HH, h = bh - b * HH;
  int i0 = blockIdx.x * 64;
  int tid = threadIdx.x;
  int tx = tid & 15, ty = tid >> 4;

  const float* A = q + (size_t)bh * (LL * DHH);
  const float* B = k + (size_t)bh * (LL * DHH);
  const u16* kpg = kp + (size_t)bh * (LL * PP);
  const u16* qpg = qp + (size_t)bh * (LL * PP);
  const u8* bd = bdT + (size_t)b * (LL * LL);
  const float* eb = edge + (size_t)bh * (LL * LL);
  float* ob = eout + (size_t)bh * (LL * LL);

  // Stage qpl (rows i0..i0+63) once.
  for (int c = tid; c < 1024; c += 256) {
    int row = c >> 4, ch = (c & 15) * 8;
    *(uint4*)&qpl[row][ch] = *(const uint4*)&qpg[(size_t)(i0 + row) * PP + ch];
  }

  int r = tid >> 2, kq = (tid & 3) * 4;

  // ---- Phase 1: scores + stats ----
  for (int jt = 0; jt < 8; jt++) {
    int j0 = jt * 64;
    __syncthreads();  // previous iteration's kpl reads done
    for (int c = tid; c < 1024; c += 256) {
      int row = c >> 4, ch = (c & 15) * 8;
      *(uint4*)&kpl[row][ch] = *(const uint4*)&kpg[(size_t)(j0 + row) * PP + ch];
    }
    float acc[4][4] = {};
    for (int k0 = 0; k0 < DHH; k0 += 16) {
      float4 av = *(const float4*)(A + (size_t)(i0 + r) * DHH + (k0 + kq));
      float4 bv = *(const float4*)(B + (size_t)(j0 + r) * DHH + (k0 + kq));
      As[kq + 0][r] = av.x; As[kq + 1][r] = av.y; As[kq + 2][r] = av.z; As[kq + 3][r] = av.w;
      Bs[kq + 0][r] = bv.x; Bs[kq + 1][r] = bv.y; Bs[kq + 2][r] = bv.z; Bs[kq + 3][r] = bv.w;
      __syncthreads();
#pragma unroll
      for (int kk = 0; kk < 16; kk++) {
        float4 a4 = *(const float4*)&As[kk][ty * 4];
        float4 b4 = *(const float4*)&Bs[kk][tx * 4];
        float ar[4] = {a4.x, a4.y, a4.z, a4.w};
        float br[4] = {b4.x, b4.y, b4.z, b4.w};
#pragma unroll
        for (int i2 = 0; i2 < 4; i2++)
#pragma unroll
          for (int j2 = 0; j2 < 4; j2++)
            acc[i2][j2] += ar[i2] * br[j2];
      }
      __syncthreads();
    }

#pragma unroll
    for (int i2 = 0; i2 < 4; i2++) {
      int row = i0 + ty * 4 + i2;
      int col0 = j0 + tx * 4;
      uchar4 p4 = *(const uchar4*)&bd[(size_t)row * LL + col0];
      float4 e4 = *(const float4*)&eb[(size_t)row * LL + col0];
      int pp[4] = {p4.x, p4.y, p4.z, p4.w};
      float ee[4] = {e4.x, e4.y, e4.z, e4.w};
      float sv[4];
#pragma unroll
      for (int j2 = 0; j2 < 4; j2++) {
        float gk = bf2f(kpl[tx * 4 + j2][pp[j2]]);
        float gq = bf2f(qpl[ty * 4 + i2][pp[j2]]);
        sv[j2] = (acc[i2][j2] + gk + gq) * 0.125f + ee[j2];
      }
      *(float4*)&ob[(size_t)row * LL + col0] =
          make_float4(sv[0], sv[1], sv[2], sv[3]);
      float m = fmaxf(fmaxf(sv[0], sv[1]), fmaxf(sv[2], sv[3]));
#pragma unroll
      for (int off = 1; off < 16; off <<= 1) m = fmaxf(m, __shfl_xor(m, off, 64));
      float ss = expf(sv[0] - m) + expf(sv[1] - m) + expf(sv[2] - m) + expf(sv[3] - m);
#pragma unroll
      for (int off = 1; off < 16; off <<= 1) ss += __shfl_xor(ss, off, 64);
      if (tx == 0) {
        stat_m[jt][ty * 4 + i2] = m;
        stat_s[jt][ty * 4 + i2] = ss;
      }
    }
  }
  __syncthreads();

  // ---- Combine stats ----
  if (tid < 64) {
    float m = stat_m[0][tid];
#pragma unroll
    for (int j = 1; j < 8; j++) m = fmaxf(m, stat_m[j][tid]);
    float s = 0.f;
#pragma unroll
    for (int j = 0; j < 8; j++) s += stat_s[j][tid] * expf(stat_m[j][tid] - m);
    smax[tid] = m;
    srs[tid] = 1.0f / s;
  }
  __syncthreads();

  // ---- Phase 2: softmax + PV (reads back own eout tiles, L2-hot) ----
  float acco[4][4] = {};
  const u16* vbb = vb_ + (size_t)bh * (LL * DHH);
  int c4 = tx * 4, r0 = ty;

  for (int jt = 0; jt < 8; jt++) {
    int j0 = jt * 64;
#pragma unroll
    for (int rr = 0; rr < 4; rr++) {
      int rL = r0 + rr * 16;
      float4 s4 = *(const float4*)(ob + (size_t)(i0 + rL) * LL + j0 + c4);
      float m = smax[rL], rs = srs[rL];
      Pt[c4 + 0][rL] = expf(s4.x - m) * rs;
      Pt[c4 + 1][rL] = expf(s4.y - m) * rs;
      Pt[c4 + 2][rL] = expf(s4.z - m) * rs;
      Pt[c4 + 3][rL] = expf(s4.w - m) * rs;
      uint2 v2 = *(const uint2*)(vbb + (size_t)(j0 + rL) * DHH + c4);
      Vt[rL][c4 + 0] = bf2f((u16)(v2.x & 0xffff));
      Vt[rL][c4 + 1] = bf2f((u16)(v2.x >> 16));
      Vt[rL][c4 + 2] = bf2f((u16)(v2.y & 0xffff));
      Vt[rL][c4 + 3] = bf2f((u16)(v2.y >> 16));
    }
    __syncthreads();
#pragma unroll 8
    for (int kk = 0; kk < 64; kk++) {
      float4 a4 = *(const float4*)&Pt[kk][ty * 4];
      float4 b4 = *(const float4*)&Vt[kk][tx * 4];
      float ar[4] = {a4.x, a4.y, a4.z, a4.w};
      float br[4] = {b4.x, b4.y, b4.z, b4.w};
#pragma unroll
      for (int i2 = 0; i2 < 4; i2++)
#pragma unroll
        for (int j2 = 0; j2 < 4; j2++)
          acco[i2][j2] += ar[i2] * br[j2];
    }
    __syncthreads();
  }

#pragma unroll
  for (int i2 = 0; i2 < 4; i2++) {
    int i = i0 + ty * 4 + i2;
    u32 lo = (u32)f2bf(acco[i2][0]) | ((u32)f2bf(acco[i2][1]) << 16);
    u32 hi = (u32)f2bf(acco[i2][2]) | ((u32)f2bf(acco[i2][3]) << 16);
    *(uint2*)&olbd[((size_t)i * BB + b) * DD + h * 64 + tx * 4] =
        make_uint2(lo, hi);
  }
}

// ---------------------------------------------------------------------------
extern "C" void kernel_launch(void* const* d_in, const int* in_sizes, int n_in,
                              void* d_out, int out_size, void* d_ws, size_t ws_size,
                              hipStream_t stream) {
  const float* x      = (const float*)d_in[0];
  const float* edge   = (const float*)d_in[1];
  const int*   bdist  = (const int*)d_in[2];
  const float* W_in   = (const float*)d_in[3];
  const float* b_in   = (const float*)d_in[4];
  const float* pe_emb = (const float*)d_in[5];
  const float* W_out  = (const float*)d_in[6];
  const float* b_out  = (const float*)d_in[7];
  const float* W1     = (const float*)d_in[8];
  const float* b1     = (const float*)d_in[9];
  const float* W2     = (const float*)d_in[10];
  const float* b2     = (const float*)d_in[11];
  const float* ln1w   = (const float*)d_in[12];
  const float* ln1b   = (const float*)d_in[13];
  const float* ln2w   = (const float*)d_in[14];
  const float* ln2b   = (const float*)d_in[15];

  float* xout = (float*)d_out;                 // [L,B,D]
  float* eout = xout + (size_t)LL * BB * DD;   // [B*H,L,L] == final scores

  // Workspace layout (float units). Max used: ~34,000,000 floats = 136 MB.
  float* ws = (float*)d_ws;
  u16*   xnb    = (u16*)(ws + 0);          // [4096,768] bf16
  float* qkv    = ws + 1600000;            // [4096,2304] fp32
  u16*   olbdb  = (u16*)(ws + 1600000);    // bf16 O, reuse after split
  u16*   ff1b   = (u16*)(ws + 3200000);    // [4096,3072] bf16
  float* x1     = ws + 11100000;
  float* pe     = ws + 14300000;           // [128,2304] fp32
  float* q      = ws + 14600000;
  float* k      = ws + 17800000;
  u16*   vb     = (u16*)(ws + 21000000);
  u8*    bdT    = (u8*)(ws + 23400000);    // [8,512,512] u8
  u16*   kpb    = (u16*)(ws + 24000000);   // [96,512,128] bf16
  u16*   qpb    = (u16*)(ws + 27200000);
  u16*   W1b    = (u16*)(ws + 30400000);
  u16*   W2b    = (u16*)(ws + 31600000);
  u16*   W_inb  = (u16*)(ws + 32800000);
  u16*   W_outb = (u16*)(ws + 33700000);

  // 0) dtype conversions + bdist transpose
  f2b_kernel<<<1728, 256, 0, stream>>>(W_in, W_inb);
  f2b_kernel<<<576, 256, 0, stream>>>(W_out, W_outb);
  f2b_kernel<<<2304, 256, 0, stream>>>(W1, W1b);
  f2b_kernel<<<2304, 256, 0, stream>>>(W2, W2b);
  bdist_t<<<8192, 256, 0, stream>>>(bdist, bdT);
  // 1) LN1 -> bf16
  ln_bf16<<<4096, 256, 0, stream>>>(x, ln1w, ln1b, xnb);
  // 2) qkv = xn @ W_in^T + b_in  (MFMA, fp32 out)
  gemm_mfma<0, 0, 0><<<dim3(18, 32), 256, 0, stream>>>(
      xnb, DD, W_inb, DD, qkv, 3 * DD, b_in, nullptr, DD);
  // 3) pe_proj fp32
  gemm_kernel<0><<<dim3(36, 2, 1), 256, 0, stream>>>(
      pe_emb, DD, 0, 0, W_in, DD, 0, 0, pe, 3 * DD, 0, 0, b_in, nullptr, DD, 0);
  // 4) split -> q,k fp32 + vb bf16
  split_qkv3<<<12288, 256, 0, stream>>>(qkv, q, k, vb);
  // 5) kp = k @ pe_q^T per head (bf16 store)
  gemm_kernel<1><<<dim3(2, 8, 96), 256, 0, stream>>>(
      k, DHH, (long)HH * LL * DHH, (long)LL * DHH,
      pe, 3 * DD, 0, 64,
      kpb, PP, (long)HH * LL * PP, (long)LL * PP, nullptr, nullptr, DHH, 0);
  // 6) qp = q @ pe_k^T per head
  gemm_kernel<1><<<dim3(2, 8, 96), 256, 0, stream>>>(
      q, DHH, (long)HH * LL * DHH, (long)LL * DHH,
      pe + DD, 3 * DD, 0, 64,
      qpb, PP, (long)HH * LL * PP, (long)LL * PP, nullptr, nullptr, DHH, 0);
  // 7) fused scores + softmax + PV -> eout + olbd bf16 [L,B,D]
  attn_fused<<<dim3(8, 96), 256, 0, stream>>>(q, k, kpb, qpb, bdT, edge, vb,
                                              eout, olbdb);
  // 8) x1 = O @ W_out^T + b_out + x
  gemm_mfma<0, 0, 1><<<dim3(6, 32), 256, 0, stream>>>(
      olbdb, DD, W_outb, DD, x1, DD, b_out, x, DD);
  // 9) LN2 -> bf16
  ln_bf16<<<4096, 256, 0, stream>>>(x1, ln2w, ln2b, xnb);
  // 10) ff1 = gelu(xn @ W1^T + b1) (bf16 out)
  gemm_mfma<1, 1, 0><<<dim3(24, 32), 256, 0, stream>>>(
      xnb, DD, W1b, DD, ff1b, 4 * DD, b1, nullptr, DD);
  // 11) x_out = ff1 @ W2^T + b2 + x1  (K=3072)
  gemm_mfma<0, 0, 1><<<dim3(6, 32), 256, 0, stream>>>(
      ff1b, 4 * DD, W2b, 4 * DD, xout, DD, b2, x1, 4 * DD);
}

// Round 9
// 504.382 us; speedup vs baseline: 1.1149x; 1.1149x over previous
//
#include <hip/hip_runtime.h>
#include <hip/hip_bf16.h>
#include <math.h>

// Problem constants
#define LL 512
#define BB 8
#define DD 768
#define HH 12
#define DHH 64
#define PP 128

typedef unsigned char u8;
typedef unsigned short u16;
typedef unsigned int u32;
typedef __attribute__((ext_vector_type(8))) short bf16x8;
typedef __attribute__((ext_vector_type(4))) float f32x4;

__device__ __forceinline__ u16 f2bf(float f) {
  u32 u = __float_as_uint(f);
  u32 r = (u + 0x7fffu + ((u >> 16) & 1u)) >> 16;
  return (u16)r;
}
__device__ __forceinline__ float bf2f(u16 u) {
  return __uint_as_float((u32)u << 16);
}

#define GLDS(g, l)                                                             \
  __builtin_amdgcn_global_load_lds(                                            \
      (const __attribute__((address_space(1))) void*)(g),                      \
      (__attribute__((address_space(3))) void*)(l), 16, 0, 0)

// ---------------------------------------------------------------------------
__device__ __forceinline__ void block_reduce2(float& a, float& b, float* sbuf) {
#pragma unroll
  for (int off = 32; off > 0; off >>= 1) {
    a += __shfl_down(a, off, 64);
    b += __shfl_down(b, off, 64);
  }
  int wid = threadIdx.x >> 6, lane = threadIdx.x & 63;
  __syncthreads();
  if (lane == 0) { sbuf[wid] = a; sbuf[4 + wid] = b; }
  __syncthreads();
  a = sbuf[0] + sbuf[1] + sbuf[2] + sbuf[3];
  b = sbuf[4] + sbuf[5] + sbuf[6] + sbuf[7];
}

// LayerNorm over D=768, one block per row, bf16 output
__global__ __launch_bounds__(256) void ln_bf16(const float* __restrict__ x,
                                               const float* __restrict__ w,
                                               const float* __restrict__ bb,
                                               u16* __restrict__ out) {
  __shared__ float sbuf[8];
  size_t row = blockIdx.x;
  const float* xr = x + row * DD;
  int t = threadIdx.x;
  float v0 = xr[t], v1 = xr[t + 256], v2 = xr[t + 512];
  float s = v0 + v1 + v2;
  float ss = v0 * v0 + v1 * v1 + v2 * v2;
  block_reduce2(s, ss, sbuf);
  float mu = s * (1.0f / DD);
  float var = ss * (1.0f / DD) - mu * mu;
  float r = rsqrtf(var + 1e-5f);
  u16* orow = out + row * DD;
  orow[t]       = f2bf((v0 - mu) * r * w[t]       + bb[t]);
  orow[t + 256] = f2bf((v1 - mu) * r * w[t + 256] + bb[t + 256]);
  orow[t + 512] = f2bf((v2 - mu) * r * w[t + 512] + bb[t + 512]);
}

// fp32 -> bf16, 4 elements/thread
__global__ __launch_bounds__(256) void f2b_kernel(const float* __restrict__ in,
                                                  u16* __restrict__ out) {
  int idx = blockIdx.x * 256 + threadIdx.x;
  float4 v = *(const float4*)(in + (size_t)idx * 4);
  u32 lo = (u32)f2bf(v.x) | ((u32)f2bf(v.y) << 16);
  u32 hi = (u32)f2bf(v.z) | ((u32)f2bf(v.w) << 16);
  *(uint2*)(out + (size_t)idx * 4) = make_uint2(lo, hi);
}

// bdist [L,L,B] int32 -> bdistT [B,L,L] u8 (values < 128)
__global__ __launch_bounds__(256) void bdist_t(const int* __restrict__ bd,
                                               u8* __restrict__ out) {
  int t = blockIdx.x * 256 + threadIdx.x;  // 2,097,152 items, read-coalesced
  int b = t & 7, jj = (t >> 3) & 511, ii = t >> 12;
  out[((size_t)b << 18) + ((size_t)ii << 9) + jj] = (u8)bd[t];
}

// ---------------------------------------------------------------------------
// bf16 MFMA GEMM (round-3-proven): C = act(A * B^T + bias) [+ residual].
// 128x128 tile, BK=32, 4 waves 2x2. Requires 128 | grid-covered M,N; 32 | K.
template <int ACT, int OBF, int RES>
__global__ __launch_bounds__(256) void gemm_mfma(
    const u16* __restrict__ A, int lda, const u16* __restrict__ B, int ldb,
    void* __restrict__ Cv, int ldc, const float* __restrict__ bias,
    const float* __restrict__ residual, int K) {
  __shared__ __align__(16) u16 Asl[128 * 32];
  __shared__ __align__(16) u16 Bsl[128 * 32];
  int t = threadIdx.x;
  int m0 = blockIdx.y * 128, n0 = blockIdx.x * 128;
  int lane = t & 63, w = t >> 6;
  int wr = w >> 1, wc = w & 1;
  int lr = lane & 15, lg = lane >> 4;

  f32x4 acc[4][4] = {};

  const u16* Ag0 = A + (size_t)(m0 + (t >> 2)) * lda + (t & 3) * 8;
  const u16* Ag1 = A + (size_t)(m0 + 64 + (t >> 2)) * lda + (t & 3) * 8;
  const u16* Bg0 = B + (size_t)(n0 + (t >> 2)) * ldb + (t & 3) * 8;
  const u16* Bg1 = B + (size_t)(n0 + 64 + (t >> 2)) * ldb + (t & 3) * 8;
  u16* Ad0 = &Asl[t * 8];
  u16* Ad1 = &Asl[2048 + t * 8];
  u16* Bd0 = &Bsl[t * 8];
  u16* Bd1 = &Bsl[2048 + t * 8];

  for (int k0 = 0; k0 < K; k0 += 32) {
    GLDS(Ag0 + k0, Ad0);
    GLDS(Ag1 + k0, Ad1);
    GLDS(Bg0 + k0, Bd0);
    GLDS(Bg1 + k0, Bd1);
    __syncthreads();
    bf16x8 a[4], b[4];
#pragma unroll
    for (int i = 0; i < 4; i++)
      a[i] = *(const bf16x8*)&Asl[(wr * 64 + i * 16 + lr) * 32 + lg * 8];
#pragma unroll
    for (int j = 0; j < 4; j++)
      b[j] = *(const bf16x8*)&Bsl[(wc * 64 + j * 16 + lr) * 32 + lg * 8];
#pragma unroll
    for (int i = 0; i < 4; i++)
#pragma unroll
      for (int j = 0; j < 4; j++)
        asm volatile("v_mfma_f32_16x16x32_bf16 %0, %1, %2, %0"
                     : "+v"(acc[i][j])
                     : "v"(a[i]), "v"(b[j]));
    __syncthreads();
  }
  asm volatile("s_nop 7\n\ts_nop 7" ::);

  float* Cf = (float*)Cv;
  u16* Cb = (u16*)Cv;
#pragma unroll
  for (int i = 0; i < 4; i++) {
#pragma unroll
    for (int r = 0; r < 4; r++) {
      int row = m0 + wr * 64 + i * 16 + lg * 4 + r;
#pragma unroll
      for (int j = 0; j < 4; j++) {
        int col = n0 + wc * 64 + j * 16 + lr;
        float vv = acc[i][j][r];
        if (bias) vv += bias[col];
        if (ACT) vv = 0.5f * vv * (1.0f + erff(vv * 0.70710678118654752f));
        if (RES) vv += residual[(size_t)row * ldc + col];
        if (OBF) Cb[(size_t)row * ldc + col] = f2bf(vv);
        else     Cf[(size_t)row * ldc + col] = vv;
      }
    }
  }
}

// ---------------------------------------------------------------------------
// Batched variant of the proven gemm_mfma (z-offsets only; used for kp/qp).
// A += z*sAz; B += (z%HH)*sBz; C += z*sCz. bf16 out, no bias/act/res.
__global__ __launch_bounds__(256) void gemm_mfma_b(
    const u16* __restrict__ A, int lda, long sAz,
    const u16* __restrict__ B, int ldb, long sBz,
    u16* __restrict__ Cb, int ldc, long sCz, int K) {
  __shared__ __align__(16) u16 Asl[128 * 32];
  __shared__ __align__(16) u16 Bsl[128 * 32];
  int z = blockIdx.z;
  A += (size_t)z * sAz;
  B += (size_t)(z % HH) * sBz;
  Cb += (size_t)z * sCz;
  int t = threadIdx.x;
  int m0 = blockIdx.y * 128, n0 = blockIdx.x * 128;
  int lane = t & 63, w = t >> 6;
  int wr = w >> 1, wc = w & 1;
  int lr = lane & 15, lg = lane >> 4;

  f32x4 acc[4][4] = {};

  const u16* Ag0 = A + (size_t)(m0 + (t >> 2)) * lda + (t & 3) * 8;
  const u16* Ag1 = A + (size_t)(m0 + 64 + (t >> 2)) * lda + (t & 3) * 8;
  const u16* Bg0 = B + (size_t)(n0 + (t >> 2)) * ldb + (t & 3) * 8;
  const u16* Bg1 = B + (size_t)(n0 + 64 + (t >> 2)) * ldb + (t & 3) * 8;
  u16* Ad0 = &Asl[t * 8];
  u16* Ad1 = &Asl[2048 + t * 8];
  u16* Bd0 = &Bsl[t * 8];
  u16* Bd1 = &Bsl[2048 + t * 8];

  for (int k0 = 0; k0 < K; k0 += 32) {
    GLDS(Ag0 + k0, Ad0);
    GLDS(Ag1 + k0, Ad1);
    GLDS(Bg0 + k0, Bd0);
    GLDS(Bg1 + k0, Bd1);
    __syncthreads();
    bf16x8 a[4], b[4];
#pragma unroll
    for (int i = 0; i < 4; i++)
      a[i] = *(const bf16x8*)&Asl[(wr * 64 + i * 16 + lr) * 32 + lg * 8];
#pragma unroll
    for (int j = 0; j < 4; j++)
      b[j] = *(const bf16x8*)&Bsl[(wc * 64 + j * 16 + lr) * 32 + lg * 8];
#pragma unroll
    for (int i = 0; i < 4; i++)
#pragma unroll
      for (int j = 0; j < 4; j++)
        asm volatile("v_mfma_f32_16x16x32_bf16 %0, %1, %2, %0"
                     : "+v"(acc[i][j])
                     : "v"(a[i]), "v"(b[j]));
    __syncthreads();
  }
  asm volatile("s_nop 7\n\ts_nop 7" ::);

#pragma unroll
  for (int i = 0; i < 4; i++) {
#pragma unroll
    for (int r = 0; r < 4; r++) {
      int row = m0 + wr * 64 + i * 16 + lg * 4 + r;
#pragma unroll
      for (int j = 0; j < 4; j++) {
        int col = n0 + wc * 64 + j * 16 + lr;
        Cb[(size_t)row * ldc + col] = f2bf(acc[i][j][r]);
      }
    }
  }
}

// ---------------------------------------------------------------------------
// Generic fp32 GEMM (round-3-proven): C = A*B^T (+bias); OBF=1 -> bf16 store.
template <int OBF>
__global__ __launch_bounds__(256) void gemm_kernel(
    const float* __restrict__ A, int lda, long sAo, long sAi,
    const float* __restrict__ B, int ldb, long sBo, long sBi,
    void* __restrict__ Cv, int ldc, long sCo, long sCi,
    const float* __restrict__ bias,
    const float* __restrict__ residual,
    int K, int act) {
  int z = blockIdx.z;
  int zo = z / HH, zi = z - zo * HH;
  A += (size_t)zo * sAo + (size_t)zi * sAi;
  B += (size_t)zo * sBo + (size_t)zi * sBi;
  size_t coff = (size_t)zo * sCo + (size_t)zi * sCi;

  __shared__ float As[16][68];
  __shared__ float Bs[16][68];
  int tid = threadIdx.x;
  int tx = tid & 15, ty = tid >> 4;
  int m0 = blockIdx.y * 64, n0 = blockIdx.x * 64;
  float acc[4][4] = {};
  int r = tid >> 2, kq = (tid & 3) * 4;

  for (int k0 = 0; k0 < K; k0 += 16) {
    float4 av = *(const float4*)(A + (size_t)(m0 + r) * lda + (k0 + kq));
    float4 bv = *(const float4*)(B + (size_t)(n0 + r) * ldb + (k0 + kq));
    As[kq + 0][r] = av.x; As[kq + 1][r] = av.y; As[kq + 2][r] = av.z; As[kq + 3][r] = av.w;
    Bs[kq + 0][r] = bv.x; Bs[kq + 1][r] = bv.y; Bs[kq + 2][r] = bv.z; Bs[kq + 3][r] = bv.w;
    __syncthreads();
#pragma unroll
    for (int kk = 0; kk < 16; kk++) {
      float4 a4 = *(const float4*)&As[kk][ty * 4];
      float4 b4 = *(const float4*)&Bs[kk][tx * 4];
      float ar[4] = {a4.x, a4.y, a4.z, a4.w};
      float br[4] = {b4.x, b4.y, b4.z, b4.w};
#pragma unroll
      for (int i2 = 0; i2 < 4; i2++)
#pragma unroll
        for (int j2 = 0; j2 < 4; j2++)
          acc[i2][j2] += ar[i2] * br[j2];
    }
    __syncthreads();
  }

  float bs[4] = {0.f, 0.f, 0.f, 0.f};
  if (bias) {
    float4 b4 = *(const float4*)&bias[n0 + tx * 4];
    bs[0] = b4.x; bs[1] = b4.y; bs[2] = b4.z; bs[3] = b4.w;
  }
  float* Cf = (float*)Cv;
  u16* Cb = (u16*)Cv;
#pragma unroll
  for (int i2 = 0; i2 < 4; i2++) {
    size_t m = (size_t)(m0 + ty * 4 + i2);
    float vout[4];
#pragma unroll
    for (int j2 = 0; j2 < 4; j2++) vout[j2] = acc[i2][j2] + bs[j2];
    if (residual) {
      const float4 r4 = *(const float4*)&residual[coff + m * ldc + n0 + tx * 4];
      vout[0] += r4.x; vout[1] += r4.y; vout[2] += r4.z; vout[3] += r4.w;
    }
    if (OBF) {
      u32 lo = (u32)f2bf(vout[0]) | ((u32)f2bf(vout[1]) << 16);
      u32 hi = (u32)f2bf(vout[2]) | ((u32)f2bf(vout[3]) << 16);
      *(uint2*)&Cb[coff + m * ldc + n0 + tx * 4] = make_uint2(lo, hi);
    } else {
      *(float4*)&Cf[coff + m * ldc + n0 + tx * 4] =
          make_float4(vout[0], vout[1], vout[2], vout[3]);
    }
  }
}

// ---------------------------------------------------------------------------
// qkv fp32 [L*B, 3D] -> q,k fp32 + qb,kb,vb bf16, all [B,H,L,Dh]
__global__ __launch_bounds__(256) void split_qkv4(const float* __restrict__ qkv,
                                                  float* __restrict__ q,
                                                  float* __restrict__ k,
                                                  u16* __restrict__ qb,
                                                  u16* __restrict__ kb,
                                                  u16* __restrict__ vb) {
  int idx = blockIdx.x * 256 + threadIdx.x;  // over 3,145,728
  int d = idx & 63;
  int l = (idx >> 6) & 511;
  int bh = idx >> 15;
  int b = bh / HH, h = bh - b * HH;
  size_t src = ((size_t)(l * BB + b)) * (3 * DD) + h * 64 + d;
  float qv = qkv[src], kv = qkv[src + DD], vv = qkv[src + 2 * DD];
  q[idx] = qv;
  k[idx] = kv;
  qb[idx] = f2bf(qv);
  kb[idx] = f2bf(kv);
  vb[idx] = f2bf(vv);
}

// ---------------------------------------------------------------------------
// Fused fp32 QK^T + LDS-staged bf16 kp/qp gathers + scale + edge -> scores,
// plus per-(row, 64-col-tile) softmax partials -> stats. (round-7-proven)
__global__ __launch_bounds__(256) void qkt_gather_f32(
    const float* __restrict__ q, const float* __restrict__ k,
    const u16* __restrict__ kp, const u16* __restrict__ qp,
    const u8* __restrict__ bdT, const float* __restrict__ edge,
    float* __restrict__ eout, float* __restrict__ stats) {
  int bh = blockIdx.z, b = bh / HH;
  int i0 = blockIdx.y * 64, j0 = blockIdx.x * 64, jt = blockIdx.x;
  __shared__ float As[16][68];
  __shared__ float Bs[16][68];
  __shared__ u16 kpl[64][PP];
  __shared__ u16 qpl[64][PP];
  int tid = threadIdx.x;
  int tx = tid & 15, ty = tid >> 4;

  const u16* kpg = kp + (size_t)bh * (LL * PP);
  const u16* qpg = qp + (size_t)bh * (LL * PP);
  for (int c = tid; c < 1024; c += 256) {
    int row = c >> 4, ch = (c & 15) * 8;
    *(uint4*)&kpl[row][ch] = *(const uint4*)&kpg[(size_t)(j0 + row) * PP + ch];
    *(uint4*)&qpl[row][ch] = *(const uint4*)&qpg[(size_t)(i0 + row) * PP + ch];
  }

  float acc[4][4] = {};
  int r = tid >> 2, kq = (tid & 3) * 4;
  const float* A = q + (size_t)bh * (LL * DHH);
  const float* B = k + (size_t)bh * (LL * DHH);

  for (int k0 = 0; k0 < DHH; k0 += 16) {
    float4 av = *(const float4*)(A + (size_t)(i0 + r) * DHH + (k0 + kq));
    float4 bv = *(const float4*)(B + (size_t)(j0 + r) * DHH + (k0 + kq));
    As[kq + 0][r] = av.x; As[kq + 1][r] = av.y; As[kq + 2][r] = av.z; As[kq + 3][r] = av.w;
    Bs[kq + 0][r] = bv.x; Bs[kq + 1][r] = bv.y; Bs[kq + 2][r] = bv.z; Bs[kq + 3][r] = bv.w;
    __syncthreads();
#pragma unroll
    for (int kk = 0; kk < 16; kk++) {
      float4 a4 = *(const float4*)&As[kk][ty * 4];
      float4 b4 = *(const float4*)&Bs[kk][tx * 4];
      float ar[4] = {a4.x, a4.y, a4.z, a4.w};
      float br[4] = {b4.x, b4.y, b4.z, b4.w};
#pragma unroll
      for (int i2 = 0; i2 < 4; i2++)
#pragma unroll
        for (int j2 = 0; j2 < 4; j2++)
          acc[i2][j2] += ar[i2] * br[j2];
    }
    __syncthreads();
  }

  const u8* bd = bdT + (size_t)b * (LL * LL);
  const float* eb = edge + (size_t)bh * (LL * LL);
  float* ob = eout + (size_t)bh * (LL * LL);

  float rowm[4], rows[4];
#pragma unroll
  for (int i2 = 0; i2 < 4; i2++) {
    int row = i0 + ty * 4 + i2;
    int col0 = j0 + tx * 4;
    uchar4 p4 = *(const uchar4*)&bd[(size_t)row * LL + col0];
    float4 e4 = *(const float4*)&eb[(size_t)row * LL + col0];
    int pp[4] = {p4.x, p4.y, p4.z, p4.w};
    float ee[4] = {e4.x, e4.y, e4.z, e4.w};
    float sv[4];
#pragma unroll
    for (int j2 = 0; j2 < 4; j2++) {
      float gk = bf2f(kpl[tx * 4 + j2][pp[j2]]);
      float gq = bf2f(qpl[ty * 4 + i2][pp[j2]]);
      sv[j2] = (acc[i2][j2] + gk + gq) * 0.125f + ee[j2];
    }
    *(float4*)&ob[(size_t)row * LL + col0] =
        make_float4(sv[0], sv[1], sv[2], sv[3]);
    float m = fmaxf(fmaxf(sv[0], sv[1]), fmaxf(sv[2], sv[3]));
#pragma unroll
    for (int off = 1; off < 16; off <<= 1) m = fmaxf(m, __shfl_xor(m, off, 64));
    float ss = expf(sv[0] - m) + expf(sv[1] - m) + expf(sv[2] - m) + expf(sv[3] - m);
#pragma unroll
    for (int off = 1; off < 16; off <<= 1) ss += __shfl_xor(ss, off, 64);
    rowm[i2] = m;
    rows[i2] = ss;
  }
  if (tx == 0) {
#pragma unroll
    for (int i2 = 0; i2 < 4; i2++) {
      size_t si = ((size_t)bh * LL + i0 + ty * 4 + i2) * 16 + jt;
      stats[si] = rowm[i2];
      stats[si + 8] = rows[i2];
    }
  }
}

// ---------------------------------------------------------------------------
// Fused softmax + P@V using precomputed tile stats; V bf16; O bf16 [L,B,D].
__global__ __launch_bounds__(256) void softmax_pv_tiled(
    const float* __restrict__ scores, const u16* __restrict__ vb_,
    const float* __restrict__ stats, u16* __restrict__ olbd) {
  int bh = blockIdx.y;
  int i0 = blockIdx.x * 64;
  int b = bh / HH, h = bh - b * HH;
  __shared__ float Pt[64][66];
  __shared__ float Vt[64][72];
  __shared__ float smax[64], srs[64];
  int t = threadIdx.x;
  const float* sbase = scores + (size_t)bh * (LL * LL);

  if (t < 64) {
    size_t si = ((size_t)bh * LL + i0 + t) * 16;
    float m = stats[si];
#pragma unroll
    for (int j = 1; j < 8; j++) m = fmaxf(m, stats[si + j]);
    float s = 0.f;
#pragma unroll
    for (int j = 0; j < 8; j++) s += stats[si + 8 + j] * expf(stats[si + j] - m);
    smax[t] = m;
    srs[t] = 1.0f / s;
  }
  __syncthreads();

  float acc[4][4] = {};
  int tx = t & 15, ty = t >> 4;
  const u16* vb = vb_ + (size_t)bh * (LL * DHH);
  int c4 = (t & 15) * 4, r0 = t >> 4;

  for (int jt = 0; jt < 8; jt++) {
    int j0 = jt * 64;
#pragma unroll
    for (int rr = 0; rr < 4; rr++) {
      int r = r0 + rr * 16;
      float4 s4 = *(const float4*)(sbase + (size_t)(i0 + r) * LL + j0 + c4);
      float m = smax[r], rs = srs[r];
      Pt[c4 + 0][r] = expf(s4.x - m) * rs;
      Pt[c4 + 1][r] = expf(s4.y - m) * rs;
      Pt[c4 + 2][r] = expf(s4.z - m) * rs;
      Pt[c4 + 3][r] = expf(s4.w - m) * rs;
      uint2 v2 = *(const uint2*)(vb + (size_t)(j0 + r) * DHH + c4);
      Vt[r][c4 + 0] = bf2f((u16)(v2.x & 0xffff));
      Vt[r][c4 + 1] = bf2f((u16)(v2.x >> 16));
      Vt[r][c4 + 2] = bf2f((u16)(v2.y & 0xffff));
      Vt[r][c4 + 3] = bf2f((u16)(v2.y >> 16));
    }
    __syncthreads();
#pragma unroll 8
    for (int kk = 0; kk < 64; kk++) {
      float4 a4 = *(const float4*)&Pt[kk][ty * 4];
      float4 b4 = *(const float4*)&Vt[kk][tx * 4];
      float ar[4] = {a4.x, a4.y, a4.z, a4.w};
      float br[4] = {b4.x, b4.y, b4.z, b4.w};
#pragma unroll
      for (int i2 = 0; i2 < 4; i2++)
#pragma unroll
        for (int j2 = 0; j2 < 4; j2++)
          acc[i2][j2] += ar[i2] * br[j2];
    }
    __syncthreads();
  }

#pragma unroll
  for (int i2 = 0; i2 < 4; i2++) {
    int i = i0 + ty * 4 + i2;
    u32 lo = (u32)f2bf(acc[i2][0]) | ((u32)f2bf(acc[i2][1]) << 16);
    u32 hi = (u32)f2bf(acc[i2][2]) | ((u32)f2bf(acc[i2][3]) << 16);
    *(uint2*)&olbd[((size_t)i * BB + b) * DD + h * 64 + tx * 4] =
        make_uint2(lo, hi);
  }
}

// ---------------------------------------------------------------------------
extern "C" void kernel_launch(void* const* d_in, const int* in_sizes, int n_in,
                              void* d_out, int out_size, void* d_ws, size_t ws_size,
                              hipStream_t stream) {
  const float* x      = (const float*)d_in[0];
  const float* edge   = (const float*)d_in[1];
  const int*   bdist  = (const int*)d_in[2];
  const float* W_in   = (const float*)d_in[3];
  const float* b_in   = (const float*)d_in[4];
  const float* pe_emb = (const float*)d_in[5];
  const float* W_out  = (const float*)d_in[6];
  const float* b_out  = (const float*)d_in[7];
  const float* W1     = (const float*)d_in[8];
  const float* b1     = (const float*)d_in[9];
  const float* W2     = (const float*)d_in[10];
  const float* b2     = (const float*)d_in[11];
  const float* ln1w   = (const float*)d_in[12];
  const float* ln1b   = (const float*)d_in[13];
  const float* ln2w   = (const float*)d_in[14];
  const float* ln2b   = (const float*)d_in[15];

  float* xout = (float*)d_out;                 // [L,B,D]
  float* eout = xout + (size_t)LL * BB * DD;   // [B*H,L,L] == final scores

  // Workspace layout (float units). Max used: ~37.35M floats = 149.4 MB.
  float* ws = (float*)d_ws;
  u16*   xnb    = (u16*)(ws + 0);          // [4096,768] bf16 (1,572,864 fl)
  float* qkv    = ws + 1600000;            // [4096,2304] fp32, ends 11,037,184
  u16*   olbdb  = (u16*)(ws + 1600000);    // bf16 O, reuse after split
  u16*   ff1b   = (u16*)(ws + 3200000);    // [4096,3072] bf16, ends 9,491,456
  float* x1     = ws + 11100000;           // ends 14,245,728
  float* pe     = ws + 14300000;           // [128,2304] fp32, ends 14,594,912
  float* q      = ws + 14600000;           // ends 17,745,728
  float* k      = ws + 17800000;           // ends 20,945,728
  u16*   vb     = (u16*)(ws + 21000000);   // ends 22,572,864
  float* stats  = ws + 22600000;           // [96,512,16], ends 23,386,432
  u8*    bdT    = (u8*)(ws + 23400000);    // [8,512,512] u8, ends 23,924,288
  u16*   kpb    = (u16*)(ws + 24000000);   // [96,512,128] bf16, ends 27,145,728
  u16*   qpb    = (u16*)(ws + 27200000);   // ends 30,345,728
  u16*   W1b    = (u16*)(ws + 30400000);   // ends 31,579,648
  u16*   W2b    = (u16*)(ws + 31600000);   // ends 32,779,648
  u16*   W_inb  = (u16*)(ws + 32800000);   // ends 33,684,736
  u16*   W_outb = (u16*)(ws + 33700000);   // ends 33,994,912
  u16*   qb     = (u16*)(ws + 34000000);   // ends 35,572,864
  u16*   kb     = (u16*)(ws + 35600000);   // ends 37,172,864
  u16*   peb    = (u16*)(ws + 37200000);   // [128,2304] bf16, ends 37,347,456

  // 0) dtype conversions + bdist transpose
  f2b_kernel<<<1728, 256, 0, stream>>>(W_in, W_inb);
  f2b_kernel<<<576, 256, 0, stream>>>(W_out, W_outb);
  f2b_kernel<<<2304, 256, 0, stream>>>(W1, W1b);
  f2b_kernel<<<2304, 256, 0, stream>>>(W2, W2b);
  bdist_t<<<8192, 256, 0, stream>>>(bdist, bdT);
  // 1) LN1 -> bf16
  ln_bf16<<<4096, 256, 0, stream>>>(x, ln1w, ln1b, xnb);
  // 2) qkv = xn @ W_in^T + b_in  (MFMA, fp32 out)
  gemm_mfma<0, 0, 0><<<dim3(18, 32), 256, 0, stream>>>(
      xnb, DD, W_inb, DD, qkv, 3 * DD, b_in, nullptr, DD);
  // 3) pe_proj fp32, then bf16 copy for the kp/qp MFMA B-operand
  gemm_kernel<0><<<dim3(36, 2, 1), 256, 0, stream>>>(
      pe_emb, DD, 0, 0, W_in, DD, 0, 0, pe, 3 * DD, 0, 0, b_in, nullptr, DD, 0);
  f2b_kernel<<<288, 256, 0, stream>>>(pe, peb);
  // 4) split -> q,k fp32 + qb,kb,vb bf16
  split_qkv4<<<12288, 256, 0, stream>>>(qkv, q, k, qb, kb, vb);
  // 5) kp = k @ pe_q^T per head (batched MFMA; pe_q = peb[:, h*64:+64])
  gemm_mfma_b<<<dim3(1, 4, 96), 256, 0, stream>>>(
      kb, DHH, (long)LL * DHH, peb, 3 * DD, 64, kpb, PP, (long)LL * PP, DHH);
  // 6) qp = q @ pe_k^T per head (pe_k = peb[:, D + h*64:+64])
  gemm_mfma_b<<<dim3(1, 4, 96), 256, 0, stream>>>(
      qb, DHH, (long)LL * DHH, peb + DD, 3 * DD, 64, qpb, PP, (long)LL * PP, DHH);
  // 7) fused fp32 QK^T + LDS gathers + edge -> eout, + softmax tile stats
  qkt_gather_f32<<<dim3(8, 8, 96), 256, 0, stream>>>(q, k, kpb, qpb, bdT, edge,
                                                     eout, stats);
  // 8) fused softmax + PV -> olbd bf16 [L,B,D]
  softmax_pv_tiled<<<dim3(8, 96), 256, 0, stream>>>(eout, vb, stats, olbdb);
  // 9) x1 = O @ W_out^T + b_out + x
  gemm_mfma<0, 0, 1><<<dim3(6, 32), 256, 0, stream>>>(
      olbdb, DD, W_outb, DD, x1, DD, b_out, x, DD);
  // 10) LN2 -> bf16
  ln_bf16<<<4096, 256, 0, stream>>>(x1, ln2w, ln2b, xnb);
  // 11) ff1 = gelu(xn @ W1^T + b1) (bf16 out)
  gemm_mfma<1, 1, 0><<<dim3(24, 32), 256, 0, stream>>>(
      xnb, DD, W1b, DD, ff1b, 4 * DD, b1, nullptr, DD);
  // 12) x_out = ff1 @ W2^T + b2 + x1  (K=3072)
  gemm_mfma<0, 0, 1><<<dim3(6, 32), 256, 0, stream>>>(
      ff1b, 4 * DD, W2b, 4 * DD, xout, DD, b2, x1, 4 * DD);
}

// Round 11
// 416.408 us; speedup vs baseline: 1.3504x; 1.2113x over previous
//
#include <hip/hip_runtime.h>
#include <hip/hip_bf16.h>
#include <math.h>

// Problem constants
#define LL 512
#define BB 8
#define DD 768
#define HH 12
#define DHH 64
#define PP 128

typedef unsigned char u8;
typedef unsigned short u16;
typedef unsigned int u32;
typedef __attribute__((ext_vector_type(8))) short bf16x8;
typedef __attribute__((ext_vector_type(4))) float f32x4;

__device__ __forceinline__ u16 f2bf(float f) {
  u32 u = __float_as_uint(f);
  u32 r = (u + 0x7fffu + ((u >> 16) & 1u)) >> 16;
  return (u16)r;
}
__device__ __forceinline__ float bf2f(u32 u) {
  return __uint_as_float((u & 0xffffu) << 16);
}

#define GLDS(g, l)                                                             \
  __builtin_amdgcn_global_load_lds(                                            \
      (const __attribute__((address_space(1))) void*)(g),                      \
      (__attribute__((address_space(3))) void*)(l), 16, 0, 0)

// ---------------------------------------------------------------------------
__device__ __forceinline__ void block_reduce2(float& a, float& b, float* sbuf) {
#pragma unroll
  for (int off = 32; off > 0; off >>= 1) {
    a += __shfl_down(a, off, 64);
    b += __shfl_down(b, off, 64);
  }
  int wid = threadIdx.x >> 6, lane = threadIdx.x & 63;
  __syncthreads();
  if (lane == 0) { sbuf[wid] = a; sbuf[4 + wid] = b; }
  __syncthreads();
  a = sbuf[0] + sbuf[1] + sbuf[2] + sbuf[3];
  b = sbuf[4] + sbuf[5] + sbuf[6] + sbuf[7];
}

// LayerNorm over D=768, one block per row, bf16 output
__global__ __launch_bounds__(256) void ln_bf16(const float* __restrict__ x,
                                               const float* __restrict__ w,
                                               const float* __restrict__ bb,
                                               u16* __restrict__ out) {
  __shared__ float sbuf[8];
  size_t row = blockIdx.x;
  const float* xr = x + row * DD;
  int t = threadIdx.x;
  float v0 = xr[t], v1 = xr[t + 256], v2 = xr[t + 512];
  float s = v0 + v1 + v2;
  float ss = v0 * v0 + v1 * v1 + v2 * v2;
  block_reduce2(s, ss, sbuf);
  float mu = s * (1.0f / DD);
  float var = ss * (1.0f / DD) - mu * mu;
  float r = rsqrtf(var + 1e-5f);
  u16* orow = out + row * DD;
  orow[t]       = f2bf((v0 - mu) * r * w[t]       + bb[t]);
  orow[t + 256] = f2bf((v1 - mu) * r * w[t + 256] + bb[t + 256]);
  orow[t + 512] = f2bf((v2 - mu) * r * w[t + 512] + bb[t + 512]);
}

// fp32 -> bf16, 4 elements/thread
__global__ __launch_bounds__(256) void f2b_kernel(const float* __restrict__ in,
                                                  u16* __restrict__ out) {
  int idx = blockIdx.x * 256 + threadIdx.x;
  float4 v = *(const float4*)(in + (size_t)idx * 4);
  u32 lo = (u32)f2bf(v.x) | ((u32)f2bf(v.y) << 16);
  u32 hi = (u32)f2bf(v.z) | ((u32)f2bf(v.w) << 16);
  *(uint2*)(out + (size_t)idx * 4) = make_uint2(lo, hi);
}

// bdist [L,L,B] int32 -> bdistT [B,L,L] u8 (values < 128)
__global__ __launch_bounds__(256) void bdist_t(const int* __restrict__ bd,
                                               u8* __restrict__ out) {
  int t = blockIdx.x * 256 + threadIdx.x;  // 2,097,152 items, read-coalesced
  int b = t & 7, jj = (t >> 3) & 511, ii = t >> 12;
  out[((size_t)b << 18) + ((size_t)ii << 9) + jj] = (u8)bd[t];
}

// ---------------------------------------------------------------------------
// bf16 MFMA GEMM (round-3-proven): C = act(A * B^T + bias) [+ residual].
// 128x128 tile, BK=32, 4 waves 2x2. Requires 128 | grid-covered M,N; 32 | K.
template <int ACT, int OBF, int RES>
__global__ __launch_bounds__(256) void gemm_mfma(
    const u16* __restrict__ A, int lda, const u16* __restrict__ B, int ldb,
    void* __restrict__ Cv, int ldc, const float* __restrict__ bias,
    const float* __restrict__ residual, int K) {
  __shared__ __align__(16) u16 Asl[128 * 32];
  __shared__ __align__(16) u16 Bsl[128 * 32];
  int t = threadIdx.x;
  int m0 = blockIdx.y * 128, n0 = blockIdx.x * 128;
  int lane = t & 63, w = t >> 6;
  int wr = w >> 1, wc = w & 1;
  int lr = lane & 15, lg = lane >> 4;

  f32x4 acc[4][4] = {};

  const u16* Ag0 = A + (size_t)(m0 + (t >> 2)) * lda + (t & 3) * 8;
  const u16* Ag1 = A + (size_t)(m0 + 64 + (t >> 2)) * lda + (t & 3) * 8;
  const u16* Bg0 = B + (size_t)(n0 + (t >> 2)) * ldb + (t & 3) * 8;
  const u16* Bg1 = B + (size_t)(n0 + 64 + (t >> 2)) * ldb + (t & 3) * 8;
  u16* Ad0 = &Asl[t * 8];
  u16* Ad1 = &Asl[2048 + t * 8];
  u16* Bd0 = &Bsl[t * 8];
  u16* Bd1 = &Bsl[2048 + t * 8];

  for (int k0 = 0; k0 < K; k0 += 32) {
    GLDS(Ag0 + k0, Ad0);
    GLDS(Ag1 + k0, Ad1);
    GLDS(Bg0 + k0, Bd0);
    GLDS(Bg1 + k0, Bd1);
    __syncthreads();
    bf16x8 a[4], b[4];
#pragma unroll
    for (int i = 0; i < 4; i++)
      a[i] = *(const bf16x8*)&Asl[(wr * 64 + i * 16 + lr) * 32 + lg * 8];
#pragma unroll
    for (int j = 0; j < 4; j++)
      b[j] = *(const bf16x8*)&Bsl[(wc * 64 + j * 16 + lr) * 32 + lg * 8];
#pragma unroll
    for (int i = 0; i < 4; i++)
#pragma unroll
      for (int j = 0; j < 4; j++)
        asm volatile("v_mfma_f32_16x16x32_bf16 %0, %1, %2, %0"
                     : "+v"(acc[i][j])
                     : "v"(a[i]), "v"(b[j]));
    __syncthreads();
  }
  asm volatile("s_nop 7\n\ts_nop 7" ::);

  float* Cf = (float*)Cv;
  u16* Cb = (u16*)Cv;
#pragma unroll
  for (int i = 0; i < 4; i++) {
#pragma unroll
    for (int r = 0; r < 4; r++) {
      int row = m0 + wr * 64 + i * 16 + lg * 4 + r;
#pragma unroll
      for (int j = 0; j < 4; j++) {
        int col = n0 + wc * 64 + j * 16 + lr;
        float vv = acc[i][j][r];
        if (bias) vv += bias[col];
        if (ACT) vv = 0.5f * vv * (1.0f + erff(vv * 0.70710678118654752f));
        if (RES) vv += residual[(size_t)row * ldc + col];
        if (OBF) Cb[(size_t)row * ldc + col] = f2bf(vv);
        else     Cf[(size_t)row * ldc + col] = vv;
      }
    }
  }
}

// ---------------------------------------------------------------------------
// Batched variant (round-9-proven; kp/qp): A += z*sAz; B += (z%HH)*sBz.
__global__ __launch_bounds__(256) void gemm_mfma_b(
    const u16* __restrict__ A, int lda, long sAz,
    const u16* __restrict__ B, int ldb, long sBz,
    u16* __restrict__ Cb, int ldc, long sCz, int K) {
  __shared__ __align__(16) u16 Asl[128 * 32];
  __shared__ __align__(16) u16 Bsl[128 * 32];
  int z = blockIdx.z;
  A += (size_t)z * sAz;
  B += (size_t)(z % HH) * sBz;
  Cb += (size_t)z * sCz;
  int t = threadIdx.x;
  int m0 = blockIdx.y * 128, n0 = blockIdx.x * 128;
  int lane = t & 63, w = t >> 6;
  int wr = w >> 1, wc = w & 1;
  int lr = lane & 15, lg = lane >> 4;

  f32x4 acc[4][4] = {};

  const u16* Ag0 = A + (size_t)(m0 + (t >> 2)) * lda + (t & 3) * 8;
  const u16* Ag1 = A + (size_t)(m0 + 64 + (t >> 2)) * lda + (t & 3) * 8;
  const u16* Bg0 = B + (size_t)(n0 + (t >> 2)) * ldb + (t & 3) * 8;
  const u16* Bg1 = B + (size_t)(n0 + 64 + (t >> 2)) * ldb + (t & 3) * 8;
  u16* Ad0 = &Asl[t * 8];
  u16* Ad1 = &Asl[2048 + t * 8];
  u16* Bd0 = &Bsl[t * 8];
  u16* Bd1 = &Bsl[2048 + t * 8];

  for (int k0 = 0; k0 < K; k0 += 32) {
    GLDS(Ag0 + k0, Ad0);
    GLDS(Ag1 + k0, Ad1);
    GLDS(Bg0 + k0, Bd0);
    GLDS(Bg1 + k0, Bd1);
    __syncthreads();
    bf16x8 a[4], b[4];
#pragma unroll
    for (int i = 0; i < 4; i++)
      a[i] = *(const bf16x8*)&Asl[(wr * 64 + i * 16 + lr) * 32 + lg * 8];
#pragma unroll
    for (int j = 0; j < 4; j++)
      b[j] = *(const bf16x8*)&Bsl[(wc * 64 + j * 16 + lr) * 32 + lg * 8];
#pragma unroll
    for (int i = 0; i < 4; i++)
#pragma unroll
      for (int j = 0; j < 4; j++)
        asm volatile("v_mfma_f32_16x16x32_bf16 %0, %1, %2, %0"
                     : "+v"(acc[i][j])
                     : "v"(a[i]), "v"(b[j]));
    __syncthreads();
  }
  asm volatile("s_nop 7\n\ts_nop 7" ::);

#pragma unroll
  for (int i = 0; i < 4; i++) {
#pragma unroll
    for (int r = 0; r < 4; r++) {
      int row = m0 + wr * 64 + i * 16 + lg * 4 + r;
#pragma unroll
      for (int j = 0; j < 4; j++) {
        int col = n0 + wc * 64 + j * 16 + lr;
        Cb[(size_t)row * ldc + col] = f2bf(acc[i][j][r]);
      }
    }
  }
}

// ---------------------------------------------------------------------------
// Split-K partial MFMA GEMM: z = blockIdx.z selects K-window and partial buf.
// A[M,Ktot] (lda), B[N,Ktot] (ldb); computes A[:,zK:(z+1)K] * B[:,...]^T
// into Cf + z*partStride, fp32, no bias/act/res. Same proven 128x128 core.
__global__ __launch_bounds__(256) void gemm_mfma_part(
    const u16* __restrict__ A, int lda, const u16* __restrict__ B, int ldb,
    float* __restrict__ Cf, int ldc, long partStride, int Kper) {
  __shared__ __align__(16) u16 Asl[128 * 32];
  __shared__ __align__(16) u16 Bsl[128 * 32];
  int z = blockIdx.z;
  A += (size_t)z * Kper;
  B += (size_t)z * Kper;
  Cf += (size_t)z * partStride;
  int t = threadIdx.x;
  int m0 = blockIdx.y * 128, n0 = blockIdx.x * 128;
  int lane = t & 63, w = t >> 6;
  int wr = w >> 1, wc = w & 1;
  int lr = lane & 15, lg = lane >> 4;

  f32x4 acc[4][4] = {};

  const u16* Ag0 = A + (size_t)(m0 + (t >> 2)) * lda + (t & 3) * 8;
  const u16* Ag1 = A + (size_t)(m0 + 64 + (t >> 2)) * lda + (t & 3) * 8;
  const u16* Bg0 = B + (size_t)(n0 + (t >> 2)) * ldb + (t & 3) * 8;
  const u16* Bg1 = B + (size_t)(n0 + 64 + (t >> 2)) * ldb + (t & 3) * 8;
  u16* Ad0 = &Asl[t * 8];
  u16* Ad1 = &Asl[2048 + t * 8];
  u16* Bd0 = &Bsl[t * 8];
  u16* Bd1 = &Bsl[2048 + t * 8];

  for (int k0 = 0; k0 < Kper; k0 += 32) {
    GLDS(Ag0 + k0, Ad0);
    GLDS(Ag1 + k0, Ad1);
    GLDS(Bg0 + k0, Bd0);
    GLDS(Bg1 + k0, Bd1);
    __syncthreads();
    bf16x8 a[4], b[4];
#pragma unroll
    for (int i = 0; i < 4; i++)
      a[i] = *(const bf16x8*)&Asl[(wr * 64 + i * 16 + lr) * 32 + lg * 8];
#pragma unroll
    for (int j = 0; j < 4; j++)
      b[j] = *(const bf16x8*)&Bsl[(wc * 64 + j * 16 + lr) * 32 + lg * 8];
#pragma unroll
    for (int i = 0; i < 4; i++)
#pragma unroll
      for (int j = 0; j < 4; j++)
        asm volatile("v_mfma_f32_16x16x32_bf16 %0, %1, %2, %0"
                     : "+v"(acc[i][j])
                     : "v"(a[i]), "v"(b[j]));
    __syncthreads();
  }
  asm volatile("s_nop 7\n\ts_nop 7" ::);

#pragma unroll
  for (int i = 0; i < 4; i++) {
#pragma unroll
    for (int r = 0; r < 4; r++) {
      int row = m0 + wr * 64 + i * 16 + lg * 4 + r;
#pragma unroll
      for (int j = 0; j < 4; j++) {
        int col = n0 + wc * 64 + j * 16 + lr;
        Cf[(size_t)row * ldc + col] = acc[i][j][r];
      }
    }
  }
}

// Combine NS split-K partials: out = sum(parts) + bias + res. 4 elems/thread.
template <int NS>
__global__ __launch_bounds__(256) void combine_k(const float* __restrict__ p,
                                                 const float* __restrict__ bias,
                                                 const float* __restrict__ res,
                                                 float* __restrict__ out) {
  int idx = blockIdx.x * 256 + threadIdx.x;  // over 786,432
  size_t e = (size_t)idx * 4;
  float4 s = *(const float4*)(p + e);
#pragma unroll
  for (int z = 1; z < NS; z++) {
    float4 t2 = *(const float4*)(p + (size_t)z * 3145728 + e);
    s.x += t2.x; s.y += t2.y; s.z += t2.z; s.w += t2.w;
  }
  int col = (int)(e % DD);
  float4 b4 = *(const float4*)(bias + col);
  float4 r4 = *(const float4*)(res + e);
  *(float4*)(out + e) = make_float4(s.x + b4.x + r4.x, s.y + b4.y + r4.y,
                                    s.z + b4.z + r4.z, s.w + b4.w + r4.w);
}

// ---------------------------------------------------------------------------
// Generic fp32 GEMM (round-3-proven) — used only for pe_proj now.
template <int OBF>
__global__ __launch_bounds__(256) void gemm_kernel(
    const float* __restrict__ A, int lda, long sAo, long sAi,
    const float* __restrict__ B, int ldb, long sBo, long sBi,
    void* __restrict__ Cv, int ldc, long sCo, long sCi,
    const float* __restrict__ bias,
    const float* __restrict__ residual,
    int K, int act) {
  int z = blockIdx.z;
  int zo = z / HH, zi = z - zo * HH;
  A += (size_t)zo * sAo + (size_t)zi * sAi;
  B += (size_t)zo * sBo + (size_t)zi * sBi;
  size_t coff = (size_t)zo * sCo + (size_t)zi * sCi;

  __shared__ float As[16][68];
  __shared__ float Bs[16][68];
  int tid = threadIdx.x;
  int tx = tid & 15, ty = tid >> 4;
  int m0 = blockIdx.y * 64, n0 = blockIdx.x * 64;
  float acc[4][4] = {};
  int r = tid >> 2, kq = (tid & 3) * 4;

  for (int k0 = 0; k0 < K; k0 += 16) {
    float4 av = *(const float4*)(A + (size_t)(m0 + r) * lda + (k0 + kq));
    float4 bv = *(const float4*)(B + (size_t)(n0 + r) * ldb + (k0 + kq));
    As[kq + 0][r] = av.x; As[kq + 1][r] = av.y; As[kq + 2][r] = av.z; As[kq + 3][r] = av.w;
    Bs[kq + 0][r] = bv.x; Bs[kq + 1][r] = bv.y; Bs[kq + 2][r] = bv.z; Bs[kq + 3][r] = bv.w;
    __syncthreads();
#pragma unroll
    for (int kk = 0; kk < 16; kk++) {
      float4 a4 = *(const float4*)&As[kk][ty * 4];
      float4 b4 = *(const float4*)&Bs[kk][tx * 4];
      float ar[4] = {a4.x, a4.y, a4.z, a4.w};
      float br[4] = {b4.x, b4.y, b4.z, b4.w};
#pragma unroll
      for (int i2 = 0; i2 < 4; i2++)
#pragma unroll
        for (int j2 = 0; j2 < 4; j2++)
          acc[i2][j2] += ar[i2] * br[j2];
    }
    __syncthreads();
  }

  float bs[4] = {0.f, 0.f, 0.f, 0.f};
  if (bias) {
    float4 b4 = *(const float4*)&bias[n0 + tx * 4];
    bs[0] = b4.x; bs[1] = b4.y; bs[2] = b4.z; bs[3] = b4.w;
  }
  float* Cf = (float*)Cv;
  u16* Cb = (u16*)Cv;
#pragma unroll
  for (int i2 = 0; i2 < 4; i2++) {
    size_t m = (size_t)(m0 + ty * 4 + i2);
    float vout[4];
#pragma unroll
    for (int j2 = 0; j2 < 4; j2++) vout[j2] = acc[i2][j2] + bs[j2];
    if (residual) {
      const float4 r4 = *(const float4*)&residual[coff + m * ldc + n0 + tx * 4];
      vout[0] += r4.x; vout[1] += r4.y; vout[2] += r4.z; vout[3] += r4.w;
    }
    if (OBF) {
      u32 lo = (u32)f2bf(vout[0]) | ((u32)f2bf(vout[1]) << 16);
      u32 hi = (u32)f2bf(vout[2]) | ((u32)f2bf(vout[3]) << 16);
      *(uint2*)&Cb[coff + m * ldc + n0 + tx * 4] = make_uint2(lo, hi);
    } else {
      *(float4*)&Cf[coff + m * ldc + n0 + tx * 4] =
          make_float4(vout[0], vout[1], vout[2], vout[3]);
    }
  }
}

// ---------------------------------------------------------------------------
// qkv bf16 [L*B, 3D] -> qb,kb,vb bf16 [B,H,L,Dh] (4 elems/thread)
__global__ __launch_bounds__(256) void split_qkv5(const u16* __restrict__ qkvb,
                                                  u16* __restrict__ qb,
                                                  u16* __restrict__ kb,
                                                  u16* __restrict__ vb) {
  int idx = blockIdx.x * 256 + threadIdx.x;  // over 786,432
  int d4 = idx & 15;
  int l = (idx >> 4) & 511;
  int bh = idx >> 13;
  int b = bh / HH, h = bh - b * HH;
  size_t src = ((size_t)(l * BB + b)) * (3 * DD) + h * 64 + d4 * 4;
  uint2 qv = *(const uint2*)(qkvb + src);
  uint2 kv = *(const uint2*)(qkvb + src + DD);
  uint2 vv = *(const uint2*)(qkvb + src + 2 * DD);
  size_t dst = (size_t)idx * 4;
  *(uint2*)(qb + dst) = qv;
  *(uint2*)(kb + dst) = kv;
  *(uint2*)(vb + dst) = vv;
}

// ---------------------------------------------------------------------------
// Fused QK^T (fp32 math, bf16 inputs) + LDS-staged bf16 kp/qp gathers +
// scale + edge -> scores, plus per-(row, 64-col-tile) stats. (round-7 core)
__global__ __launch_bounds__(256) void qkt_gather_f32(
    const u16* __restrict__ qb, const u16* __restrict__ kb,
    const u16* __restrict__ kp, const u16* __restrict__ qp,
    const u8* __restrict__ bdT, const float* __restrict__ edge,
    float* __restrict__ eout, float* __restrict__ stats) {
  int bh = blockIdx.z, b = bh / HH;
  int i0 = blockIdx.y * 64, j0 = blockIdx.x * 64, jt = blockIdx.x;
  __shared__ float As[16][68];
  __shared__ float Bs[16][68];
  __shared__ u16 kpl[64][PP];
  __shared__ u16 qpl[64][PP];
  int tid = threadIdx.x;
  int tx = tid & 15, ty = tid >> 4;

  const u16* kpg = kp + (size_t)bh * (LL * PP);
  const u16* qpg = qp + (size_t)bh * (LL * PP);
  for (int c = tid; c < 1024; c += 256) {
    int row = c >> 4, ch = (c & 15) * 8;
    *(uint4*)&kpl[row][ch] = *(const uint4*)&kpg[(size_t)(j0 + row) * PP + ch];
    *(uint4*)&qpl[row][ch] = *(const uint4*)&qpg[(size_t)(i0 + row) * PP + ch];
  }

  float acc[4][4] = {};
  int r = tid >> 2, kq = (tid & 3) * 4;
  const u16* A = qb + (size_t)bh * (LL * DHH);
  const u16* B = kb + (size_t)bh * (LL * DHH);

  for (int k0 = 0; k0 < DHH; k0 += 16) {
    uint2 ar = *(const uint2*)(A + (size_t)(i0 + r) * DHH + (k0 + kq));
    uint2 br = *(const uint2*)(B + (size_t)(j0 + r) * DHH + (k0 + kq));
    As[kq + 0][r] = bf2f(ar.x); As[kq + 1][r] = bf2f(ar.x >> 16);
    As[kq + 2][r] = bf2f(ar.y); As[kq + 3][r] = bf2f(ar.y >> 16);
    Bs[kq + 0][r] = bf2f(br.x); Bs[kq + 1][r] = bf2f(br.x >> 16);
    Bs[kq + 2][r] = bf2f(br.y); Bs[kq + 3][r] = bf2f(br.y >> 16);
    __syncthreads();
#pragma unroll
    for (int kk = 0; kk < 16; kk++) {
      float4 a4 = *(const float4*)&As[kk][ty * 4];
      float4 b4 = *(const float4*)&Bs[kk][tx * 4];
      float ar2[4] = {a4.x, a4.y, a4.z, a4.w};
      float br2[4] = {b4.x, b4.y, b4.z, b4.w};
#pragma unroll
      for (int i2 = 0; i2 < 4; i2++)
#pragma unroll
        for (int j2 = 0; j2 < 4; j2++)
          acc[i2][j2] += ar2[i2] * br2[j2];
    }
    __syncthreads();
  }

  const u8* bd = bdT + (size_t)b * (LL * LL);
  const float* eb = edge + (size_t)bh * (LL * LL);
  float* ob = eout + (size_t)bh * (LL * LL);

  float rowm[4], rows[4];
#pragma unroll
  for (int i2 = 0; i2 < 4; i2++) {
    int row = i0 + ty * 4 + i2;
    int col0 = j0 + tx * 4;
    uchar4 p4 = *(const uchar4*)&bd[(size_t)row * LL + col0];
    float4 e4 = *(const float4*)&eb[(size_t)row * LL + col0];
    int pp[4] = {p4.x, p4.y, p4.z, p4.w};
    float ee[4] = {e4.x, e4.y, e4.z, e4.w};
    float sv[4];
#pragma unroll
    for (int j2 = 0; j2 < 4; j2++) {
      float gk = bf2f((u32)kpl[tx * 4 + j2][pp[j2]]);
      float gq = bf2f((u32)qpl[ty * 4 + i2][pp[j2]]);
      sv[j2] = (acc[i2][j2] + gk + gq) * 0.125f + ee[j2];
    }
    *(float4*)&ob[(size_t)row * LL + col0] =
        make_float4(sv[0], sv[1], sv[2], sv[3]);
    float m = fmaxf(fmaxf(sv[0], sv[1]), fmaxf(sv[2], sv[3]));
#pragma unroll
    for (int off = 1; off < 16; off <<= 1) m = fmaxf(m, __shfl_xor(m, off, 64));
    float ss = expf(sv[0] - m) + expf(sv[1] - m) + expf(sv[2] - m) + expf(sv[3] - m);
#pragma unroll
    for (int off = 1; off < 16; off <<= 1) ss += __shfl_xor(ss, off, 64);
    rowm[i2] = m;
    rows[i2] = ss;
  }
  if (tx == 0) {
#pragma unroll
    for (int i2 = 0; i2 < 4; i2++) {
      size_t si = ((size_t)bh * LL + i0 + ty * 4 + i2) * 16 + jt;
      stats[si] = rowm[i2];
      stats[si + 8] = rows[i2];
    }
  }
}

// ---------------------------------------------------------------------------
// Fused softmax + P@V using precomputed tile stats; V bf16; O bf16 [L,B,D].
__global__ __launch_bounds__(256) void softmax_pv_tiled(
    const float* __restrict__ scores, const u16* __restrict__ vb_,
    const float* __restrict__ stats, u16* __restrict__ olbd) {
  int bh = blockIdx.y;
  int i0 = blockIdx.x * 64;
  int b = bh / HH, h = bh - b * HH;
  __shared__ float Pt[64][66];
  __shared__ float Vt[64][72];
  __shared__ float smax[64], srs[64];
  int t = threadIdx.x;
  const float* sbase = scores + (size_t)bh * (LL * LL);

  if (t < 64) {
    size_t si = ((size_t)bh * LL + i0 + t) * 16;
    float m = stats[si];
#pragma unroll
    for (int j = 1; j < 8; j++) m = fmaxf(m, stats[si + j]);
    float s = 0.f;
#pragma unroll
    for (int j = 0; j < 8; j++) s += stats[si + 8 + j] * expf(stats[si + j] - m);
    smax[t] = m;
    srs[t] = 1.0f / s;
  }
  __syncthreads();

  float acc[4][4] = {};
  int tx = t & 15, ty = t >> 4;
  const u16* vb = vb_ + (size_t)bh * (LL * DHH);
  int c4 = (t & 15) * 4, r0 = t >> 4;

  for (int jt = 0; jt < 8; jt++) {
    int j0 = jt * 64;
#pragma unroll
    for (int rr = 0; rr < 4; rr++) {
      int r = r0 + rr * 16;
      float4 s4 = *(const float4*)(sbase + (size_t)(i0 + r) * LL + j0 + c4);
      float m = smax[r], rs = srs[r];
      Pt[c4 + 0][r] = expf(s4.x - m) * rs;
      Pt[c4 + 1][r] = expf(s4.y - m) * rs;
      Pt[c4 + 2][r] = expf(s4.z - m) * rs;
      Pt[c4 + 3][r] = expf(s4.w - m) * rs;
      uint2 v2 = *(const uint2*)(vb + (size_t)(j0 + r) * DHH + c4);
      Vt[r][c4 + 0] = bf2f(v2.x);
      Vt[r][c4 + 1] = bf2f(v2.x >> 16);
      Vt[r][c4 + 2] = bf2f(v2.y);
      Vt[r][c4 + 3] = bf2f(v2.y >> 16);
    }
    __syncthreads();
#pragma unroll 8
    for (int kk = 0; kk < 64; kk++) {
      float4 a4 = *(const float4*)&Pt[kk][ty * 4];
      float4 b4 = *(const float4*)&Vt[kk][tx * 4];
      float ar[4] = {a4.x, a4.y, a4.z, a4.w};
      float br[4] = {b4.x, b4.y, b4.z, b4.w};
#pragma unroll
      for (int i2 = 0; i2 < 4; i2++)
#pragma unroll
        for (int j2 = 0; j2 < 4; j2++)
          acc[i2][j2] += ar[i2] * br[j2];
    }
    __syncthreads();
  }

#pragma unroll
  for (int i2 = 0; i2 < 4; i2++) {
    int i = i0 + ty * 4 + i2;
    u32 lo = (u32)f2bf(acc[i2][0]) | ((u32)f2bf(acc[i2][1]) << 16);
    u32 hi = (u32)f2bf(acc[i2][2]) | ((u32)f2bf(acc[i2][3]) << 16);
    *(uint2*)&olbd[((size_t)i * BB + b) * DD + h * 64 + tx * 4] =
        make_uint2(lo, hi);
  }
}

// ---------------------------------------------------------------------------
extern "C" void kernel_launch(void* const* d_in, const int* in_sizes, int n_in,
                              void* d_out, int out_size, void* d_ws, size_t ws_size,
                              hipStream_t stream) {
  const float* x      = (const float*)d_in[0];
  const float* edge   = (const float*)d_in[1];
  const int*   bdist  = (const int*)d_in[2];
  const float* W_in   = (const float*)d_in[3];
  const float* b_in   = (const float*)d_in[4];
  const float* pe_emb = (const float*)d_in[5];
  const float* W_out  = (const float*)d_in[6];
  const float* b_out  = (const float*)d_in[7];
  const float* W1     = (const float*)d_in[8];
  const float* b1     = (const float*)d_in[9];
  const float* W2     = (const float*)d_in[10];
  const float* b2     = (const float*)d_in[11];
  const float* ln1w   = (const float*)d_in[12];
  const float* ln1b   = (const float*)d_in[13];
  const float* ln2w   = (const float*)d_in[14];
  const float* ln2b   = (const float*)d_in[15];

  float* xout = (float*)d_out;                 // [L,B,D]
  float* eout = xout + (size_t)LL * BB * DD;   // [B*H,L,L] == final scores

  // Workspace layout (float units). Max used: ~37.35M floats = 149.4 MB.
  float* ws = (float*)d_ws;
  u16*   xnb    = (u16*)(ws + 0);          // [4096,768] bf16
  u16*   qkvb   = (u16*)(ws + 1600000);    // [4096,2304] bf16, ends 6,318,592
  u16*   olbdb  = (u16*)(ws + 1600000);    // bf16 O (reuse after split)
  u16*   ff1b   = (u16*)(ws + 3200000);    // [4096,3072] bf16, ends 9,491,456
  float* x1     = ws + 11100000;           // ends 14,245,728
  float* pe     = ws + 14300000;           // [128,2304] fp32, ends 14,594,912
  float* part   = ws + 14600000;           // split-K partials, <=4x3,145,728
  u16*   vb     = (u16*)(ws + 21000000);   // ends 22,572,864
  float* stats  = ws + 22600000;           // [96,512,16], ends 23,386,432
  u8*    bdT    = (u8*)(ws + 23400000);    // [8,512,512] u8, ends 23,924,288
  u16*   kpb    = (u16*)(ws + 24000000);   // [96,512,128] bf16, ends 27,145,728
  u16*   qpb    = (u16*)(ws + 27200000);   // ends 30,345,728
  u16*   W1b    = (u16*)(ws + 30400000);   // ends 31,579,648
  u16*   W2b    = (u16*)(ws + 31600000);   // ends 32,779,648
  u16*   W_inb  = (u16*)(ws + 32800000);   // ends 33,684,736
  u16*   W_outb = (u16*)(ws + 33700000);   // ends 33,994,912
  u16*   qb     = (u16*)(ws + 34000000);   // ends 35,572,864
  u16*   kb     = (u16*)(ws + 35600000);   // ends 37,172,864
  u16*   peb    = (u16*)(ws + 37200000);   // [128,2304] bf16, ends 37,347,456

  // 0) dtype conversions + bdist transpose
  f2b_kernel<<<1728, 256, 0, stream>>>(W_in, W_inb);
  f2b_kernel<<<576, 256, 0, stream>>>(W_out, W_outb);
  f2b_kernel<<<2304, 256, 0, stream>>>(W1, W1b);
  f2b_kernel<<<2304, 256, 0, stream>>>(W2, W2b);
  bdist_t<<<8192, 256, 0, stream>>>(bdist, bdT);
  // 1) LN1 -> bf16
  ln_bf16<<<4096, 256, 0, stream>>>(x, ln1w, ln1b, xnb);
  // 2) qkv = xn @ W_in^T + b_in  (MFMA, bf16 out)
  gemm_mfma<0, 1, 0><<<dim3(18, 32), 256, 0, stream>>>(
      xnb, DD, W_inb, DD, qkvb, 3 * DD, b_in, nullptr, DD);
  // 3) pe_proj fp32 + bf16 copy
  gemm_kernel<0><<<dim3(36, 2, 1), 256, 0, stream>>>(
      pe_emb, DD, 0, 0, W_in, DD, 0, 0, pe, 3 * DD, 0, 0, b_in, nullptr, DD, 0);
  f2b_kernel<<<288, 256, 0, stream>>>(pe, peb);
  // 4) split -> qb,kb,vb bf16
  split_qkv5<<<3072, 256, 0, stream>>>(qkvb, qb, kb, vb);
  // 5) kp = k @ pe_q^T per head (batched MFMA)
  gemm_mfma_b<<<dim3(1, 4, 96), 256, 0, stream>>>(
      kb, DHH, (long)LL * DHH, peb, 3 * DD, 64, kpb, PP, (long)LL * PP, DHH);
  // 6) qp = q @ pe_k^T per head
  gemm_mfma_b<<<dim3(1, 4, 96), 256, 0, stream>>>(
      qb, DHH, (long)LL * DHH, peb + DD, 3 * DD, 64, qpb, PP, (long)LL * PP, DHH);
  // 7) fused QK^T + LDS gathers + edge -> eout, + softmax tile stats
  qkt_gather_f32<<<dim3(8, 8, 96), 256, 0, stream>>>(qb, kb, kpb, qpb, bdT,
                                                     edge, eout, stats);
  // 8) fused softmax + PV -> olbd bf16 [L,B,D]
  softmax_pv_tiled<<<dim3(8, 96), 256, 0, stream>>>(eout, vb, stats, olbdb);
  // 9) x1 = O @ W_out^T + b_out + x   (split-K=2 + combine)
  gemm_mfma_part<<<dim3(6, 32, 2), 256, 0, stream>>>(
      olbdb, DD, W_outb, DD, part, DD, 3145728L, DD / 2);
  combine_k<2><<<3072, 256, 0, stream>>>(part, b_out, x, x1);
  // 10) LN2 -> bf16
  ln_bf16<<<4096, 256, 0, stream>>>(x1, ln2w, ln2b, xnb);
  // 11) ff1 = gelu(xn @ W1^T + b1) (bf16 out)
  gemm_mfma<1, 1, 0><<<dim3(24, 32), 256, 0, stream>>>(
      xnb, DD, W1b, DD, ff1b, 4 * DD, b1, nullptr, DD);
  // 12) x_out = ff1 @ W2^T + b2 + x1  (split-K=4 + combine)
  gemm_mfma_part<<<dim3(6, 32, 4), 256, 0, stream>>>(
      ff1b, 4 * DD, W2b, 4 * DD, part, DD, 3145728L, DD);
  combine_k<4><<<3072, 256, 0, stream>>>(part, b2, x1, xout);
}

// Round 13
// 398.430 us; speedup vs baseline: 1.4113x; 1.0451x over previous
//
#include <hip/hip_runtime.h>
#include <hip/hip_bf16.h>
#include <math.h>

// Problem constants
#define LL 512
#define BB 8
#define DD 768
#define HH 12
#define DHH 64
#define PP 128

typedef unsigned char u8;
typedef unsigned short u16;
typedef unsigned int u32;
typedef __attribute__((ext_vector_type(8))) short bf16x8;
typedef __attribute__((ext_vector_type(4))) float f32x4;

__device__ __forceinline__ u16 f2bf(float f) {
  u32 u = __float_as_uint(f);
  u32 r = (u + 0x7fffu + ((u >> 16) & 1u)) >> 16;
  return (u16)r;
}
__device__ __forceinline__ float bf2f(u32 u) {
  return __uint_as_float((u & 0xffffu) << 16);
}

#define GLDS(g, l)                                                             \
  __builtin_amdgcn_global_load_lds(                                            \
      (const __attribute__((address_space(1))) void*)(g),                      \
      (__attribute__((address_space(3))) void*)(l), 16, 0, 0)

// ---------------------------------------------------------------------------
__device__ __forceinline__ void block_reduce2(float& a, float& b, float* sbuf) {
#pragma unroll
  for (int off = 32; off > 0; off >>= 1) {
    a += __shfl_down(a, off, 64);
    b += __shfl_down(b, off, 64);
  }
  int wid = threadIdx.x >> 6, lane = threadIdx.x & 63;
  __syncthreads();
  if (lane == 0) { sbuf[wid] = a; sbuf[4 + wid] = b; }
  __syncthreads();
  a = sbuf[0] + sbuf[1] + sbuf[2] + sbuf[3];
  b = sbuf[4] + sbuf[5] + sbuf[6] + sbuf[7];
}

// LayerNorm over D=768, one block per row, bf16 output
__global__ __launch_bounds__(256) void ln_bf16(const float* __restrict__ x,
                                               const float* __restrict__ w,
                                               const float* __restrict__ bb,
                                               u16* __restrict__ out) {
  __shared__ float sbuf[8];
  size_t row = blockIdx.x;
  const float* xr = x + row * DD;
  int t = threadIdx.x;
  float v0 = xr[t], v1 = xr[t + 256], v2 = xr[t + 512];
  float s = v0 + v1 + v2;
  float ss = v0 * v0 + v1 * v1 + v2 * v2;
  block_reduce2(s, ss, sbuf);
  float mu = s * (1.0f / DD);
  float var = ss * (1.0f / DD) - mu * mu;
  float r = rsqrtf(var + 1e-5f);
  u16* orow = out + row * DD;
  orow[t]       = f2bf((v0 - mu) * r * w[t]       + bb[t]);
  orow[t + 256] = f2bf((v1 - mu) * r * w[t + 256] + bb[t + 256]);
  orow[t + 512] = f2bf((v2 - mu) * r * w[t + 512] + bb[t + 512]);
}

// fp32 -> bf16, 4 elements/thread
__global__ __launch_bounds__(256) void f2b_kernel(const float* __restrict__ in,
                                                  u16* __restrict__ out) {
  int idx = blockIdx.x * 256 + threadIdx.x;
  float4 v = *(const float4*)(in + (size_t)idx * 4);
  u32 lo = (u32)f2bf(v.x) | ((u32)f2bf(v.y) << 16);
  u32 hi = (u32)f2bf(v.z) | ((u32)f2bf(v.w) << 16);
  *(uint2*)(out + (size_t)idx * 4) = make_uint2(lo, hi);
}

// bdist [L,L,B] int32 -> bdistT [B,L,L] u8 (values < 128)
__global__ __launch_bounds__(256) void bdist_t(const int* __restrict__ bd,
                                               u8* __restrict__ out) {
  int t = blockIdx.x * 256 + threadIdx.x;  // 2,097,152 items, read-coalesced
  int b = t & 7, jj = (t >> 3) & 511, ii = t >> 12;
  out[((size_t)b << 18) + ((size_t)ii << 9) + jj] = (u8)bd[t];
}

// ---------------------------------------------------------------------------
// bf16 MFMA GEMM (round-3-proven): C = act(A * B^T + bias) [+ residual].
// 128x128 tile, BK=32, 4 waves 2x2. Requires 128 | grid-covered M,N; 32 | K.
template <int ACT, int OBF, int RES>
__global__ __launch_bounds__(256) void gemm_mfma(
    const u16* __restrict__ A, int lda, const u16* __restrict__ B, int ldb,
    void* __restrict__ Cv, int ldc, const float* __restrict__ bias,
    const float* __restrict__ residual, int K) {
  __shared__ __align__(16) u16 Asl[128 * 32];
  __shared__ __align__(16) u16 Bsl[128 * 32];
  int t = threadIdx.x;
  int m0 = blockIdx.y * 128, n0 = blockIdx.x * 128;
  int lane = t & 63, w = t >> 6;
  int wr = w >> 1, wc = w & 1;
  int lr = lane & 15, lg = lane >> 4;

  f32x4 acc[4][4] = {};

  const u16* Ag0 = A + (size_t)(m0 + (t >> 2)) * lda + (t & 3) * 8;
  const u16* Ag1 = A + (size_t)(m0 + 64 + (t >> 2)) * lda + (t & 3) * 8;
  const u16* Bg0 = B + (size_t)(n0 + (t >> 2)) * ldb + (t & 3) * 8;
  const u16* Bg1 = B + (size_t)(n0 + 64 + (t >> 2)) * ldb + (t & 3) * 8;
  u16* Ad0 = &Asl[t * 8];
  u16* Ad1 = &Asl[2048 + t * 8];
  u16* Bd0 = &Bsl[t * 8];
  u16* Bd1 = &Bsl[2048 + t * 8];

  for (int k0 = 0; k0 < K; k0 += 32) {
    GLDS(Ag0 + k0, Ad0);
    GLDS(Ag1 + k0, Ad1);
    GLDS(Bg0 + k0, Bd0);
    GLDS(Bg1 + k0, Bd1);
    __syncthreads();
    bf16x8 a[4], b[4];
#pragma unroll
    for (int i = 0; i < 4; i++)
      a[i] = *(const bf16x8*)&Asl[(wr * 64 + i * 16 + lr) * 32 + lg * 8];
#pragma unroll
    for (int j = 0; j < 4; j++)
      b[j] = *(const bf16x8*)&Bsl[(wc * 64 + j * 16 + lr) * 32 + lg * 8];
#pragma unroll
    for (int i = 0; i < 4; i++)
#pragma unroll
      for (int j = 0; j < 4; j++)
        asm volatile("v_mfma_f32_16x16x32_bf16 %0, %1, %2, %0"
                     : "+v"(acc[i][j])
                     : "v"(a[i]), "v"(b[j]));
    __syncthreads();
  }
  asm volatile("s_nop 7\n\ts_nop 7" ::);

  float* Cf = (float*)Cv;
  u16* Cb = (u16*)Cv;
#pragma unroll
  for (int i = 0; i < 4; i++) {
#pragma unroll
    for (int r = 0; r < 4; r++) {
      int row = m0 + wr * 64 + i * 16 + lg * 4 + r;
#pragma unroll
      for (int j = 0; j < 4; j++) {
        int col = n0 + wc * 64 + j * 16 + lr;
        float vv = acc[i][j][r];
        if (bias) vv += bias[col];
        if (ACT) vv = 0.5f * vv * (1.0f + erff(vv * 0.70710678118654752f));
        if (RES) vv += residual[(size_t)row * ldc + col];
        if (OBF) Cb[(size_t)row * ldc + col] = f2bf(vv);
        else     Cf[(size_t)row * ldc + col] = vv;
      }
    }
  }
}

// ---------------------------------------------------------------------------
// Batched variant (round-9/11-proven core): A += z*sAz;
// B += (BMOD ? z%HH : z)*sBz. bf16 out, no bias/act/res.
template <int BMOD>
__global__ __launch_bounds__(256) void gemm_mfma_b(
    const u16* __restrict__ A, int lda, long sAz,
    const u16* __restrict__ B, int ldb, long sBz,
    u16* __restrict__ Cb, int ldc, long sCz, int K) {
  __shared__ __align__(16) u16 Asl[128 * 32];
  __shared__ __align__(16) u16 Bsl[128 * 32];
  int z = blockIdx.z;
  A += (size_t)z * sAz;
  B += (size_t)(BMOD ? (z % HH) : z) * sBz;
  Cb += (size_t)z * sCz;
  int t = threadIdx.x;
  int m0 = blockIdx.y * 128, n0 = blockIdx.x * 128;
  int lane = t & 63, w = t >> 6;
  int wr = w >> 1, wc = w & 1;
  int lr = lane & 15, lg = lane >> 4;

  f32x4 acc[4][4] = {};

  const u16* Ag0 = A + (size_t)(m0 + (t >> 2)) * lda + (t & 3) * 8;
  const u16* Ag1 = A + (size_t)(m0 + 64 + (t >> 2)) * lda + (t & 3) * 8;
  const u16* Bg0 = B + (size_t)(n0 + (t >> 2)) * ldb + (t & 3) * 8;
  const u16* Bg1 = B + (size_t)(n0 + 64 + (t >> 2)) * ldb + (t & 3) * 8;
  u16* Ad0 = &Asl[t * 8];
  u16* Ad1 = &Asl[2048 + t * 8];
  u16* Bd0 = &Bsl[t * 8];
  u16* Bd1 = &Bsl[2048 + t * 8];

  for (int k0 = 0; k0 < K; k0 += 32) {
    GLDS(Ag0 + k0, Ad0);
    GLDS(Ag1 + k0, Ad1);
    GLDS(Bg0 + k0, Bd0);
    GLDS(Bg1 + k0, Bd1);
    __syncthreads();
    bf16x8 a[4], b[4];
#pragma unroll
    for (int i = 0; i < 4; i++)
      a[i] = *(const bf16x8*)&Asl[(wr * 64 + i * 16 + lr) * 32 + lg * 8];
#pragma unroll
    for (int j = 0; j < 4; j++)
      b[j] = *(const bf16x8*)&Bsl[(wc * 64 + j * 16 + lr) * 32 + lg * 8];
#pragma unroll
    for (int i = 0; i < 4; i++)
#pragma unroll
      for (int j = 0; j < 4; j++)
        asm volatile("v_mfma_f32_16x16x32_bf16 %0, %1, %2, %0"
                     : "+v"(acc[i][j])
                     : "v"(a[i]), "v"(b[j]));
    __syncthreads();
  }
  asm volatile("s_nop 7\n\ts_nop 7" ::);

#pragma unroll
  for (int i = 0; i < 4; i++) {
#pragma unroll
    for (int r = 0; r < 4; r++) {
      int row = m0 + wr * 64 + i * 16 + lg * 4 + r;
#pragma unroll
      for (int j = 0; j < 4; j++) {
        int col = n0 + wc * 64 + j * 16 + lr;
        Cb[(size_t)row * ldc + col] = f2bf(acc[i][j][r]);
      }
    }
  }
}

// ---------------------------------------------------------------------------
// Split-K partial MFMA GEMM (round-11-proven).
__global__ __launch_bounds__(256) void gemm_mfma_part(
    const u16* __restrict__ A, int lda, const u16* __restrict__ B, int ldb,
    float* __restrict__ Cf, int ldc, long partStride, int Kper) {
  __shared__ __align__(16) u16 Asl[128 * 32];
  __shared__ __align__(16) u16 Bsl[128 * 32];
  int z = blockIdx.z;
  A += (size_t)z * Kper;
  B += (size_t)z * Kper;
  Cf += (size_t)z * partStride;
  int t = threadIdx.x;
  int m0 = blockIdx.y * 128, n0 = blockIdx.x * 128;
  int lane = t & 63, w = t >> 6;
  int wr = w >> 1, wc = w & 1;
  int lr = lane & 15, lg = lane >> 4;

  f32x4 acc[4][4] = {};

  const u16* Ag0 = A + (size_t)(m0 + (t >> 2)) * lda + (t & 3) * 8;
  const u16* Ag1 = A + (size_t)(m0 + 64 + (t >> 2)) * lda + (t & 3) * 8;
  const u16* Bg0 = B + (size_t)(n0 + (t >> 2)) * ldb + (t & 3) * 8;
  const u16* Bg1 = B + (size_t)(n0 + 64 + (t >> 2)) * ldb + (t & 3) * 8;
  u16* Ad0 = &Asl[t * 8];
  u16* Ad1 = &Asl[2048 + t * 8];
  u16* Bd0 = &Bsl[t * 8];
  u16* Bd1 = &Bsl[2048 + t * 8];

  for (int k0 = 0; k0 < Kper; k0 += 32) {
    GLDS(Ag0 + k0, Ad0);
    GLDS(Ag1 + k0, Ad1);
    GLDS(Bg0 + k0, Bd0);
    GLDS(Bg1 + k0, Bd1);
    __syncthreads();
    bf16x8 a[4], b[4];
#pragma unroll
    for (int i = 0; i < 4; i++)
      a[i] = *(const bf16x8*)&Asl[(wr * 64 + i * 16 + lr) * 32 + lg * 8];
#pragma unroll
    for (int j = 0; j < 4; j++)
      b[j] = *(const bf16x8*)&Bsl[(wc * 64 + j * 16 + lr) * 32 + lg * 8];
#pragma unroll
    for (int i = 0; i < 4; i++)
#pragma unroll
      for (int j = 0; j < 4; j++)
        asm volatile("v_mfma_f32_16x16x32_bf16 %0, %1, %2, %0"
                     : "+v"(acc[i][j])
                     : "v"(a[i]), "v"(b[j]));
    __syncthreads();
  }
  asm volatile("s_nop 7\n\ts_nop 7" ::);

#pragma unroll
  for (int i = 0; i < 4; i++) {
#pragma unroll
    for (int r = 0; r < 4; r++) {
      int row = m0 + wr * 64 + i * 16 + lg * 4 + r;
#pragma unroll
      for (int j = 0; j < 4; j++) {
        int col = n0 + wc * 64 + j * 16 + lr;
        Cf[(size_t)row * ldc + col] = acc[i][j][r];
      }
    }
  }
}

// Combine NS split-K partials: out = sum(parts) + bias + res. 4 elems/thread.
template <int NS>
__global__ __launch_bounds__(256) void combine_k(const float* __restrict__ p,
                                                 const float* __restrict__ bias,
                                                 const float* __restrict__ res,
                                                 float* __restrict__ out) {
  int idx = blockIdx.x * 256 + threadIdx.x;  // over 786,432
  size_t e = (size_t)idx * 4;
  float4 s = *(const float4*)(p + e);
#pragma unroll
  for (int z = 1; z < NS; z++) {
    float4 t2 = *(const float4*)(p + (size_t)z * 3145728 + e);
    s.x += t2.x; s.y += t2.y; s.z += t2.z; s.w += t2.w;
  }
  int col = (int)(e % DD);
  float4 b4 = *(const float4*)(bias + col);
  float4 r4 = *(const float4*)(res + e);
  *(float4*)(out + e) = make_float4(s.x + b4.x + r4.x, s.y + b4.y + r4.y,
                                    s.z + b4.z + r4.z, s.w + b4.w + r4.w);
}

// ---------------------------------------------------------------------------
// Generic fp32 GEMM (round-3-proven) — used only for pe_proj now.
template <int OBF>
__global__ __launch_bounds__(256) void gemm_kernel(
    const float* __restrict__ A, int lda, long sAo, long sAi,
    const float* __restrict__ B, int ldb, long sBo, long sBi,
    void* __restrict__ Cv, int ldc, long sCo, long sCi,
    const float* __restrict__ bias,
    const float* __restrict__ residual,
    int K, int act) {
  int z = blockIdx.z;
  int zo = z / HH, zi = z - zo * HH;
  A += (size_t)zo * sAo + (size_t)zi * sAi;
  B += (size_t)zo * sBo + (size_t)zi * sBi;
  size_t coff = (size_t)zo * sCo + (size_t)zi * sCi;

  __shared__ float As[16][68];
  __shared__ float Bs[16][68];
  int tid = threadIdx.x;
  int tx = tid & 15, ty = tid >> 4;
  int m0 = blockIdx.y * 64, n0 = blockIdx.x * 64;
  float acc[4][4] = {};
  int r = tid >> 2, kq = (tid & 3) * 4;

  for (int k0 = 0; k0 < K; k0 += 16) {
    float4 av = *(const float4*)(A + (size_t)(m0 + r) * lda + (k0 + kq));
    float4 bv = *(const float4*)(B + (size_t)(n0 + r) * ldb + (k0 + kq));
    As[kq + 0][r] = av.x; As[kq + 1][r] = av.y; As[kq + 2][r] = av.z; As[kq + 3][r] = av.w;
    Bs[kq + 0][r] = bv.x; Bs[kq + 1][r] = bv.y; Bs[kq + 2][r] = bv.z; Bs[kq + 3][r] = bv.w;
    __syncthreads();
#pragma unroll
    for (int kk = 0; kk < 16; kk++) {
      float4 a4 = *(const float4*)&As[kk][ty * 4];
      float4 b4 = *(const float4*)&Bs[kk][tx * 4];
      float ar[4] = {a4.x, a4.y, a4.z, a4.w};
      float br[4] = {b4.x, b4.y, b4.z, b4.w};
#pragma unroll
      for (int i2 = 0; i2 < 4; i2++)
#pragma unroll
        for (int j2 = 0; j2 < 4; j2++)
          acc[i2][j2] += ar[i2] * br[j2];
    }
    __syncthreads();
  }

  float bs[4] = {0.f, 0.f, 0.f, 0.f};
  if (bias) {
    float4 b4 = *(const float4*)&bias[n0 + tx * 4];
    bs[0] = b4.x; bs[1] = b4.y; bs[2] = b4.z; bs[3] = b4.w;
  }
  float* Cf = (float*)Cv;
  u16* Cb = (u16*)Cv;
#pragma unroll
  for (int i2 = 0; i2 < 4; i2++) {
    size_t m = (size_t)(m0 + ty * 4 + i2);
    float vout[4];
#pragma unroll
    for (int j2 = 0; j2 < 4; j2++) vout[j2] = acc[i2][j2] + bs[j2];
    if (residual) {
      const float4 r4 = *(const float4*)&residual[coff + m * ldc + n0 + tx * 4];
      vout[0] += r4.x; vout[1] += r4.y; vout[2] += r4.z; vout[3] += r4.w;
    }
    if (OBF) {
      u32 lo = (u32)f2bf(vout[0]) | ((u32)f2bf(vout[1]) << 16);
      u32 hi = (u32)f2bf(vout[2]) | ((u32)f2bf(vout[3]) << 16);
      *(uint2*)&Cb[coff + m * ldc + n0 + tx * 4] = make_uint2(lo, hi);
    } else {
      *(float4*)&Cf[coff + m * ldc + n0 + tx * 4] =
          make_float4(vout[0], vout[1], vout[2], vout[3]);
    }
  }
}

// ---------------------------------------------------------------------------
// qkv bf16 [L*B, 3D] -> qb,kb,vb bf16 [B,H,L,Dh] (4 elems/thread)
__global__ __launch_bounds__(256) void split_qkv5(const u16* __restrict__ qkvb,
                                                  u16* __restrict__ qb,
                                                  u16* __restrict__ kb,
                                                  u16* __restrict__ vb) {
  int idx = blockIdx.x * 256 + threadIdx.x;  // over 786,432
  int d4 = idx & 15;
  int l = (idx >> 4) & 511;
  int bh = idx >> 13;
  int b = bh / HH, h = bh - b * HH;
  size_t src = ((size_t)(l * BB + b)) * (3 * DD) + h * 64 + d4 * 4;
  uint2 qv = *(const uint2*)(qkvb + src);
  uint2 kv = *(const uint2*)(qkvb + src + DD);
  uint2 vv = *(const uint2*)(qkvb + src + 2 * DD);
  size_t dst = (size_t)idx * 4;
  *(uint2*)(qb + dst) = qv;
  *(uint2*)(kb + dst) = kv;
  *(uint2*)(vb + dst) = vv;
}

// ---------------------------------------------------------------------------
// Streaming gather: eout = (t + gathers)*inv + edge, + per-tile stats.
// t read as bf16 from tb. LDS = kpl/qpl only (32KB -> 5 blocks/CU).
// Grid (8,8,96); epilogue logic identical to round-11-proven qkt_gather_f32.
__global__ __launch_bounds__(256) void gather_scale2(
    const u16* __restrict__ tb,
    const u16* __restrict__ kp, const u16* __restrict__ qp,
    const u8* __restrict__ bdT, const float* __restrict__ edge,
    float* __restrict__ eout, float* __restrict__ stats) {
  int bh = blockIdx.z, b = bh / HH;
  int i0 = blockIdx.y * 64, j0 = blockIdx.x * 64, jt = blockIdx.x;
  __shared__ u16 kpl[64][PP];
  __shared__ u16 qpl[64][PP];
  int tid = threadIdx.x;
  int tx = tid & 15, ty = tid >> 4;

  const u16* kpg = kp + (size_t)bh * (LL * PP);
  const u16* qpg = qp + (size_t)bh * (LL * PP);
  for (int c = tid; c < 1024; c += 256) {
    int row = c >> 4, ch = (c & 15) * 8;
    *(uint4*)&kpl[row][ch] = *(const uint4*)&kpg[(size_t)(j0 + row) * PP + ch];
    *(uint4*)&qpl[row][ch] = *(const uint4*)&qpg[(size_t)(i0 + row) * PP + ch];
  }
  __syncthreads();

  const u8* bd = bdT + (size_t)b * (LL * LL);
  const float* eb = edge + (size_t)bh * (LL * LL);
  const u16* tbb = tb + (size_t)bh * (LL * LL);
  float* ob = eout + (size_t)bh * (LL * LL);

  float rowm[4], rows[4];
#pragma unroll
  for (int i2 = 0; i2 < 4; i2++) {
    int row = i0 + ty * 4 + i2;
    int col0 = j0 + tx * 4;
    uchar4 p4 = *(const uchar4*)&bd[(size_t)row * LL + col0];
    float4 e4 = *(const float4*)&eb[(size_t)row * LL + col0];
    uint2 t2 = *(const uint2*)&tbb[(size_t)row * LL + col0];
    float tv[4] = {bf2f(t2.x), bf2f(t2.x >> 16), bf2f(t2.y), bf2f(t2.y >> 16)};
    int pp[4] = {p4.x, p4.y, p4.z, p4.w};
    float ee[4] = {e4.x, e4.y, e4.z, e4.w};
    float sv[4];
#pragma unroll
    for (int j2 = 0; j2 < 4; j2++) {
      float gk = bf2f((u32)kpl[tx * 4 + j2][pp[j2]]);
      float gq = bf2f((u32)qpl[ty * 4 + i2][pp[j2]]);
      sv[j2] = (tv[j2] + gk + gq) * 0.125f + ee[j2];
    }
    *(float4*)&ob[(size_t)row * LL + col0] =
        make_float4(sv[0], sv[1], sv[2], sv[3]);
    float m = fmaxf(fmaxf(sv[0], sv[1]), fmaxf(sv[2], sv[3]));
#pragma unroll
    for (int off = 1; off < 16; off <<= 1) m = fmaxf(m, __shfl_xor(m, off, 64));
    float ss = expf(sv[0] - m) + expf(sv[1] - m) + expf(sv[2] - m) + expf(sv[3] - m);
#pragma unroll
    for (int off = 1; off < 16; off <<= 1) ss += __shfl_xor(ss, off, 64);
    rowm[i2] = m;
    rows[i2] = ss;
  }
  if (tx == 0) {
#pragma unroll
    for (int i2 = 0; i2 < 4; i2++) {
      size_t si = ((size_t)bh * LL + i0 + ty * 4 + i2) * 16 + jt;
      stats[si] = rowm[i2];
      stats[si + 8] = rows[i2];
    }
  }
}

// ---------------------------------------------------------------------------
// Fused softmax + P@V using precomputed tile stats; V bf16; O bf16 [L,B,D].
__global__ __launch_bounds__(256) void softmax_pv_tiled(
    const float* __restrict__ scores, const u16* __restrict__ vb_,
    const float* __restrict__ stats, u16* __restrict__ olbd) {
  int bh = blockIdx.y;
  int i0 = blockIdx.x * 64;
  int b = bh / HH, h = bh - b * HH;
  __shared__ float Pt[64][66];
  __shared__ float Vt[64][72];
  __shared__ float smax[64], srs[64];
  int t = threadIdx.x;
  const float* sbase = scores + (size_t)bh * (LL * LL);

  if (t < 64) {
    size_t si = ((size_t)bh * LL + i0 + t) * 16;
    float m = stats[si];
#pragma unroll
    for (int j = 1; j < 8; j++) m = fmaxf(m, stats[si + j]);
    float s = 0.f;
#pragma unroll
    for (int j = 0; j < 8; j++) s += stats[si + 8 + j] * expf(stats[si + j] - m);
    smax[t] = m;
    srs[t] = 1.0f / s;
  }
  __syncthreads();

  float acc[4][4] = {};
  int tx = t & 15, ty = t >> 4;
  const u16* vb = vb_ + (size_t)bh * (LL * DHH);
  int c4 = (t & 15) * 4, r0 = t >> 4;

  for (int jt = 0; jt < 8; jt++) {
    int j0 = jt * 64;
#pragma unroll
    for (int rr = 0; rr < 4; rr++) {
      int r = r0 + rr * 16;
      float4 s4 = *(const float4*)(sbase + (size_t)(i0 + r) * LL + j0 + c4);
      float m = smax[r], rs = srs[r];
      Pt[c4 + 0][r] = expf(s4.x - m) * rs;
      Pt[c4 + 1][r] = expf(s4.y - m) * rs;
      Pt[c4 + 2][r] = expf(s4.z - m) * rs;
      Pt[c4 + 3][r] = expf(s4.w - m) * rs;
      uint2 v2 = *(const uint2*)(vb + (size_t)(j0 + r) * DHH + c4);
      Vt[r][c4 + 0] = bf2f(v2.x);
      Vt[r][c4 + 1] = bf2f(v2.x >> 16);
      Vt[r][c4 + 2] = bf2f(v2.y);
      Vt[r][c4 + 3] = bf2f(v2.y >> 16);
    }
    __syncthreads();
#pragma unroll 8
    for (int kk = 0; kk < 64; kk++) {
      float4 a4 = *(const float4*)&Pt[kk][ty * 4];
      float4 b4 = *(const float4*)&Vt[kk][tx * 4];
      float ar[4] = {a4.x, a4.y, a4.z, a4.w};
      float br[4] = {b4.x, b4.y, b4.z, b4.w};
#pragma unroll
      for (int i2 = 0; i2 < 4; i2++)
#pragma unroll
        for (int j2 = 0; j2 < 4; j2++)
          acc[i2][j2] += ar[i2] * br[j2];
    }
    __syncthreads();
  }

#pragma unroll
  for (int i2 = 0; i2 < 4; i2++) {
    int i = i0 + ty * 4 + i2;
    u32 lo = (u32)f2bf(acc[i2][0]) | ((u32)f2bf(acc[i2][1]) << 16);
    u32 hi = (u32)f2bf(acc[i2][2]) | ((u32)f2bf(acc[i2][3]) << 16);
    *(uint2*)&olbd[((size_t)i * BB + b) * DD + h * 64 + tx * 4] =
        make_uint2(lo, hi);
  }
}

// ---------------------------------------------------------------------------
extern "C" void kernel_launch(void* const* d_in, const int* in_sizes, int n_in,
                              void* d_out, int out_size, void* d_ws, size_t ws_size,
                              hipStream_t stream) {
  const float* x      = (const float*)d_in[0];
  const float* edge   = (const float*)d_in[1];
  const int*   bdist  = (const int*)d_in[2];
  const float* W_in   = (const float*)d_in[3];
  const float* b_in   = (const float*)d_in[4];
  const float* pe_emb = (const float*)d_in[5];
  const float* W_out  = (const float*)d_in[6];
  const float* b_out  = (const float*)d_in[7];
  const float* W1     = (const float*)d_in[8];
  const float* b1     = (const float*)d_in[9];
  const float* W2     = (const float*)d_in[10];
  const float* b2     = (const float*)d_in[11];
  const float* ln1w   = (const float*)d_in[12];
  const float* ln1b   = (const float*)d_in[13];
  const float* ln2w   = (const float*)d_in[14];
  const float* ln2b   = (const float*)d_in[15];

  float* xout = (float*)d_out;                 // [L,B,D]
  float* eout = xout + (size_t)LL * BB * DD;   // [B*H,L,L] == final scores

  // Workspace layout (float units). Max used: ~37.35M floats = 149.4 MB.
  float* ws = (float*)d_ws;
  u16*   xnb    = (u16*)(ws + 0);          // [4096,768] bf16
  u16*   qkvb   = (u16*)(ws + 1600000);    // [4096,2304] bf16, ends 6,318,592
  u16*   tb     = (u16*)(ws + 1600000);    // t bf16 [96,512,512] = 12.58M fl;
                                           //   live qkt_mfma->gather; overlaps
                                           //   qkvb (dead after split), ff1b/
                                           //   x1/olbdb (written later)
  u16*   olbdb  = (u16*)(ws + 1600000);    // bf16 O (written at step 8)
  u16*   ff1b   = (u16*)(ws + 3200000);    // [4096,3072] bf16 (written step 11)
  float* x1     = ws + 11100000;           // ends 14,245,728 (written step 9)
  float* pe     = ws + 14300000;           // [128,2304] fp32, ends 14,594,912
  float* part   = ws + 14600000;           // split-K partials, <=4x3,145,728
  u16*   vb     = (u16*)(ws + 21000000);   // ends 22,572,864
  float* stats  = ws + 22600000;           // [96,512,16], ends 23,386,432
  u8*    bdT    = (u8*)(ws + 23400000);    // [8,512,512] u8, ends 23,924,288
  u16*   kpb    = (u16*)(ws + 24000000);   // [96,512,128] bf16, ends 27,145,728
  u16*   qpb    = (u16*)(ws + 27200000);   // ends 30,345,728
  u16*   W1b    = (u16*)(ws + 30400000);   // ends 31,579,648
  u16*   W2b    = (u16*)(ws + 31600000);   // ends 32,779,648
  u16*   W_inb  = (u16*)(ws + 32800000);   // ends 33,684,736
  u16*   W_outb = (u16*)(ws + 33700000);   // ends 33,994,912
  u16*   qb     = (u16*)(ws + 34000000);   // ends 35,572,864
  u16*   kb     = (u16*)(ws + 35600000);   // ends 37,172,864
  u16*   peb    = (u16*)(ws + 37200000);   // [128,2304] bf16, ends 37,347,456

  // 0) dtype conversions + bdist transpose
  f2b_kernel<<<1728, 256, 0, stream>>>(W_in, W_inb);
  f2b_kernel<<<576, 256, 0, stream>>>(W_out, W_outb);
  f2b_kernel<<<2304, 256, 0, stream>>>(W1, W1b);
  f2b_kernel<<<2304, 256, 0, stream>>>(W2, W2b);
  bdist_t<<<8192, 256, 0, stream>>>(bdist, bdT);
  // 1) LN1 -> bf16
  ln_bf16<<<4096, 256, 0, stream>>>(x, ln1w, ln1b, xnb);
  // 2) qkv = xn @ W_in^T + b_in  (MFMA, bf16 out)
  gemm_mfma<0, 1, 0><<<dim3(18, 32), 256, 0, stream>>>(
      xnb, DD, W_inb, DD, qkvb, 3 * DD, b_in, nullptr, DD);
  // 3) pe_proj fp32 + bf16 copy
  gemm_kernel<0><<<dim3(36, 2, 1), 256, 0, stream>>>(
      pe_emb, DD, 0, 0, W_in, DD, 0, 0, pe, 3 * DD, 0, 0, b_in, nullptr, DD, 0);
  f2b_kernel<<<288, 256, 0, stream>>>(pe, peb);
  // 4) split -> qb,kb,vb bf16  (qkvb dead after this; tb reuses its region)
  split_qkv5<<<3072, 256, 0, stream>>>(qkvb, qb, kb, vb);
  // 5) kp = k @ pe_q^T per head (batched MFMA, B mod-12)
  gemm_mfma_b<1><<<dim3(1, 4, 96), 256, 0, stream>>>(
      kb, DHH, (long)LL * DHH, peb, 3 * DD, 64, kpb, PP, (long)LL * PP, DHH);
  // 6) qp = q @ pe_k^T per head
  gemm_mfma_b<1><<<dim3(1, 4, 96), 256, 0, stream>>>(
      qb, DHH, (long)LL * DHH, peb + DD, 3 * DD, 64, qpb, PP, (long)LL * PP, DHH);
  // 7a) t = q @ k^T per head (batched MFMA, B per-z) -> tb bf16
  gemm_mfma_b<0><<<dim3(4, 4, 96), 256, 0, stream>>>(
      qb, DHH, (long)LL * DHH, kb, DHH, (long)LL * DHH, tb, LL, (long)LL * LL,
      DHH);
  // 7b) eout = (t + gathers)*inv + edge, + softmax tile stats (streaming)
  gather_scale2<<<dim3(8, 8, 96), 256, 0, stream>>>(tb, kpb, qpb, bdT, edge,
                                                    eout, stats);
  // 8) fused softmax + PV -> olbd bf16 [L,B,D]
  softmax_pv_tiled<<<dim3(8, 96), 256, 0, stream>>>(eout, vb, stats, olbdb);
  // 9) x1 = O @ W_out^T + b_out + x   (split-K=2 + combine)
  gemm_mfma_part<<<dim3(6, 32, 2), 256, 0, stream>>>(
      olbdb, DD, W_outb, DD, part, DD, 3145728L, DD / 2);
  combine_k<2><<<3072, 256, 0, stream>>>(part, b_out, x, x1);
  // 10) LN2 -> bf16
  ln_bf16<<<4096, 256, 0, stream>>>(x1, ln2w, ln2b, xnb);
  // 11) ff1 = gelu(xn @ W1^T + b1) (bf16 out)
  gemm_mfma<1, 1, 0><<<dim3(24, 32), 256, 0, stream>>>(
      xnb, DD, W1b, DD, ff1b, 4 * DD, b1, nullptr, DD);
  // 12) x_out = ff1 @ W2^T + b2 + x1  (split-K=4 + combine)
  gemm_mfma_part<<<dim3(6, 32, 4), 256, 0, stream>>>(
      ff1b, 4 * DD, W2b, 4 * DD, part, DD, 3145728L, DD);
  combine_k<4><<<3072, 256, 0, stream>>>(part, b2, x1, xout);
}

// Round 14
// 377.014 us; speedup vs baseline: 1.4915x; 1.0568x over previous
//
#include <hip/hip_runtime.h>
#include <hip/hip_bf16.h>
#include <math.h>

// Problem constants
#define LL 512
#define BB 8
#define DD 768
#define HH 12
#define DHH 64
#define PP 128

typedef unsigned char u8;
typedef unsigned short u16;
typedef unsigned int u32;
typedef __attribute__((ext_vector_type(8))) short bf16x8;
typedef __attribute__((ext_vector_type(4))) float f32x4;

__device__ __forceinline__ u16 f2bf(float f) {
  u32 u = __float_as_uint(f);
  u32 r = (u + 0x7fffu + ((u >> 16) & 1u)) >> 16;
  return (u16)r;
}
__device__ __forceinline__ float bf2f(u32 u) {
  return __uint_as_float((u & 0xffffu) << 16);
}

#define GLDS(g, l)                                                             \
  __builtin_amdgcn_global_load_lds(                                            \
      (const __attribute__((address_space(1))) void*)(g),                      \
      (__attribute__((address_space(3))) void*)(l), 16, 0, 0)

// ---------------------------------------------------------------------------
__device__ __forceinline__ void block_reduce2(float& a, float& b, float* sbuf) {
#pragma unroll
  for (int off = 32; off > 0; off >>= 1) {
    a += __shfl_down(a, off, 64);
    b += __shfl_down(b, off, 64);
  }
  int wid = threadIdx.x >> 6, lane = threadIdx.x & 63;
  __syncthreads();
  if (lane == 0) { sbuf[wid] = a; sbuf[4 + wid] = b; }
  __syncthreads();
  a = sbuf[0] + sbuf[1] + sbuf[2] + sbuf[3];
  b = sbuf[4] + sbuf[5] + sbuf[6] + sbuf[7];
}

// LayerNorm over D=768, one block per row, bf16 output
__global__ __launch_bounds__(256) void ln_bf16(const float* __restrict__ x,
                                               const float* __restrict__ w,
                                               const float* __restrict__ bb,
                                               u16* __restrict__ out) {
  __shared__ float sbuf[8];
  size_t row = blockIdx.x;
  const float* xr = x + row * DD;
  int t = threadIdx.x;
  float v0 = xr[t], v1 = xr[t + 256], v2 = xr[t + 512];
  float s = v0 + v1 + v2;
  float ss = v0 * v0 + v1 * v1 + v2 * v2;
  block_reduce2(s, ss, sbuf);
  float mu = s * (1.0f / DD);
  float var = ss * (1.0f / DD) - mu * mu;
  float r = rsqrtf(var + 1e-5f);
  u16* orow = out + row * DD;
  orow[t]       = f2bf((v0 - mu) * r * w[t]       + bb[t]);
  orow[t + 256] = f2bf((v1 - mu) * r * w[t + 256] + bb[t + 256]);
  orow[t + 512] = f2bf((v2 - mu) * r * w[t + 512] + bb[t + 512]);
}

// fp32 -> bf16, 4 elements/thread
__global__ __launch_bounds__(256) void f2b_kernel(const float* __restrict__ in,
                                                  u16* __restrict__ out) {
  int idx = blockIdx.x * 256 + threadIdx.x;
  float4 v = *(const float4*)(in + (size_t)idx * 4);
  u32 lo = (u32)f2bf(v.x) | ((u32)f2bf(v.y) << 16);
  u32 hi = (u32)f2bf(v.z) | ((u32)f2bf(v.w) << 16);
  *(uint2*)(out + (size_t)idx * 4) = make_uint2(lo, hi);
}

// bdist [L,L,B] int32 -> bdistT [B,L,L] u8 (values < 128)
__global__ __launch_bounds__(256) void bdist_t(const int* __restrict__ bd,
                                               u8* __restrict__ out) {
  int t = blockIdx.x * 256 + threadIdx.x;  // 2,097,152 items, read-coalesced
  int b = t & 7, jj = (t >> 3) & 511, ii = t >> 12;
  out[((size_t)b << 18) + ((size_t)ii << 9) + jj] = (u8)bd[t];
}

// ---------------------------------------------------------------------------
// bf16 MFMA GEMM (round-3-proven): C = act(A * B^T + bias) [+ residual].
// 128x128 tile, BK=32, 4 waves 2x2. Requires 128 | grid-covered M,N; 32 | K.
template <int ACT, int OBF, int RES>
__global__ __launch_bounds__(256) void gemm_mfma(
    const u16* __restrict__ A, int lda, const u16* __restrict__ B, int ldb,
    void* __restrict__ Cv, int ldc, const float* __restrict__ bias,
    const float* __restrict__ residual, int K) {
  __shared__ __align__(16) u16 Asl[128 * 32];
  __shared__ __align__(16) u16 Bsl[128 * 32];
  int t = threadIdx.x;
  int m0 = blockIdx.y * 128, n0 = blockIdx.x * 128;
  int lane = t & 63, w = t >> 6;
  int wr = w >> 1, wc = w & 1;
  int lr = lane & 15, lg = lane >> 4;

  f32x4 acc[4][4] = {};

  const u16* Ag0 = A + (size_t)(m0 + (t >> 2)) * lda + (t & 3) * 8;
  const u16* Ag1 = A + (size_t)(m0 + 64 + (t >> 2)) * lda + (t & 3) * 8;
  const u16* Bg0 = B + (size_t)(n0 + (t >> 2)) * ldb + (t & 3) * 8;
  const u16* Bg1 = B + (size_t)(n0 + 64 + (t >> 2)) * ldb + (t & 3) * 8;
  u16* Ad0 = &Asl[t * 8];
  u16* Ad1 = &Asl[2048 + t * 8];
  u16* Bd0 = &Bsl[t * 8];
  u16* Bd1 = &Bsl[2048 + t * 8];

  for (int k0 = 0; k0 < K; k0 += 32) {
    GLDS(Ag0 + k0, Ad0);
    GLDS(Ag1 + k0, Ad1);
    GLDS(Bg0 + k0, Bd0);
    GLDS(Bg1 + k0, Bd1);
    __syncthreads();
    bf16x8 a[4], b[4];
#pragma unroll
    for (int i = 0; i < 4; i++)
      a[i] = *(const bf16x8*)&Asl[(wr * 64 + i * 16 + lr) * 32 + lg * 8];
#pragma unroll
    for (int j = 0; j < 4; j++)
      b[j] = *(const bf16x8*)&Bsl[(wc * 64 + j * 16 + lr) * 32 + lg * 8];
#pragma unroll
    for (int i = 0; i < 4; i++)
#pragma unroll
      for (int j = 0; j < 4; j++)
        asm volatile("v_mfma_f32_16x16x32_bf16 %0, %1, %2, %0"
                     : "+v"(acc[i][j])
                     : "v"(a[i]), "v"(b[j]));
    __syncthreads();
  }
  asm volatile("s_nop 7\n\ts_nop 7" ::);

  float* Cf = (float*)Cv;
  u16* Cb = (u16*)Cv;
#pragma unroll
  for (int i = 0; i < 4; i++) {
#pragma unroll
    for (int r = 0; r < 4; r++) {
      int row = m0 + wr * 64 + i * 16 + lg * 4 + r;
#pragma unroll
      for (int j = 0; j < 4; j++) {
        int col = n0 + wc * 64 + j * 16 + lr;
        float vv = acc[i][j][r];
        if (bias) vv += bias[col];
        if (ACT) vv = 0.5f * vv * (1.0f + erff(vv * 0.70710678118654752f));
        if (RES) vv += residual[(size_t)row * ldc + col];
        if (OBF) Cb[(size_t)row * ldc + col] = f2bf(vv);
        else     Cf[(size_t)row * ldc + col] = vv;
      }
    }
  }
}

// ---------------------------------------------------------------------------
// Batched variant (round-9/11/13-proven core): A += z*sAz;
// B += (BMOD ? z%HH : z)*sBz. bf16 out scaled by 0.125 (all uses: t/kp/qp
// feed the attention-score sum which multiplies by 1/sqrt(64)).
template <int BMOD>
__global__ __launch_bounds__(256) void gemm_mfma_b(
    const u16* __restrict__ A, int lda, long sAz,
    const u16* __restrict__ B, int ldb, long sBz,
    u16* __restrict__ Cb, int ldc, long sCz, int K) {
  __shared__ __align__(16) u16 Asl[128 * 32];
  __shared__ __align__(16) u16 Bsl[128 * 32];
  int z = blockIdx.z;
  A += (size_t)z * sAz;
  B += (size_t)(BMOD ? (z % HH) : z) * sBz;
  Cb += (size_t)z * sCz;
  int t = threadIdx.x;
  int m0 = blockIdx.y * 128, n0 = blockIdx.x * 128;
  int lane = t & 63, w = t >> 6;
  int wr = w >> 1, wc = w & 1;
  int lr = lane & 15, lg = lane >> 4;

  f32x4 acc[4][4] = {};

  const u16* Ag0 = A + (size_t)(m0 + (t >> 2)) * lda + (t & 3) * 8;
  const u16* Ag1 = A + (size_t)(m0 + 64 + (t >> 2)) * lda + (t & 3) * 8;
  const u16* Bg0 = B + (size_t)(n0 + (t >> 2)) * ldb + (t & 3) * 8;
  const u16* Bg1 = B + (size_t)(n0 + 64 + (t >> 2)) * ldb + (t & 3) * 8;
  u16* Ad0 = &Asl[t * 8];
  u16* Ad1 = &Asl[2048 + t * 8];
  u16* Bd0 = &Bsl[t * 8];
  u16* Bd1 = &Bsl[2048 + t * 8];

  for (int k0 = 0; k0 < K; k0 += 32) {
    GLDS(Ag0 + k0, Ad0);
    GLDS(Ag1 + k0, Ad1);
    GLDS(Bg0 + k0, Bd0);
    GLDS(Bg1 + k0, Bd1);
    __syncthreads();
    bf16x8 a[4], b[4];
#pragma unroll
    for (int i = 0; i < 4; i++)
      a[i] = *(const bf16x8*)&Asl[(wr * 64 + i * 16 + lr) * 32 + lg * 8];
#pragma unroll
    for (int j = 0; j < 4; j++)
      b[j] = *(const bf16x8*)&Bsl[(wc * 64 + j * 16 + lr) * 32 + lg * 8];
#pragma unroll
    for (int i = 0; i < 4; i++)
#pragma unroll
      for (int j = 0; j < 4; j++)
        asm volatile("v_mfma_f32_16x16x32_bf16 %0, %1, %2, %0"
                     : "+v"(acc[i][j])
                     : "v"(a[i]), "v"(b[j]));
    __syncthreads();
  }
  asm volatile("s_nop 7\n\ts_nop 7" ::);

#pragma unroll
  for (int i = 0; i < 4; i++) {
#pragma unroll
    for (int r = 0; r < 4; r++) {
      int row = m0 + wr * 64 + i * 16 + lg * 4 + r;
#pragma unroll
      for (int j = 0; j < 4; j++) {
        int col = n0 + wc * 64 + j * 16 + lr;
        Cb[(size_t)row * ldc + col] = f2bf(acc[i][j][r] * 0.125f);
      }
    }
  }
}

// ---------------------------------------------------------------------------
// Split-K partial MFMA GEMM (round-11-proven).
__global__ __launch_bounds__(256) void gemm_mfma_part(
    const u16* __restrict__ A, int lda, const u16* __restrict__ B, int ldb,
    float* __restrict__ Cf, int ldc, long partStride, int Kper) {
  __shared__ __align__(16) u16 Asl[128 * 32];
  __shared__ __align__(16) u16 Bsl[128 * 32];
  int z = blockIdx.z;
  A += (size_t)z * Kper;
  B += (size_t)z * Kper;
  Cf += (size_t)z * partStride;
  int t = threadIdx.x;
  int m0 = blockIdx.y * 128, n0 = blockIdx.x * 128;
  int lane = t & 63, w = t >> 6;
  int wr = w >> 1, wc = w & 1;
  int lr = lane & 15, lg = lane >> 4;

  f32x4 acc[4][4] = {};

  const u16* Ag0 = A + (size_t)(m0 + (t >> 2)) * lda + (t & 3) * 8;
  const u16* Ag1 = A + (size_t)(m0 + 64 + (t >> 2)) * lda + (t & 3) * 8;
  const u16* Bg0 = B + (size_t)(n0 + (t >> 2)) * ldb + (t & 3) * 8;
  const u16* Bg1 = B + (size_t)(n0 + 64 + (t >> 2)) * ldb + (t & 3) * 8;
  u16* Ad0 = &Asl[t * 8];
  u16* Ad1 = &Asl[2048 + t * 8];
  u16* Bd0 = &Bsl[t * 8];
  u16* Bd1 = &Bsl[2048 + t * 8];

  for (int k0 = 0; k0 < Kper; k0 += 32) {
    GLDS(Ag0 + k0, Ad0);
    GLDS(Ag1 + k0, Ad1);
    GLDS(Bg0 + k0, Bd0);
    GLDS(Bg1 + k0, Bd1);
    __syncthreads();
    bf16x8 a[4], b[4];
#pragma unroll
    for (int i = 0; i < 4; i++)
      a[i] = *(const bf16x8*)&Asl[(wr * 64 + i * 16 + lr) * 32 + lg * 8];
#pragma unroll
    for (int j = 0; j < 4; j++)
      b[j] = *(const bf16x8*)&Bsl[(wc * 64 + j * 16 + lr) * 32 + lg * 8];
#pragma unroll
    for (int i = 0; i < 4; i++)
#pragma unroll
      for (int j = 0; j < 4; j++)
        asm volatile("v_mfma_f32_16x16x32_bf16 %0, %1, %2, %0"
                     : "+v"(acc[i][j])
                     : "v"(a[i]), "v"(b[j]));
    __syncthreads();
  }
  asm volatile("s_nop 7\n\ts_nop 7" ::);

#pragma unroll
  for (int i = 0; i < 4; i++) {
#pragma unroll
    for (int r = 0; r < 4; r++) {
      int row = m0 + wr * 64 + i * 16 + lg * 4 + r;
#pragma unroll
      for (int j = 0; j < 4; j++) {
        int col = n0 + wc * 64 + j * 16 + lr;
        Cf[(size_t)row * ldc + col] = acc[i][j][r];
      }
    }
  }
}

// Combine NS split-K partials: out = sum(parts) + bias + res. 4 elems/thread.
template <int NS>
__global__ __launch_bounds__(256) void combine_k(const float* __restrict__ p,
                                                 const float* __restrict__ bias,
                                                 const float* __restrict__ res,
                                                 float* __restrict__ out) {
  int idx = blockIdx.x * 256 + threadIdx.x;  // over 786,432
  size_t e = (size_t)idx * 4;
  float4 s = *(const float4*)(p + e);
#pragma unroll
  for (int z = 1; z < NS; z++) {
    float4 t2 = *(const float4*)(p + (size_t)z * 3145728 + e);
    s.x += t2.x; s.y += t2.y; s.z += t2.z; s.w += t2.w;
  }
  int col = (int)(e % DD);
  float4 b4 = *(const float4*)(bias + col);
  float4 r4 = *(const float4*)(res + e);
  *(float4*)(out + e) = make_float4(s.x + b4.x + r4.x, s.y + b4.y + r4.y,
                                    s.z + b4.z + r4.z, s.w + b4.w + r4.w);
}

// ---------------------------------------------------------------------------
// Generic fp32 GEMM (round-3-proven) — used only for pe_proj now.
template <int OBF>
__global__ __launch_bounds__(256) void gemm_kernel(
    const float* __restrict__ A, int lda, long sAo, long sAi,
    const float* __restrict__ B, int ldb, long sBo, long sBi,
    void* __restrict__ Cv, int ldc, long sCo, long sCi,
    const float* __restrict__ bias,
    const float* __restrict__ residual,
    int K, int act) {
  int z = blockIdx.z;
  int zo = z / HH, zi = z - zo * HH;
  A += (size_t)zo * sAo + (size_t)zi * sAi;
  B += (size_t)zo * sBo + (size_t)zi * sBi;
  size_t coff = (size_t)zo * sCo + (size_t)zi * sCi;

  __shared__ float As[16][68];
  __shared__ float Bs[16][68];
  int tid = threadIdx.x;
  int tx = tid & 15, ty = tid >> 4;
  int m0 = blockIdx.y * 64, n0 = blockIdx.x * 64;
  float acc[4][4] = {};
  int r = tid >> 2, kq = (tid & 3) * 4;

  for (int k0 = 0; k0 < K; k0 += 16) {
    float4 av = *(const float4*)(A + (size_t)(m0 + r) * lda + (k0 + kq));
    float4 bv = *(const float4*)(B + (size_t)(n0 + r) * ldb + (k0 + kq));
    As[kq + 0][r] = av.x; As[kq + 1][r] = av.y; As[kq + 2][r] = av.z; As[kq + 3][r] = av.w;
    Bs[kq + 0][r] = bv.x; Bs[kq + 1][r] = bv.y; Bs[kq + 2][r] = bv.z; Bs[kq + 3][r] = bv.w;
    __syncthreads();
#pragma unroll
    for (int kk = 0; kk < 16; kk++) {
      float4 a4 = *(const float4*)&As[kk][ty * 4];
      float4 b4 = *(const float4*)&Bs[kk][tx * 4];
      float ar[4] = {a4.x, a4.y, a4.z, a4.w};
      float br[4] = {b4.x, b4.y, b4.z, b4.w};
#pragma unroll
      for (int i2 = 0; i2 < 4; i2++)
#pragma unroll
        for (int j2 = 0; j2 < 4; j2++)
          acc[i2][j2] += ar[i2] * br[j2];
    }
    __syncthreads();
  }

  float bs[4] = {0.f, 0.f, 0.f, 0.f};
  if (bias) {
    float4 b4 = *(const float4*)&bias[n0 + tx * 4];
    bs[0] = b4.x; bs[1] = b4.y; bs[2] = b4.z; bs[3] = b4.w;
  }
  float* Cf = (float*)Cv;
  u16* Cb = (u16*)Cv;
#pragma unroll
  for (int i2 = 0; i2 < 4; i2++) {
    size_t m = (size_t)(m0 + ty * 4 + i2);
    float vout[4];
#pragma unroll
    for (int j2 = 0; j2 < 4; j2++) vout[j2] = acc[i2][j2] + bs[j2];
    if (residual) {
      const float4 r4 = *(const float4*)&residual[coff + m * ldc + n0 + tx * 4];
      vout[0] += r4.x; vout[1] += r4.y; vout[2] += r4.z; vout[3] += r4.w;
    }
    if (OBF) {
      u32 lo = (u32)f2bf(vout[0]) | ((u32)f2bf(vout[1]) << 16);
      u32 hi = (u32)f2bf(vout[2]) | ((u32)f2bf(vout[3]) << 16);
      *(uint2*)&Cb[coff + m * ldc + n0 + tx * 4] = make_uint2(lo, hi);
    } else {
      *(float4*)&Cf[coff + m * ldc + n0 + tx * 4] =
          make_float4(vout[0], vout[1], vout[2], vout[3]);
    }
  }
}

// ---------------------------------------------------------------------------
// qkv bf16 [L*B, 3D] -> qb,kb bf16 [B,H,L,Dh] + vbT bf16 [B,H,Dh,L]
__global__ __launch_bounds__(256) void split_qkv6(const u16* __restrict__ qkvb,
                                                  u16* __restrict__ qb,
                                                  u16* __restrict__ kb,
                                                  u16* __restrict__ vbT) {
  int idx = blockIdx.x * 256 + threadIdx.x;  // over 786,432
  int d4 = idx & 15;
  int l = (idx >> 4) & 511;
  int bh = idx >> 13;
  int b = bh / HH, h = bh - b * HH;
  size_t src = ((size_t)(l * BB + b)) * (3 * DD) + h * 64 + d4 * 4;
  uint2 qv = *(const uint2*)(qkvb + src);
  uint2 kv = *(const uint2*)(qkvb + src + DD);
  uint2 vv = *(const uint2*)(qkvb + src + 2 * DD);
  size_t dst = (size_t)idx * 4;
  *(uint2*)(qb + dst) = qv;
  *(uint2*)(kb + dst) = kv;
  // V transposed: vbT[bh][d][l]
  u16 v0 = (u16)(vv.x & 0xffff), v1 = (u16)(vv.x >> 16);
  u16 v2 = (u16)(vv.y & 0xffff), v3 = (u16)(vv.y >> 16);
  size_t vtb = ((size_t)bh * DHH + d4 * 4) * LL + l;
  vbT[vtb]          = v0;
  vbT[vtb + LL]     = v1;
  vbT[vtb + 2 * LL] = v2;
  vbT[vtb + 3 * LL] = v3;
}

// ---------------------------------------------------------------------------
// Streaming gather: eout = t' + kp' + qp' + edge (inputs pre-scaled 0.125),
// + per-tile stats. LDS = kpl/qpl (32KB). Round-13-proven epilogue.
__global__ __launch_bounds__(256) void gather_scale2(
    const u16* __restrict__ tb,
    const u16* __restrict__ kp, const u16* __restrict__ qp,
    const u8* __restrict__ bdT, const float* __restrict__ edge,
    float* __restrict__ eout, float* __restrict__ stats) {
  int bh = blockIdx.z, b = bh / HH;
  int i0 = blockIdx.y * 64, j0 = blockIdx.x * 64, jt = blockIdx.x;
  __shared__ u16 kpl[64][PP];
  __shared__ u16 qpl[64][PP];
  int tid = threadIdx.x;
  int tx = tid & 15, ty = tid >> 4;

  const u16* kpg = kp + (size_t)bh * (LL * PP);
  const u16* qpg = qp + (size_t)bh * (LL * PP);
  for (int c = tid; c < 1024; c += 256) {
    int row = c >> 4, ch = (c & 15) * 8;
    *(uint4*)&kpl[row][ch] = *(const uint4*)&kpg[(size_t)(j0 + row) * PP + ch];
    *(uint4*)&qpl[row][ch] = *(const uint4*)&qpg[(size_t)(i0 + row) * PP + ch];
  }
  __syncthreads();

  const u8* bd = bdT + (size_t)b * (LL * LL);
  const float* eb = edge + (size_t)bh * (LL * LL);
  const u16* tbb = tb + (size_t)bh * (LL * LL);
  float* ob = eout + (size_t)bh * (LL * LL);

  float rowm[4], rows[4];
#pragma unroll
  for (int i2 = 0; i2 < 4; i2++) {
    int row = i0 + ty * 4 + i2;
    int col0 = j0 + tx * 4;
    uchar4 p4 = *(const uchar4*)&bd[(size_t)row * LL + col0];
    float4 e4 = *(const float4*)&eb[(size_t)row * LL + col0];
    uint2 t2 = *(const uint2*)&tbb[(size_t)row * LL + col0];
    float tv[4] = {bf2f(t2.x), bf2f(t2.x >> 16), bf2f(t2.y), bf2f(t2.y >> 16)};
    int pp[4] = {p4.x, p4.y, p4.z, p4.w};
    float ee[4] = {e4.x, e4.y, e4.z, e4.w};
    float sv[4];
#pragma unroll
    for (int j2 = 0; j2 < 4; j2++) {
      float gk = bf2f((u32)kpl[tx * 4 + j2][pp[j2]]);
      float gq = bf2f((u32)qpl[ty * 4 + i2][pp[j2]]);
      sv[j2] = tv[j2] + gk + gq + ee[j2];
    }
    *(float4*)&ob[(size_t)row * LL + col0] =
        make_float4(sv[0], sv[1], sv[2], sv[3]);
    float m = fmaxf(fmaxf(sv[0], sv[1]), fmaxf(sv[2], sv[3]));
#pragma unroll
    for (int off = 1; off < 16; off <<= 1) m = fmaxf(m, __shfl_xor(m, off, 64));
    float ss = expf(sv[0] - m) + expf(sv[1] - m) + expf(sv[2] - m) + expf(sv[3] - m);
#pragma unroll
    for (int off = 1; off < 16; off <<= 1) ss += __shfl_xor(ss, off, 64);
    rowm[i2] = m;
    rows[i2] = ss;
  }
  if (tx == 0) {
#pragma unroll
    for (int i2 = 0; i2 < 4; i2++) {
      size_t si = ((size_t)bh * LL + i0 + ty * 4 + i2) * 16 + jt;
      stats[si] = rowm[i2];
      stats[si + 8] = rows[i2];
    }
  }
}

// ---------------------------------------------------------------------------
// MFMA softmax+PV: per (bh, 64-row i-tile). P built bf16 in LDS (proven
// fragment layout [row*32+k]); V staged via GLDS from vbT [bh][d][l].
// 4 waves, 2x2 grid of 32x32 output tiles. O bf16 [L,B,D].
__global__ __launch_bounds__(256) void softmax_pv_mfma(
    const float* __restrict__ scores, const u16* __restrict__ vbT,
    const float* __restrict__ stats, u16* __restrict__ olbd) {
  int bh = blockIdx.y;
  int i0 = blockIdx.x * 64;
  int b = bh / HH, h = bh - b * HH;
  __shared__ __align__(16) u16 PL[2][64 * 32];   // P[row][k], K-step ks
  __shared__ __align__(16) u16 VL[2][64 * 32];   // V^T[d][k]
  __shared__ float smax[64], srs[64];
  int tid = threadIdx.x;
  int tx = tid & 15, ty = tid >> 4;
  int lane = tid & 63, w = tid >> 6;
  int wr = w >> 1, wc = w & 1;
  int lr = lane & 15, lg = lane >> 4;
  const float* sbase = scores + (size_t)bh * (LL * LL);
  const u16* vt = vbT + (size_t)bh * (DHH * LL);

  if (tid < 64) {
    size_t si = ((size_t)bh * LL + i0 + tid) * 16;
    float m = stats[si];
#pragma unroll
    for (int j = 1; j < 8; j++) m = fmaxf(m, stats[si + j]);
    float s = 0.f;
#pragma unroll
    for (int j = 0; j < 8; j++) s += stats[si + 8 + j] * expf(stats[si + j] - m);
    smax[tid] = m;
    srs[tid] = 1.0f / s;
  }
  __syncthreads();

  f32x4 acc[2][2] = {};
  int ks = tx >> 3, kk = (tx & 7) * 4;
  int vd = tid >> 2, vjo = (tid & 3) * 8;

  for (int jt = 0; jt < 8; jt++) {
    int j0 = jt * 64;
    // stage V^T tiles (both K-steps) async into LDS
    GLDS(vt + (size_t)vd * LL + j0 + vjo, &VL[0][tid * 8]);
    GLDS(vt + (size_t)vd * LL + j0 + 32 + vjo, &VL[1][tid * 8]);
    // compute P bf16 into PL (fragment layout)
#pragma unroll
    for (int rr = 0; rr < 4; rr++) {
      int r = ty + rr * 16;
      float4 s4 = *(const float4*)(sbase + (size_t)(i0 + r) * LL + j0 + tx * 4);
      float m = smax[r], rs = srs[r];
      u16 p0 = f2bf(expf(s4.x - m) * rs);
      u16 p1 = f2bf(expf(s4.y - m) * rs);
      u16 p2 = f2bf(expf(s4.z - m) * rs);
      u16 p3 = f2bf(expf(s4.w - m) * rs);
      *(uint2*)&PL[ks][r * 32 + kk] =
          make_uint2((u32)p0 | ((u32)p1 << 16), (u32)p2 | ((u32)p3 << 16));
    }
    __syncthreads();
#pragma unroll
    for (int s2 = 0; s2 < 2; s2++) {
      bf16x8 a[2], bfr[2];
#pragma unroll
      for (int i = 0; i < 2; i++)
        a[i] = *(const bf16x8*)&PL[s2][(wr * 32 + i * 16 + lr) * 32 + lg * 8];
#pragma unroll
      for (int j = 0; j < 2; j++)
        bfr[j] = *(const bf16x8*)&VL[s2][(wc * 32 + j * 16 + lr) * 32 + lg * 8];
#pragma unroll
      for (int i = 0; i < 2; i++)
#pragma unroll
        for (int j = 0; j < 2; j++)
          asm volatile("v_mfma_f32_16x16x32_bf16 %0, %1, %2, %0"
                       : "+v"(acc[i][j])
                       : "v"(a[i]), "v"(bfr[j]));
    }
    __syncthreads();
  }
  asm volatile("s_nop 7\n\ts_nop 7" ::);

#pragma unroll
  for (int i = 0; i < 2; i++) {
#pragma unroll
    for (int r = 0; r < 4; r++) {
      int irow = i0 + wr * 32 + i * 16 + lg * 4 + r;
#pragma unroll
      for (int j = 0; j < 2; j++) {
        int d = wc * 32 + j * 16 + lr;
        olbd[((size_t)irow * BB + b) * DD + h * 64 + d] = f2bf(acc[i][j][r]);
      }
    }
  }
}

// ---------------------------------------------------------------------------
extern "C" void kernel_launch(void* const* d_in, const int* in_sizes, int n_in,
                              void* d_out, int out_size, void* d_ws, size_t ws_size,
                              hipStream_t stream) {
  const float* x      = (const float*)d_in[0];
  const float* edge   = (const float*)d_in[1];
  const int*   bdist  = (const int*)d_in[2];
  const float* W_in   = (const float*)d_in[3];
  const float* b_in   = (const float*)d_in[4];
  const float* pe_emb = (const float*)d_in[5];
  const float* W_out  = (const float*)d_in[6];
  const float* b_out  = (const float*)d_in[7];
  const float* W1     = (const float*)d_in[8];
  const float* b1     = (const float*)d_in[9];
  const float* W2     = (const float*)d_in[10];
  const float* b2     = (const float*)d_in[11];
  const float* ln1w   = (const float*)d_in[12];
  const float* ln1b   = (const float*)d_in[13];
  const float* ln2w   = (const float*)d_in[14];
  const float* ln2b   = (const float*)d_in[15];

  float* xout = (float*)d_out;                 // [L,B,D]
  float* eout = xout + (size_t)LL * BB * DD;   // [B*H,L,L] == final scores

  // Workspace layout (float units). Max used: ~37.35M floats = 149.4 MB.
  float* ws = (float*)d_ws;
  u16*   xnb    = (u16*)(ws + 0);          // [4096,768] bf16
  u16*   qkvb   = (u16*)(ws + 1600000);    // [4096,2304] bf16
  u16*   tb     = (u16*)(ws + 1600000);    // t bf16 [96,512,512] (reuse)
  u16*   olbdb  = (u16*)(ws + 1600000);    // bf16 O (written step 8)
  u16*   ff1b   = (u16*)(ws + 3200000);    // [4096,3072] bf16 (step 11)
  float* x1     = ws + 11100000;           // (step 9)
  float* pe     = ws + 14300000;           // [128,2304] fp32
  float* part   = ws + 14600000;           // split-K partials
  u16*   vbT    = (u16*)(ws + 21000000);   // [96,64,512] bf16 transposed V
  float* stats  = ws + 22600000;           // [96,512,16]
  u8*    bdT    = (u8*)(ws + 23400000);    // [8,512,512] u8
  u16*   kpb    = (u16*)(ws + 24000000);   // [96,512,128] bf16
  u16*   qpb    = (u16*)(ws + 27200000);
  u16*   W1b    = (u16*)(ws + 30400000);
  u16*   W2b    = (u16*)(ws + 31600000);
  u16*   W_inb  = (u16*)(ws + 32800000);
  u16*   W_outb = (u16*)(ws + 33700000);
  u16*   qb     = (u16*)(ws + 34000000);
  u16*   kb     = (u16*)(ws + 35600000);
  u16*   peb    = (u16*)(ws + 37200000);   // [128,2304] bf16

  // 0) dtype conversions + bdist transpose
  f2b_kernel<<<1728, 256, 0, stream>>>(W_in, W_inb);
  f2b_kernel<<<576, 256, 0, stream>>>(W_out, W_outb);
  f2b_kernel<<<2304, 256, 0, stream>>>(W1, W1b);
  f2b_kernel<<<2304, 256, 0, stream>>>(W2, W2b);
  bdist_t<<<8192, 256, 0, stream>>>(bdist, bdT);
  // 1) LN1 -> bf16
  ln_bf16<<<4096, 256, 0, stream>>>(x, ln1w, ln1b, xnb);
  // 2) qkv = xn @ W_in^T + b_in  (MFMA, bf16 out)
  gemm_mfma<0, 1, 0><<<dim3(18, 32), 256, 0, stream>>>(
      xnb, DD, W_inb, DD, qkvb, 3 * DD, b_in, nullptr, DD);
  // 3) pe_proj fp32 + bf16 copy
  gemm_kernel<0><<<dim3(36, 2, 1), 256, 0, stream>>>(
      pe_emb, DD, 0, 0, W_in, DD, 0, 0, pe, 3 * DD, 0, 0, b_in, nullptr, DD, 0);
  f2b_kernel<<<288, 256, 0, stream>>>(pe, peb);
  // 4) split -> qb,kb bf16 + vbT transposed
  split_qkv6<<<3072, 256, 0, stream>>>(qkvb, qb, kb, vbT);
  // 5) kp' = (k @ pe_q^T)/8 per head (batched MFMA, B mod-12)
  gemm_mfma_b<1><<<dim3(1, 4, 96), 256, 0, stream>>>(
      kb, DHH, (long)LL * DHH, peb, 3 * DD, 64, kpb, PP, (long)LL * PP, DHH);
  // 6) qp' = (q @ pe_k^T)/8 per head
  gemm_mfma_b<1><<<dim3(1, 4, 96), 256, 0, stream>>>(
      qb, DHH, (long)LL * DHH, peb + DD, 3 * DD, 64, qpb, PP, (long)LL * PP, DHH);
  // 7a) t' = (q @ k^T)/8 per head -> tb bf16
  gemm_mfma_b<0><<<dim3(4, 4, 96), 256, 0, stream>>>(
      qb, DHH, (long)LL * DHH, kb, DHH, (long)LL * DHH, tb, LL, (long)LL * LL,
      DHH);
  // 7b) eout = t' + kp' + qp' + edge, + softmax tile stats (streaming)
  gather_scale2<<<dim3(8, 8, 96), 256, 0, stream>>>(tb, kpb, qpb, bdT, edge,
                                                    eout, stats);
  // 8) MFMA softmax + PV -> olbd bf16 [L,B,D]
  softmax_pv_mfma<<<dim3(8, 96), 256, 0, stream>>>(eout, vbT, stats, olbdb);
  // 9) x1 = O @ W_out^T + b_out + x   (split-K=2 + combine)
  gemm_mfma_part<<<dim3(6, 32, 2), 256, 0, stream>>>(
      olbdb, DD, W_outb, DD, part, DD, 3145728L, DD / 2);
  combine_k<2><<<3072, 256, 0, stream>>>(part, b_out, x, x1);
  // 10) LN2 -> bf16
  ln_bf16<<<4096, 256, 0, stream>>>(x1, ln2w, ln2b, xnb);
  // 11) ff1 = gelu(xn @ W1^T + b1) (bf16 out)
  gemm_mfma<1, 1, 0><<<dim3(24, 32), 256, 0, stream>>>(
      xnb, DD, W1b, DD, ff1b, 4 * DD, b1, nullptr, DD);
  // 12) x_out = ff1 @ W2^T + b2 + x1  (split-K=4 + combine)
  gemm_mfma_part<<<dim3(6, 32, 4), 256, 0, stream>>>(
      ff1b, 4 * DD, W2b, 4 * DD, part, DD, 3145728L, DD);
  combine_k<4><<<3072, 256, 0, stream>>>(part, b2, x1, xout);
}

// Round 15
// 342.843 us; speedup vs baseline: 1.6401x; 1.0997x over previous
//
#include <hip/hip_runtime.h>
#include <hip/hip_bf16.h>
#include <math.h>

// Problem constants
#define LL 512
#define BB 8
#define DD 768
#define HH 12
#define DHH 64
#define PP 128

typedef unsigned char u8;
typedef unsigned short u16;
typedef unsigned int u32;
typedef __attribute__((ext_vector_type(8))) short bf16x8;
typedef __attribute__((ext_vector_type(4))) float f32x4;

__device__ __forceinline__ u16 f2bf(float f) {
  u32 u = __float_as_uint(f);
  u32 r = (u + 0x7fffu + ((u >> 16) & 1u)) >> 16;
  return (u16)r;
}
__device__ __forceinline__ float bf2f(u32 u) {
  return __uint_as_float((u & 0xffffu) << 16);
}

#define GLDS(g, l)                                                             \
  __builtin_amdgcn_global_load_lds(                                            \
      (const __attribute__((address_space(1))) void*)(g),                      \
      (__attribute__((address_space(3))) void*)(l), 16, 0, 0)

// ---------------------------------------------------------------------------
__device__ __forceinline__ void block_reduce2(float& a, float& b, float* sbuf) {
#pragma unroll
  for (int off = 32; off > 0; off >>= 1) {
    a += __shfl_down(a, off, 64);
    b += __shfl_down(b, off, 64);
  }
  int wid = threadIdx.x >> 6, lane = threadIdx.x & 63;
  __syncthreads();
  if (lane == 0) { sbuf[wid] = a; sbuf[4 + wid] = b; }
  __syncthreads();
  a = sbuf[0] + sbuf[1] + sbuf[2] + sbuf[3];
  b = sbuf[4] + sbuf[5] + sbuf[6] + sbuf[7];
}

// LayerNorm over D=768, one block per row, bf16 output
__global__ __launch_bounds__(256) void ln_bf16(const float* __restrict__ x,
                                               const float* __restrict__ w,
                                               const float* __restrict__ bb,
                                               u16* __restrict__ out) {
  __shared__ float sbuf[8];
  size_t row = blockIdx.x;
  const float* xr = x + row * DD;
  int t = threadIdx.x;
  float v0 = xr[t], v1 = xr[t + 256], v2 = xr[t + 512];
  float s = v0 + v1 + v2;
  float ss = v0 * v0 + v1 * v1 + v2 * v2;
  block_reduce2(s, ss, sbuf);
  float mu = s * (1.0f / DD);
  float var = ss * (1.0f / DD) - mu * mu;
  float r = rsqrtf(var + 1e-5f);
  u16* orow = out + row * DD;
  orow[t]       = f2bf((v0 - mu) * r * w[t]       + bb[t]);
  orow[t + 256] = f2bf((v1 - mu) * r * w[t + 256] + bb[t + 256]);
  orow[t + 512] = f2bf((v2 - mu) * r * w[t + 512] + bb[t + 512]);
}

// fp32 -> bf16, 4 elements/thread
__global__ __launch_bounds__(256) void f2b_kernel(const float* __restrict__ in,
                                                  u16* __restrict__ out) {
  int idx = blockIdx.x * 256 + threadIdx.x;
  float4 v = *(const float4*)(in + (size_t)idx * 4);
  u32 lo = (u32)f2bf(v.x) | ((u32)f2bf(v.y) << 16);
  u32 hi = (u32)f2bf(v.z) | ((u32)f2bf(v.w) << 16);
  *(uint2*)(out + (size_t)idx * 4) = make_uint2(lo, hi);
}

// Four weight conversions in one launch. Sizes in 4-element groups.
__global__ __launch_bounds__(256) void f2b4_kernel(
    const float* __restrict__ i0, u16* __restrict__ o0,
    const float* __restrict__ i1, u16* __restrict__ o1,
    const float* __restrict__ i2, u16* __restrict__ o2,
    const float* __restrict__ i3, u16* __restrict__ o3) {
  // groups: W_in 442368 | W_out 147456 | W1 589824 | W2 589824
  int idx = blockIdx.x * 256 + threadIdx.x;  // 0..1769471
  const float* in;
  u16* out;
  if (idx < 442368) { in = i0; out = o0; }
  else if (idx < 589824) { in = i1; out = o1; idx -= 442368; }
  else if (idx < 1179648) { in = i2; out = o2; idx -= 589824; }
  else { in = i3; out = o3; idx -= 1179648; }
  float4 v = *(const float4*)(in + (size_t)idx * 4);
  u32 lo = (u32)f2bf(v.x) | ((u32)f2bf(v.y) << 16);
  u32 hi = (u32)f2bf(v.z) | ((u32)f2bf(v.w) << 16);
  *(uint2*)(out + (size_t)idx * 4) = make_uint2(lo, hi);
}

// bdist [L,L,B] int32 -> bdistT [B,L,L] u8 (values < 128)
__global__ __launch_bounds__(256) void bdist_t(const int* __restrict__ bd,
                                               u8* __restrict__ out) {
  int t = blockIdx.x * 256 + threadIdx.x;  // 2,097,152 items, read-coalesced
  int b = t & 7, jj = (t >> 3) & 511, ii = t >> 12;
  out[((size_t)b << 18) + ((size_t)ii << 9) + jj] = (u8)bd[t];
}

// ---------------------------------------------------------------------------
// bf16 MFMA GEMM (round-3-proven): C = act(A * B^T + bias) [+ residual].
// 128x128 tile, BK=32, 4 waves 2x2. Requires 128 | grid-covered M,N; 32 | K.
template <int ACT, int OBF, int RES>
__global__ __launch_bounds__(256) void gemm_mfma(
    const u16* __restrict__ A, int lda, const u16* __restrict__ B, int ldb,
    void* __restrict__ Cv, int ldc, const float* __restrict__ bias,
    const float* __restrict__ residual, int K) {
  __shared__ __align__(16) u16 Asl[128 * 32];
  __shared__ __align__(16) u16 Bsl[128 * 32];
  int t = threadIdx.x;
  int m0 = blockIdx.y * 128, n0 = blockIdx.x * 128;
  int lane = t & 63, w = t >> 6;
  int wr = w >> 1, wc = w & 1;
  int lr = lane & 15, lg = lane >> 4;

  f32x4 acc[4][4] = {};

  const u16* Ag0 = A + (size_t)(m0 + (t >> 2)) * lda + (t & 3) * 8;
  const u16* Ag1 = A + (size_t)(m0 + 64 + (t >> 2)) * lda + (t & 3) * 8;
  const u16* Bg0 = B + (size_t)(n0 + (t >> 2)) * ldb + (t & 3) * 8;
  const u16* Bg1 = B + (size_t)(n0 + 64 + (t >> 2)) * ldb + (t & 3) * 8;
  u16* Ad0 = &Asl[t * 8];
  u16* Ad1 = &Asl[2048 + t * 8];
  u16* Bd0 = &Bsl[t * 8];
  u16* Bd1 = &Bsl[2048 + t * 8];

  for (int k0 = 0; k0 < K; k0 += 32) {
    GLDS(Ag0 + k0, Ad0);
    GLDS(Ag1 + k0, Ad1);
    GLDS(Bg0 + k0, Bd0);
    GLDS(Bg1 + k0, Bd1);
    __syncthreads();
    bf16x8 a[4], b[4];
#pragma unroll
    for (int i = 0; i < 4; i++)
      a[i] = *(const bf16x8*)&Asl[(wr * 64 + i * 16 + lr) * 32 + lg * 8];
#pragma unroll
    for (int j = 0; j < 4; j++)
      b[j] = *(const bf16x8*)&Bsl[(wc * 64 + j * 16 + lr) * 32 + lg * 8];
#pragma unroll
    for (int i = 0; i < 4; i++)
#pragma unroll
      for (int j = 0; j < 4; j++)
        asm volatile("v_mfma_f32_16x16x32_bf16 %0, %1, %2, %0"
                     : "+v"(acc[i][j])
                     : "v"(a[i]), "v"(b[j]));
    __syncthreads();
  }
  asm volatile("s_nop 7\n\ts_nop 7" ::);

  float* Cf = (float*)Cv;
  u16* Cb = (u16*)Cv;
#pragma unroll
  for (int i = 0; i < 4; i++) {
#pragma unroll
    for (int r = 0; r < 4; r++) {
      int row = m0 + wr * 64 + i * 16 + lg * 4 + r;
#pragma unroll
      for (int j = 0; j < 4; j++) {
        int col = n0 + wc * 64 + j * 16 + lr;
        float vv = acc[i][j][r];
        if (bias) vv += bias[col];
        if (ACT) vv = 0.5f * vv * (1.0f + erff(vv * 0.70710678118654752f));
        if (RES) vv += residual[(size_t)row * ldc + col];
        if (OBF) Cb[(size_t)row * ldc + col] = f2bf(vv);
        else     Cf[(size_t)row * ldc + col] = vv;
      }
    }
  }
}

// ---------------------------------------------------------------------------
// Batched variant (round-9/11/13-proven core): A += z*sAz;
// B += (BMOD ? z%HH : z)*sBz. bf16 out scaled by 0.125.
template <int BMOD>
__global__ __launch_bounds__(256) void gemm_mfma_b(
    const u16* __restrict__ A, int lda, long sAz,
    const u16* __restrict__ B, int ldb, long sBz,
    u16* __restrict__ Cb, int ldc, long sCz, int K) {
  __shared__ __align__(16) u16 Asl[128 * 32];
  __shared__ __align__(16) u16 Bsl[128 * 32];
  int z = blockIdx.z;
  A += (size_t)z * sAz;
  B += (size_t)(BMOD ? (z % HH) : z) * sBz;
  Cb += (size_t)z * sCz;
  int t = threadIdx.x;
  int m0 = blockIdx.y * 128, n0 = blockIdx.x * 128;
  int lane = t & 63, w = t >> 6;
  int wr = w >> 1, wc = w & 1;
  int lr = lane & 15, lg = lane >> 4;

  f32x4 acc[4][4] = {};

  const u16* Ag0 = A + (size_t)(m0 + (t >> 2)) * lda + (t & 3) * 8;
  const u16* Ag1 = A + (size_t)(m0 + 64 + (t >> 2)) * lda + (t & 3) * 8;
  const u16* Bg0 = B + (size_t)(n0 + (t >> 2)) * ldb + (t & 3) * 8;
  const u16* Bg1 = B + (size_t)(n0 + 64 + (t >> 2)) * ldb + (t & 3) * 8;
  u16* Ad0 = &Asl[t * 8];
  u16* Ad1 = &Asl[2048 + t * 8];
  u16* Bd0 = &Bsl[t * 8];
  u16* Bd1 = &Bsl[2048 + t * 8];

  for (int k0 = 0; k0 < K; k0 += 32) {
    GLDS(Ag0 + k0, Ad0);
    GLDS(Ag1 + k0, Ad1);
    GLDS(Bg0 + k0, Bd0);
    GLDS(Bg1 + k0, Bd1);
    __syncthreads();
    bf16x8 a[4], b[4];
#pragma unroll
    for (int i = 0; i < 4; i++)
      a[i] = *(const bf16x8*)&Asl[(wr * 64 + i * 16 + lr) * 32 + lg * 8];
#pragma unroll
    for (int j = 0; j < 4; j++)
      b[j] = *(const bf16x8*)&Bsl[(wc * 64 + j * 16 + lr) * 32 + lg * 8];
#pragma unroll
    for (int i = 0; i < 4; i++)
#pragma unroll
      for (int j = 0; j < 4; j++)
        asm volatile("v_mfma_f32_16x16x32_bf16 %0, %1, %2, %0"
                     : "+v"(acc[i][j])
                     : "v"(a[i]), "v"(b[j]));
    __syncthreads();
  }
  asm volatile("s_nop 7\n\ts_nop 7" ::);

#pragma unroll
  for (int i = 0; i < 4; i++) {
#pragma unroll
    for (int r = 0; r < 4; r++) {
      int row = m0 + wr * 64 + i * 16 + lg * 4 + r;
#pragma unroll
      for (int j = 0; j < 4; j++) {
        int col = n0 + wc * 64 + j * 16 + lr;
        Cb[(size_t)row * ldc + col] = f2bf(acc[i][j][r] * 0.125f);
      }
    }
  }
}

// ---------------------------------------------------------------------------
// Merged kp/qp kernel: z in [0,192). sel = z/96 selects (kb->kpb) vs (qb->qpb).
// Same proven core, K=64, output scaled 0.125. Grid (1, 4, 192).
__global__ __launch_bounds__(256) void gemm_mfma_pe(
    const u16* __restrict__ kbp, const u16* __restrict__ qbp,
    const u16* __restrict__ peb, u16* __restrict__ kpb,
    u16* __restrict__ qpb) {
  __shared__ __align__(16) u16 Asl[128 * 32];
  __shared__ __align__(16) u16 Bsl[128 * 32];
  int z = blockIdx.z;
  int sel = z / 96, zz = z - sel * 96;
  const u16* A = (sel ? qbp : kbp) + (size_t)zz * (LL * DHH);
  const u16* B = peb + sel * DD + (size_t)(zz % HH) * 64;
  u16* Cb = (sel ? qpb : kpb) + (size_t)zz * (LL * PP);
  const int lda = DHH, ldb = 3 * DD, ldc = PP, K = DHH;
  int t = threadIdx.x;
  int m0 = blockIdx.y * 128, n0 = 0;
  int lane = t & 63, w = t >> 6;
  int wr = w >> 1, wc = w & 1;
  int lr = lane & 15, lg = lane >> 4;

  f32x4 acc[4][4] = {};

  const u16* Ag0 = A + (size_t)(m0 + (t >> 2)) * lda + (t & 3) * 8;
  const u16* Ag1 = A + (size_t)(m0 + 64 + (t >> 2)) * lda + (t & 3) * 8;
  const u16* Bg0 = B + (size_t)(n0 + (t >> 2)) * ldb + (t & 3) * 8;
  const u16* Bg1 = B + (size_t)(n0 + 64 + (t >> 2)) * ldb + (t & 3) * 8;
  u16* Ad0 = &Asl[t * 8];
  u16* Ad1 = &Asl[2048 + t * 8];
  u16* Bd0 = &Bsl[t * 8];
  u16* Bd1 = &Bsl[2048 + t * 8];

  for (int k0 = 0; k0 < K; k0 += 32) {
    GLDS(Ag0 + k0, Ad0);
    GLDS(Ag1 + k0, Ad1);
    GLDS(Bg0 + k0, Bd0);
    GLDS(Bg1 + k0, Bd1);
    __syncthreads();
    bf16x8 a[4], b[4];
#pragma unroll
    for (int i = 0; i < 4; i++)
      a[i] = *(const bf16x8*)&Asl[(wr * 64 + i * 16 + lr) * 32 + lg * 8];
#pragma unroll
    for (int j = 0; j < 4; j++)
      b[j] = *(const bf16x8*)&Bsl[(wc * 64 + j * 16 + lr) * 32 + lg * 8];
#pragma unroll
    for (int i = 0; i < 4; i++)
#pragma unroll
      for (int j = 0; j < 4; j++)
        asm volatile("v_mfma_f32_16x16x32_bf16 %0, %1, %2, %0"
                     : "+v"(acc[i][j])
                     : "v"(a[i]), "v"(b[j]));
    __syncthreads();
  }
  asm volatile("s_nop 7\n\ts_nop 7" ::);

#pragma unroll
  for (int i = 0; i < 4; i++) {
#pragma unroll
    for (int r = 0; r < 4; r++) {
      int row = m0 + wr * 64 + i * 16 + lg * 4 + r;
#pragma unroll
      for (int j = 0; j < 4; j++) {
        int col = n0 + wc * 64 + j * 16 + lr;
        Cb[(size_t)row * ldc + col] = f2bf(acc[i][j][r] * 0.125f);
      }
    }
  }
}

// ---------------------------------------------------------------------------
// Split-K partial MFMA GEMM (round-11-proven).
__global__ __launch_bounds__(256) void gemm_mfma_part(
    const u16* __restrict__ A, int lda, const u16* __restrict__ B, int ldb,
    float* __restrict__ Cf, int ldc, long partStride, int Kper) {
  __shared__ __align__(16) u16 Asl[128 * 32];
  __shared__ __align__(16) u16 Bsl[128 * 32];
  int z = blockIdx.z;
  A += (size_t)z * Kper;
  B += (size_t)z * Kper;
  Cf += (size_t)z * partStride;
  int t = threadIdx.x;
  int m0 = blockIdx.y * 128, n0 = blockIdx.x * 128;
  int lane = t & 63, w = t >> 6;
  int wr = w >> 1, wc = w & 1;
  int lr = lane & 15, lg = lane >> 4;

  f32x4 acc[4][4] = {};

  const u16* Ag0 = A + (size_t)(m0 + (t >> 2)) * lda + (t & 3) * 8;
  const u16* Ag1 = A + (size_t)(m0 + 64 + (t >> 2)) * lda + (t & 3) * 8;
  const u16* Bg0 = B + (size_t)(n0 + (t >> 2)) * ldb + (t & 3) * 8;
  const u16* Bg1 = B + (size_t)(n0 + 64 + (t >> 2)) * ldb + (t & 3) * 8;
  u16* Ad0 = &Asl[t * 8];
  u16* Ad1 = &Asl[2048 + t * 8];
  u16* Bd0 = &Bsl[t * 8];
  u16* Bd1 = &Bsl[2048 + t * 8];

  for (int k0 = 0; k0 < Kper; k0 += 32) {
    GLDS(Ag0 + k0, Ad0);
    GLDS(Ag1 + k0, Ad1);
    GLDS(Bg0 + k0, Bd0);
    GLDS(Bg1 + k0, Bd1);
    __syncthreads();
    bf16x8 a[4], b[4];
#pragma unroll
    for (int i = 0; i < 4; i++)
      a[i] = *(const bf16x8*)&Asl[(wr * 64 + i * 16 + lr) * 32 + lg * 8];
#pragma unroll
    for (int j = 0; j < 4; j++)
      b[j] = *(const bf16x8*)&Bsl[(wc * 64 + j * 16 + lr) * 32 + lg * 8];
#pragma unroll
    for (int i = 0; i < 4; i++)
#pragma unroll
      for (int j = 0; j < 4; j++)
        asm volatile("v_mfma_f32_16x16x32_bf16 %0, %1, %2, %0"
                     : "+v"(acc[i][j])
                     : "v"(a[i]), "v"(b[j]));
    __syncthreads();
  }
  asm volatile("s_nop 7\n\ts_nop 7" ::);

#pragma unroll
  for (int i = 0; i < 4; i++) {
#pragma unroll
    for (int r = 0; r < 4; r++) {
      int row = m0 + wr * 64 + i * 16 + lg * 4 + r;
#pragma unroll
      for (int j = 0; j < 4; j++) {
        int col = n0 + wc * 64 + j * 16 + lr;
        Cf[(size_t)row * ldc + col] = acc[i][j][r];
      }
    }
  }
}

// Combine NS split-K partials: out = sum(parts) + bias + res. 4 elems/thread.
template <int NS>
__global__ __launch_bounds__(256) void combine_k(const float* __restrict__ p,
                                                 const float* __restrict__ bias,
                                                 const float* __restrict__ res,
                                                 float* __restrict__ out) {
  int idx = blockIdx.x * 256 + threadIdx.x;  // over 786,432
  size_t e = (size_t)idx * 4;
  float4 s = *(const float4*)(p + e);
#pragma unroll
  for (int z = 1; z < NS; z++) {
    float4 t2 = *(const float4*)(p + (size_t)z * 3145728 + e);
    s.x += t2.x; s.y += t2.y; s.z += t2.z; s.w += t2.w;
  }
  int col = (int)(e % DD);
  float4 b4 = *(const float4*)(bias + col);
  float4 r4 = *(const float4*)(res + e);
  *(float4*)(out + e) = make_float4(s.x + b4.x + r4.x, s.y + b4.y + r4.y,
                                    s.z + b4.z + r4.z, s.w + b4.w + r4.w);
}

// Fused combine_k<2> + LayerNorm: one block per row.
// x1 = p0 + p1 + bias + res;  xnb = LN(x1, w, b) bf16.
__global__ __launch_bounds__(256) void combine2_ln(
    const float* __restrict__ p, const float* __restrict__ bias,
    const float* __restrict__ res, float* __restrict__ x1,
    const float* __restrict__ w, const float* __restrict__ lb,
    u16* __restrict__ xnb) {
  __shared__ float sbuf[8];
  size_t row = blockIdx.x;
  int t = threadIdx.x;
  const float* p0 = p + row * DD;
  const float* p1 = p + 3145728 + row * DD;
  const float* rr = res + row * DD;
  float v0 = p0[t]       + p1[t]       + bias[t]       + rr[t];
  float v1 = p0[t + 256] + p1[t + 256] + bias[t + 256] + rr[t + 256];
  float v2 = p0[t + 512] + p1[t + 512] + bias[t + 512] + rr[t + 512];
  float* xr = x1 + row * DD;
  xr[t] = v0; xr[t + 256] = v1; xr[t + 512] = v2;
  float s = v0 + v1 + v2;
  float ss = v0 * v0 + v1 * v1 + v2 * v2;
  block_reduce2(s, ss, sbuf);
  float mu = s * (1.0f / DD);
  float var = ss * (1.0f / DD) - mu * mu;
  float r = rsqrtf(var + 1e-5f);
  u16* orow = xnb + row * DD;
  orow[t]       = f2bf((v0 - mu) * r * w[t]       + lb[t]);
  orow[t + 256] = f2bf((v1 - mu) * r * w[t + 256] + lb[t + 256]);
  orow[t + 512] = f2bf((v2 - mu) * r * w[t + 512] + lb[t + 512]);
}

// ---------------------------------------------------------------------------
// qkv bf16 [L*B, 3D] -> qb,kb bf16 [B,H,L,Dh] + vbT bf16 [B,H,Dh,L]
__global__ __launch_bounds__(256) void split_qkv6(const u16* __restrict__ qkvb,
                                                  u16* __restrict__ qb,
                                                  u16* __restrict__ kb,
                                                  u16* __restrict__ vbT) {
  int idx = blockIdx.x * 256 + threadIdx.x;  // over 786,432
  int d4 = idx & 15;
  int l = (idx >> 4) & 511;
  int bh = idx >> 13;
  int b = bh / HH, h = bh - b * HH;
  size_t src = ((size_t)(l * BB + b)) * (3 * DD) + h * 64 + d4 * 4;
  uint2 qv = *(const uint2*)(qkvb + src);
  uint2 kv = *(const uint2*)(qkvb + src + DD);
  uint2 vv = *(const uint2*)(qkvb + src + 2 * DD);
  size_t dst = (size_t)idx * 4;
  *(uint2*)(qb + dst) = qv;
  *(uint2*)(kb + dst) = kv;
  u16 v0 = (u16)(vv.x & 0xffff), v1 = (u16)(vv.x >> 16);
  u16 v2 = (u16)(vv.y & 0xffff), v3 = (u16)(vv.y >> 16);
  size_t vtb = ((size_t)bh * DHH + d4 * 4) * LL + l;
  vbT[vtb]          = v0;
  vbT[vtb + LL]     = v1;
  vbT[vtb + 2 * LL] = v2;
  vbT[vtb + 3 * LL] = v3;
}

// ---------------------------------------------------------------------------
// Streaming gather: eout = t' + kp' + qp' + edge (inputs pre-scaled 0.125),
// + per-tile stats. kpl/qpl staged via async GLDS (linear dest). 32KB LDS.
__global__ __launch_bounds__(256) void gather_scale2(
    const u16* __restrict__ tb,
    const u16* __restrict__ kp, const u16* __restrict__ qp,
    const u8* __restrict__ bdT, const float* __restrict__ edge,
    float* __restrict__ eout, float* __restrict__ stats) {
  int bh = blockIdx.z, b = bh / HH;
  int i0 = blockIdx.y * 64, j0 = blockIdx.x * 64, jt = blockIdx.x;
  __shared__ __align__(16) u16 kpl[64][PP];
  __shared__ __align__(16) u16 qpl[64][PP];
  int tid = threadIdx.x;
  int tx = tid & 15, ty = tid >> 4;

  const u16* kpg = kp + (size_t)bh * (LL * PP);
  const u16* qpg = qp + (size_t)bh * (LL * PP);
  u16* kflat = &kpl[0][0];
  u16* qflat = &qpl[0][0];
#pragma unroll
  for (int it = 0; it < 4; it++) {
    int c = tid + it * 256;
    int row = c >> 4, ch = (c & 15) * 8;
    GLDS(&kpg[(size_t)(j0 + row) * PP + ch], &kflat[c * 8]);
    GLDS(&qpg[(size_t)(i0 + row) * PP + ch], &qflat[c * 8]);
  }
  __syncthreads();

  const u8* bd = bdT + (size_t)b * (LL * LL);
  const float* eb = edge + (size_t)bh * (LL * LL);
  const u16* tbb = tb + (size_t)bh * (LL * LL);
  float* ob = eout + (size_t)bh * (LL * LL);

  float rowm[4], rows[4];
#pragma unroll
  for (int i2 = 0; i2 < 4; i2++) {
    int row = i0 + ty * 4 + i2;
    int col0 = j0 + tx * 4;
    uchar4 p4 = *(const uchar4*)&bd[(size_t)row * LL + col0];
    float4 e4 = *(const float4*)&eb[(size_t)row * LL + col0];
    uint2 t2 = *(const uint2*)&tbb[(size_t)row * LL + col0];
    float tv[4] = {bf2f(t2.x), bf2f(t2.x >> 16), bf2f(t2.y), bf2f(t2.y >> 16)};
    int pp[4] = {p4.x, p4.y, p4.z, p4.w};
    float ee[4] = {e4.x, e4.y, e4.z, e4.w};
    float sv[4];
#pragma unroll
    for (int j2 = 0; j2 < 4; j2++) {
      float gk = bf2f((u32)kpl[tx * 4 + j2][pp[j2]]);
      float gq = bf2f((u32)qpl[ty * 4 + i2][pp[j2]]);
      sv[j2] = tv[j2] + gk + gq + ee[j2];
    }
    *(float4*)&ob[(size_t)row * LL + col0] =
        make_float4(sv[0], sv[1], sv[2], sv[3]);
    float m = fmaxf(fmaxf(sv[0], sv[1]), fmaxf(sv[2], sv[3]));
#pragma unroll
    for (int off = 1; off < 16; off <<= 1) m = fmaxf(m, __shfl_xor(m, off, 64));
    float ss = expf(sv[0] - m) + expf(sv[1] - m) + expf(sv[2] - m) + expf(sv[3] - m);
#pragma unroll
    for (int off = 1; off < 16; off <<= 1) ss += __shfl_xor(ss, off, 64);
    rowm[i2] = m;
    rows[i2] = ss;
  }
  if (tx == 0) {
#pragma unroll
    for (int i2 = 0; i2 < 4; i2++) {
      size_t si = ((size_t)bh * LL + i0 + ty * 4 + i2) * 16 + jt;
      stats[si] = rowm[i2];
      stats[si + 8] = rows[i2];
    }
  }
}

// ---------------------------------------------------------------------------
// MFMA softmax+PV (round-14-proven): per (bh, 64-row i-tile).
__global__ __launch_bounds__(256) void softmax_pv_mfma(
    const float* __restrict__ scores, const u16* __restrict__ vbT,
    const float* __restrict__ stats, u16* __restrict__ olbd) {
  int bh = blockIdx.y;
  int i0 = blockIdx.x * 64;
  int b = bh / HH, h = bh - b * HH;
  __shared__ __align__(16) u16 PL[2][64 * 32];
  __shared__ __align__(16) u16 VL[2][64 * 32];
  __shared__ float smax[64], srs[64];
  int tid = threadIdx.x;
  int tx = tid & 15, ty = tid >> 4;
  int lane = tid & 63, w = tid >> 6;
  int wr = w >> 1, wc = w & 1;
  int lr = lane & 15, lg = lane >> 4;
  const float* sbase = scores + (size_t)bh * (LL * LL);
  const u16* vt = vbT + (size_t)bh * (DHH * LL);

  if (tid < 64) {
    size_t si = ((size_t)bh * LL + i0 + tid) * 16;
    float m = stats[si];
#pragma unroll
    for (int j = 1; j < 8; j++) m = fmaxf(m, stats[si + j]);
    float s = 0.f;
#pragma unroll
    for (int j = 0; j < 8; j++) s += stats[si + 8 + j] * expf(stats[si + j] - m);
    smax[tid] = m;
    srs[tid] = 1.0f / s;
  }
  __syncthreads();

  f32x4 acc[2][2] = {};
  int ks = tx >> 3, kk = (tx & 7) * 4;
  int vd = tid >> 2, vjo = (tid & 3) * 8;

  for (int jt = 0; jt < 8; jt++) {
    int j0 = jt * 64;
    GLDS(vt + (size_t)vd * LL + j0 + vjo, &VL[0][tid * 8]);
    GLDS(vt + (size_t)vd * LL + j0 + 32 + vjo, &VL[1][tid * 8]);
#pragma unroll
    for (int rr = 0; rr < 4; rr++) {
      int r = ty + rr * 16;
      float4 s4 = *(const float4*)(sbase + (size_t)(i0 + r) * LL + j0 + tx * 4);
      float m = smax[r], rs = srs[r];
      u16 p0 = f2bf(expf(s4.x - m) * rs);
      u16 p1 = f2bf(expf(s4.y - m) * rs);
      u16 p2 = f2bf(expf(s4.z - m) * rs);
      u16 p3 = f2bf(expf(s4.w - m) * rs);
      *(uint2*)&PL[ks][r * 32 + kk] =
          make_uint2((u32)p0 | ((u32)p1 << 16), (u32)p2 | ((u32)p3 << 16));
    }
    __syncthreads();
#pragma unroll
    for (int s2 = 0; s2 < 2; s2++) {
      bf16x8 a[2], bfr[2];
#pragma unroll
      for (int i = 0; i < 2; i++)
        a[i] = *(const bf16x8*)&PL[s2][(wr * 32 + i * 16 + lr) * 32 + lg * 8];
#pragma unroll
      for (int j = 0; j < 2; j++)
        bfr[j] = *(const bf16x8*)&VL[s2][(wc * 32 + j * 16 + lr) * 32 + lg * 8];
#pragma unroll
      for (int i = 0; i < 2; i++)
#pragma unroll
        for (int j = 0; j < 2; j++)
          asm volatile("v_mfma_f32_16x16x32_bf16 %0, %1, %2, %0"
                       : "+v"(acc[i][j])
                       : "v"(a[i]), "v"(bfr[j]));
    }
    __syncthreads();
  }
  asm volatile("s_nop 7\n\ts_nop 7" ::);

#pragma unroll
  for (int i = 0; i < 2; i++) {
#pragma unroll
    for (int r = 0; r < 4; r++) {
      int irow = i0 + wr * 32 + i * 16 + lg * 4 + r;
#pragma unroll
      for (int j = 0; j < 2; j++) {
        int d = wc * 32 + j * 16 + lr;
        olbd[((size_t)irow * BB + b) * DD + h * 64 + d] = f2bf(acc[i][j][r]);
      }
    }
  }
}

// ---------------------------------------------------------------------------
extern "C" void kernel_launch(void* const* d_in, const int* in_sizes, int n_in,
                              void* d_out, int out_size, void* d_ws, size_t ws_size,
                              hipStream_t stream) {
  const float* x      = (const float*)d_in[0];
  const float* edge   = (const float*)d_in[1];
  const int*   bdist  = (const int*)d_in[2];
  const float* W_in   = (const float*)d_in[3];
  const float* b_in   = (const float*)d_in[4];
  const float* pe_emb = (const float*)d_in[5];
  const float* W_out  = (const float*)d_in[6];
  const float* b_out  = (const float*)d_in[7];
  const float* W1     = (const float*)d_in[8];
  const float* b1     = (const float*)d_in[9];
  const float* W2     = (const float*)d_in[10];
  const float* b2     = (const float*)d_in[11];
  const float* ln1w   = (const float*)d_in[12];
  const float* ln1b   = (const float*)d_in[13];
  const float* ln2w   = (const float*)d_in[14];
  const float* ln2b   = (const float*)d_in[15];

  float* xout = (float*)d_out;                 // [L,B,D]
  float* eout = xout + (size_t)LL * BB * DD;   // [B*H,L,L] == final scores

  // Workspace layout (float units). Max used: ~37.35M floats = 149.4 MB.
  float* ws = (float*)d_ws;
  u16*   xnb    = (u16*)(ws + 0);          // [4096,768] bf16
  u16*   qkvb   = (u16*)(ws + 1600000);    // [4096,2304] bf16
  u16*   tb     = (u16*)(ws + 1600000);    // t' bf16 [96,512,512] (reuse)
  u16*   olbdb  = (u16*)(ws + 1600000);    // bf16 O (written step 8)
  u16*   ff1b   = (u16*)(ws + 3200000);    // [4096,3072] bf16 (step 11)
  float* x1     = ws + 11100000;           // (step 9)
  u16*   peemb  = (u16*)(ws + 14300000);   // [128,768] bf16
  float* part   = ws + 14600000;           // split-K partials
  u16*   vbT    = (u16*)(ws + 21000000);   // [96,64,512] bf16 transposed V
  float* stats  = ws + 22600000;           // [96,512,16]
  u8*    bdT    = (u8*)(ws + 23400000);    // [8,512,512] u8
  u16*   kpb    = (u16*)(ws + 24000000);   // [96,512,128] bf16
  u16*   qpb    = (u16*)(ws + 27200000);
  u16*   W1b    = (u16*)(ws + 30400000);
  u16*   W2b    = (u16*)(ws + 31600000);
  u16*   W_inb  = (u16*)(ws + 32800000);
  u16*   W_outb = (u16*)(ws + 33700000);
  u16*   qb     = (u16*)(ws + 34000000);
  u16*   kb     = (u16*)(ws + 35600000);
  u16*   peb    = (u16*)(ws + 37200000);   // [128,2304] bf16

  // 0) weight conversions (one launch) + pe_emb bf16 + bdist transpose
  f2b4_kernel<<<6912, 256, 0, stream>>>(W_in, W_inb, W_out, W_outb, W1, W1b,
                                        W2, W2b);
  f2b_kernel<<<96, 256, 0, stream>>>(pe_emb, peemb);
  bdist_t<<<8192, 256, 0, stream>>>(bdist, bdT);
  // 1) LN1 -> bf16
  ln_bf16<<<4096, 256, 0, stream>>>(x, ln1w, ln1b, xnb);
  // 2) qkv = xn @ W_in^T + b_in  (MFMA, bf16 out)
  gemm_mfma<0, 1, 0><<<dim3(18, 32), 256, 0, stream>>>(
      xnb, DD, W_inb, DD, qkvb, 3 * DD, b_in, nullptr, DD);
  // 3) pe_proj = pe_emb @ W_in^T + b_in (MFMA, M=128, bf16 out)
  gemm_mfma<0, 1, 0><<<dim3(18, 1), 256, 0, stream>>>(
      peemb, DD, W_inb, DD, peb, 3 * DD, b_in, nullptr, DD);
  // 4) split -> qb,kb bf16 + vbT transposed
  split_qkv6<<<3072, 256, 0, stream>>>(qkvb, qb, kb, vbT);
  // 5) kp'/qp' merged (batched MFMA, z<96 -> kp, z>=96 -> qp)
  gemm_mfma_pe<<<dim3(1, 4, 192), 256, 0, stream>>>(kb, qb, peb, kpb, qpb);
  // 6) t' = (q @ k^T)/8 per head -> tb bf16
  gemm_mfma_b<0><<<dim3(4, 4, 96), 256, 0, stream>>>(
      qb, DHH, (long)LL * DHH, kb, DHH, (long)LL * DHH, tb, LL, (long)LL * LL,
      DHH);
  // 7) eout = t' + kp' + qp' + edge, + softmax tile stats (streaming)
  gather_scale2<<<dim3(8, 8, 96), 256, 0, stream>>>(tb, kpb, qpb, bdT, edge,
                                                    eout, stats);
  // 8) MFMA softmax + PV -> olbd bf16 [L,B,D]
  softmax_pv_mfma<<<dim3(8, 96), 256, 0, stream>>>(eout, vbT, stats, olbdb);
  // 9) x1 = O @ W_out^T + b_out + x (split-K=2) + fused combine+LN2
  gemm_mfma_part<<<dim3(6, 32, 2), 256, 0, stream>>>(
      olbdb, DD, W_outb, DD, part, DD, 3145728L, DD / 2);
  combine2_ln<<<4096, 256, 0, stream>>>(part, b_out, x, x1, ln2w, ln2b, xnb);
  // 10) ff1 = gelu(xn @ W1^T + b1) (bf16 out)
  gemm_mfma<1, 1, 0><<<dim3(24, 32), 256, 0, stream>>>(
      xnb, DD, W1b, DD, ff1b, 4 * DD, b1, nullptr, DD);
  // 11) x_out = ff1 @ W2^T + b2 + x1  (split-K=4 + combine)
  gemm_mfma_part<<<dim3(6, 32, 4), 256, 0, stream>>>(
      ff1b, 4 * DD, W2b, 4 * DD, part, DD, 3145728L, DD);
  combine_k<4><<<3072, 256, 0, stream>>>(part, b2, x1, xout);
}

// Round 16
// 328.838 us; speedup vs baseline: 1.7100x; 1.0426x over previous
//
#include <hip/hip_runtime.h>
#include <hip/hip_bf16.h>
#include <math.h>

// Problem constants
#define LL 512
#define BB 8
#define DD 768
#define HH 12
#define DHH 64
#define PP 128

typedef unsigned char u8;
typedef unsigned short u16;
typedef unsigned int u32;
typedef __attribute__((ext_vector_type(8))) short bf16x8;
typedef __attribute__((ext_vector_type(4))) float f32x4;

__device__ __forceinline__ u16 f2bf(float f) {
  u32 u = __float_as_uint(f);
  u32 r = (u + 0x7fffu + ((u >> 16) & 1u)) >> 16;
  return (u16)r;
}
__device__ __forceinline__ float bf2f(u32 u) {
  return __uint_as_float((u & 0xffffu) << 16);
}

#define GLDS(g, l)                                                             \
  __builtin_amdgcn_global_load_lds(                                            \
      (const __attribute__((address_space(1))) void*)(g),                      \
      (__attribute__((address_space(3))) void*)(l), 16, 0, 0)

// ---------------------------------------------------------------------------
__device__ __forceinline__ void block_reduce2(float& a, float& b, float* sbuf) {
#pragma unroll
  for (int off = 32; off > 0; off >>= 1) {
    a += __shfl_down(a, off, 64);
    b += __shfl_down(b, off, 64);
  }
  int wid = threadIdx.x >> 6, lane = threadIdx.x & 63;
  __syncthreads();
  if (lane == 0) { sbuf[wid] = a; sbuf[4 + wid] = b; }
  __syncthreads();
  a = sbuf[0] + sbuf[1] + sbuf[2] + sbuf[3];
  b = sbuf[4] + sbuf[5] + sbuf[6] + sbuf[7];
}

// ---------------------------------------------------------------------------
// Mega-prep: [0,4096) LN1 rows; [4096,11008) weight f2b (4 ranges);
// [11008,11104) pe_emb f2b; [11104,19296) bdist transpose.
__global__ __launch_bounds__(256) void prep_kernel(
    const float* __restrict__ x, const float* __restrict__ ln1w,
    const float* __restrict__ ln1b, u16* __restrict__ xnb,
    const float* __restrict__ W_in, u16* __restrict__ W_inb,
    const float* __restrict__ W_out, u16* __restrict__ W_outb,
    const float* __restrict__ W1, u16* __restrict__ W1b,
    const float* __restrict__ W2, u16* __restrict__ W2b,
    const float* __restrict__ pe_emb, u16* __restrict__ peemb,
    const int* __restrict__ bdist, u8* __restrict__ bdT) {
  int blk = blockIdx.x;
  int t = threadIdx.x;
  if (blk < 4096) {
    // LN1, one block per row
    __shared__ float sbuf[8];
    const float* xr = x + (size_t)blk * DD;
    float v0 = xr[t], v1 = xr[t + 256], v2 = xr[t + 512];
    float s = v0 + v1 + v2;
    float ss = v0 * v0 + v1 * v1 + v2 * v2;
    block_reduce2(s, ss, sbuf);
    float mu = s * (1.0f / DD);
    float var = ss * (1.0f / DD) - mu * mu;
    float r = rsqrtf(var + 1e-5f);
    u16* orow = xnb + (size_t)blk * DD;
    orow[t]       = f2bf((v0 - mu) * r * ln1w[t]       + ln1b[t]);
    orow[t + 256] = f2bf((v1 - mu) * r * ln1w[t + 256] + ln1b[t + 256]);
    orow[t + 512] = f2bf((v2 - mu) * r * ln1w[t + 512] + ln1b[t + 512]);
  } else if (blk < 11008) {
    // weight conversions, 4-element groups
    int idx = (blk - 4096) * 256 + t;  // 0..1769471
    const float* in;
    u16* out;
    if (idx < 442368) { in = W_in; out = W_inb; }
    else if (idx < 589824) { in = W_out; out = W_outb; idx -= 442368; }
    else if (idx < 1179648) { in = W1; out = W1b; idx -= 589824; }
    else { in = W2; out = W2b; idx -= 1179648; }
    float4 v = *(const float4*)(in + (size_t)idx * 4);
    u32 lo = (u32)f2bf(v.x) | ((u32)f2bf(v.y) << 16);
    u32 hi = (u32)f2bf(v.z) | ((u32)f2bf(v.w) << 16);
    *(uint2*)(out + (size_t)idx * 4) = make_uint2(lo, hi);
  } else if (blk < 11104) {
    int idx = (blk - 11008) * 256 + t;  // 0..24575
    float4 v = *(const float4*)(pe_emb + (size_t)idx * 4);
    u32 lo = (u32)f2bf(v.x) | ((u32)f2bf(v.y) << 16);
    u32 hi = (u32)f2bf(v.z) | ((u32)f2bf(v.w) << 16);
    *(uint2*)(peemb + (size_t)idx * 4) = make_uint2(lo, hi);
  } else {
    int i = (blk - 11104) * 256 + t;  // 0..2097151
    int b = i & 7, jj = (i >> 3) & 511, ii = i >> 12;
    bdT[((size_t)b << 18) + ((size_t)ii << 9) + jj] = (u8)bdist[i];
  }
}

// ---------------------------------------------------------------------------
// bf16 MFMA GEMM (round-3-proven): C = act(A * B^T + bias) [+ residual].
// 128x128 tile, BK=32, 4 waves 2x2. Requires 128 | grid-covered M,N; 32 | K.
template <int ACT, int OBF, int RES>
__global__ __launch_bounds__(256) void gemm_mfma(
    const u16* __restrict__ A, int lda, const u16* __restrict__ B, int ldb,
    void* __restrict__ Cv, int ldc, const float* __restrict__ bias,
    const float* __restrict__ residual, int K) {
  __shared__ __align__(16) u16 Asl[128 * 32];
  __shared__ __align__(16) u16 Bsl[128 * 32];
  int t = threadIdx.x;
  int m0 = blockIdx.y * 128, n0 = blockIdx.x * 128;
  int lane = t & 63, w = t >> 6;
  int wr = w >> 1, wc = w & 1;
  int lr = lane & 15, lg = lane >> 4;

  f32x4 acc[4][4] = {};

  const u16* Ag0 = A + (size_t)(m0 + (t >> 2)) * lda + (t & 3) * 8;
  const u16* Ag1 = A + (size_t)(m0 + 64 + (t >> 2)) * lda + (t & 3) * 8;
  const u16* Bg0 = B + (size_t)(n0 + (t >> 2)) * ldb + (t & 3) * 8;
  const u16* Bg1 = B + (size_t)(n0 + 64 + (t >> 2)) * ldb + (t & 3) * 8;
  u16* Ad0 = &Asl[t * 8];
  u16* Ad1 = &Asl[2048 + t * 8];
  u16* Bd0 = &Bsl[t * 8];
  u16* Bd1 = &Bsl[2048 + t * 8];

  for (int k0 = 0; k0 < K; k0 += 32) {
    GLDS(Ag0 + k0, Ad0);
    GLDS(Ag1 + k0, Ad1);
    GLDS(Bg0 + k0, Bd0);
    GLDS(Bg1 + k0, Bd1);
    __syncthreads();
    bf16x8 a[4], b[4];
#pragma unroll
    for (int i = 0; i < 4; i++)
      a[i] = *(const bf16x8*)&Asl[(wr * 64 + i * 16 + lr) * 32 + lg * 8];
#pragma unroll
    for (int j = 0; j < 4; j++)
      b[j] = *(const bf16x8*)&Bsl[(wc * 64 + j * 16 + lr) * 32 + lg * 8];
#pragma unroll
    for (int i = 0; i < 4; i++)
#pragma unroll
      for (int j = 0; j < 4; j++)
        asm volatile("v_mfma_f32_16x16x32_bf16 %0, %1, %2, %0"
                     : "+v"(acc[i][j])
                     : "v"(a[i]), "v"(b[j]));
    __syncthreads();
  }
  asm volatile("s_nop 7\n\ts_nop 7" ::);

  float* Cf = (float*)Cv;
  u16* Cb = (u16*)Cv;
#pragma unroll
  for (int i = 0; i < 4; i++) {
#pragma unroll
    for (int r = 0; r < 4; r++) {
      int row = m0 + wr * 64 + i * 16 + lg * 4 + r;
#pragma unroll
      for (int j = 0; j < 4; j++) {
        int col = n0 + wc * 64 + j * 16 + lr;
        float vv = acc[i][j][r];
        if (bias) vv += bias[col];
        if (ACT) vv = 0.5f * vv * (1.0f + erff(vv * 0.70710678118654752f));
        if (RES) vv += residual[(size_t)row * ldc + col];
        if (OBF) Cb[(size_t)row * ldc + col] = f2bf(vv);
        else     Cf[(size_t)row * ldc + col] = vv;
      }
    }
  }
}

// ---------------------------------------------------------------------------
// qkv GEMM with layout-transforming epilogue: A=xnb [4096,768], B=W_inb
// [2304,768], bias=b_in. q/k written directly to [B,H,L,Dh] bf16; v -> vtmp
// linear [4096,768] bf16. Same proven core; grid (18,32).
__global__ __launch_bounds__(256) void gemm_mfma_qkv(
    const u16* __restrict__ A, const u16* __restrict__ B,
    const float* __restrict__ bias, u16* __restrict__ qb,
    u16* __restrict__ kb, u16* __restrict__ vtmp) {
  __shared__ __align__(16) u16 Asl[128 * 32];
  __shared__ __align__(16) u16 Bsl[128 * 32];
  const int lda = DD, ldb = DD, K = DD;
  int t = threadIdx.x;
  int m0 = blockIdx.y * 128, n0 = blockIdx.x * 128;
  int lane = t & 63, w = t >> 6;
  int wr = w >> 1, wc = w & 1;
  int lr = lane & 15, lg = lane >> 4;

  f32x4 acc[4][4] = {};

  const u16* Ag0 = A + (size_t)(m0 + (t >> 2)) * lda + (t & 3) * 8;
  const u16* Ag1 = A + (size_t)(m0 + 64 + (t >> 2)) * lda + (t & 3) * 8;
  const u16* Bg0 = B + (size_t)(n0 + (t >> 2)) * ldb + (t & 3) * 8;
  const u16* Bg1 = B + (size_t)(n0 + 64 + (t >> 2)) * ldb + (t & 3) * 8;
  u16* Ad0 = &Asl[t * 8];
  u16* Ad1 = &Asl[2048 + t * 8];
  u16* Bd0 = &Bsl[t * 8];
  u16* Bd1 = &Bsl[2048 + t * 8];

  for (int k0 = 0; k0 < K; k0 += 32) {
    GLDS(Ag0 + k0, Ad0);
    GLDS(Ag1 + k0, Ad1);
    GLDS(Bg0 + k0, Bd0);
    GLDS(Bg1 + k0, Bd1);
    __syncthreads();
    bf16x8 a[4], b[4];
#pragma unroll
    for (int i = 0; i < 4; i++)
      a[i] = *(const bf16x8*)&Asl[(wr * 64 + i * 16 + lr) * 32 + lg * 8];
#pragma unroll
    for (int j = 0; j < 4; j++)
      b[j] = *(const bf16x8*)&Bsl[(wc * 64 + j * 16 + lr) * 32 + lg * 8];
#pragma unroll
    for (int i = 0; i < 4; i++)
#pragma unroll
      for (int j = 0; j < 4; j++)
        asm volatile("v_mfma_f32_16x16x32_bf16 %0, %1, %2, %0"
                     : "+v"(acc[i][j])
                     : "v"(a[i]), "v"(b[j]));
    __syncthreads();
  }
  asm volatile("s_nop 7\n\ts_nop 7" ::);

#pragma unroll
  for (int i = 0; i < 4; i++) {
#pragma unroll
    for (int r = 0; r < 4; r++) {
      int row = m0 + wr * 64 + i * 16 + lg * 4 + r;
      int l = row >> 3, b = row & 7;
#pragma unroll
      for (int j = 0; j < 4; j++) {
        int col = n0 + wc * 64 + j * 16 + lr;
        u16 vv = f2bf(acc[i][j][r] + bias[col]);
        int which = col / DD, hd = col - which * DD;
        if (which == 0) {
          int h = hd >> 6, d = hd & 63;
          qb[(((size_t)(b * HH + h)) * LL + l) * DHH + d] = vv;
        } else if (which == 1) {
          int h = hd >> 6, d = hd & 63;
          kb[(((size_t)(b * HH + h)) * LL + l) * DHH + d] = vv;
        } else {
          vtmp[(size_t)row * DD + hd] = vv;
        }
      }
    }
  }
}

// ---------------------------------------------------------------------------
// vtmp [4096,768] bf16 -> vbT [B*H, Dh, L] bf16
__global__ __launch_bounds__(256) void split_v(const u16* __restrict__ vtmp,
                                               u16* __restrict__ vbT) {
  int idx = blockIdx.x * 256 + threadIdx.x;  // over 786,432 groups of 4
  int d4 = idx & 15;
  int l = (idx >> 4) & 511;
  int bh = idx >> 13;
  int b = bh / HH, h = bh - b * HH;
  size_t src = ((size_t)(l * BB + b)) * DD + h * 64 + d4 * 4;
  uint2 vv = *(const uint2*)(vtmp + src);
  u16 v0 = (u16)(vv.x & 0xffff), v1 = (u16)(vv.x >> 16);
  u16 v2 = (u16)(vv.y & 0xffff), v3 = (u16)(vv.y >> 16);
  size_t vtb = ((size_t)bh * DHH + d4 * 4) * LL + l;
  vbT[vtb]          = v0;
  vbT[vtb + LL]     = v1;
  vbT[vtb + 2 * LL] = v2;
  vbT[vtb + 3 * LL] = v3;
}

// ---------------------------------------------------------------------------
// Merged K=64 batched MFMA (proven core): flat grid 2304 blocks.
// id<768: kp/qp (sel=z/96): A=(sel?qb:kb)+zz*LH, B=peb+sel*768+(zz%12)*64
//   (ldb 2304), C=(sel?qpb:kpb)+zz*LP (ldc 128), m0=(id&3)*128, n0=0.
// id>=768: QK^T: id2=id-768, jx=id2&3, my=(id2>>2)&3, bh=id2>>4;
//   A=qb+bh*LH, B=kb+bh*LH (lda/ldb 64), C=tb+bh*LL*LL (ldc 512).
// Output bf16 scaled by 0.125.
__global__ __launch_bounds__(256) void attn_k64(
    const u16* __restrict__ qb, const u16* __restrict__ kb,
    const u16* __restrict__ peb, u16* __restrict__ kpb,
    u16* __restrict__ qpb, u16* __restrict__ tb) {
  __shared__ __align__(16) u16 Asl[128 * 32];
  __shared__ __align__(16) u16 Bsl[128 * 32];
  int id = blockIdx.x;
  const u16 *A, *B;
  u16* Cb;
  int lda, ldb, ldc, m0, n0;
  if (id < 768) {
    int my = id & 3, z = id >> 2;
    int sel = z / 96, zz = z - sel * 96;
    A = (sel ? qb : kb) + (size_t)zz * (LL * DHH);
    B = peb + sel * DD + (size_t)(zz % HH) * 64;
    Cb = (sel ? qpb : kpb) + (size_t)zz * (LL * PP);
    lda = DHH; ldb = 3 * DD; ldc = PP; m0 = my * 128; n0 = 0;
  } else {
    int id2 = id - 768;
    int jx = id2 & 3, my = (id2 >> 2) & 3, bh = id2 >> 4;
    A = qb + (size_t)bh * (LL * DHH);
    B = kb + (size_t)bh * (LL * DHH);
    Cb = tb + (size_t)bh * (LL * LL);
    lda = DHH; ldb = DHH; ldc = LL; m0 = my * 128; n0 = jx * 128;
  }
  int t = threadIdx.x;
  int lane = t & 63, w = t >> 6;
  int wr = w >> 1, wc = w & 1;
  int lr = lane & 15, lg = lane >> 4;

  f32x4 acc[4][4] = {};

  const u16* Ag0 = A + (size_t)(m0 + (t >> 2)) * lda + (t & 3) * 8;
  const u16* Ag1 = A + (size_t)(m0 + 64 + (t >> 2)) * lda + (t & 3) * 8;
  const u16* Bg0 = B + (size_t)(n0 + (t >> 2)) * ldb + (t & 3) * 8;
  const u16* Bg1 = B + (size_t)(n0 + 64 + (t >> 2)) * ldb + (t & 3) * 8;
  u16* Ad0 = &Asl[t * 8];
  u16* Ad1 = &Asl[2048 + t * 8];
  u16* Bd0 = &Bsl[t * 8];
  u16* Bd1 = &Bsl[2048 + t * 8];

  for (int k0 = 0; k0 < DHH; k0 += 32) {
    GLDS(Ag0 + k0, Ad0);
    GLDS(Ag1 + k0, Ad1);
    GLDS(Bg0 + k0, Bd0);
    GLDS(Bg1 + k0, Bd1);
    __syncthreads();
    bf16x8 a[4], b[4];
#pragma unroll
    for (int i = 0; i < 4; i++)
      a[i] = *(const bf16x8*)&Asl[(wr * 64 + i * 16 + lr) * 32 + lg * 8];
#pragma unroll
    for (int j = 0; j < 4; j++)
      b[j] = *(const bf16x8*)&Bsl[(wc * 64 + j * 16 + lr) * 32 + lg * 8];
#pragma unroll
    for (int i = 0; i < 4; i++)
#pragma unroll
      for (int j = 0; j < 4; j++)
        asm volatile("v_mfma_f32_16x16x32_bf16 %0, %1, %2, %0"
                     : "+v"(acc[i][j])
                     : "v"(a[i]), "v"(b[j]));
    __syncthreads();
  }
  asm volatile("s_nop 7\n\ts_nop 7" ::);

#pragma unroll
  for (int i = 0; i < 4; i++) {
#pragma unroll
    for (int r = 0; r < 4; r++) {
      int row = m0 + wr * 64 + i * 16 + lg * 4 + r;
#pragma unroll
      for (int j = 0; j < 4; j++) {
        int col = n0 + wc * 64 + j * 16 + lr;
        Cb[(size_t)row * ldc + col] = f2bf(acc[i][j][r] * 0.125f);
      }
    }
  }
}

// ---------------------------------------------------------------------------
// Split-K partial MFMA GEMM (round-11-proven).
__global__ __launch_bounds__(256) void gemm_mfma_part(
    const u16* __restrict__ A, int lda, const u16* __restrict__ B, int ldb,
    float* __restrict__ Cf, int ldc, long partStride, int Kper) {
  __shared__ __align__(16) u16 Asl[128 * 32];
  __shared__ __align__(16) u16 Bsl[128 * 32];
  int z = blockIdx.z;
  A += (size_t)z * Kper;
  B += (size_t)z * Kper;
  Cf += (size_t)z * partStride;
  int t = threadIdx.x;
  int m0 = blockIdx.y * 128, n0 = blockIdx.x * 128;
  int lane = t & 63, w = t >> 6;
  int wr = w >> 1, wc = w & 1;
  int lr = lane & 15, lg = lane >> 4;

  f32x4 acc[4][4] = {};

  const u16* Ag0 = A + (size_t)(m0 + (t >> 2)) * lda + (t & 3) * 8;
  const u16* Ag1 = A + (size_t)(m0 + 64 + (t >> 2)) * lda + (t & 3) * 8;
  const u16* Bg0 = B + (size_t)(n0 + (t >> 2)) * ldb + (t & 3) * 8;
  const u16* Bg1 = B + (size_t)(n0 + 64 + (t >> 2)) * ldb + (t & 3) * 8;
  u16* Ad0 = &Asl[t * 8];
  u16* Ad1 = &Asl[2048 + t * 8];
  u16* Bd0 = &Bsl[t * 8];
  u16* Bd1 = &Bsl[2048 + t * 8];

  for (int k0 = 0; k0 < Kper; k0 += 32) {
    GLDS(Ag0 + k0, Ad0);
    GLDS(Ag1 + k0, Ad1);
    GLDS(Bg0 + k0, Bd0);
    GLDS(Bg1 + k0, Bd1);
    __syncthreads();
    bf16x8 a[4], b[4];
#pragma unroll
    for (int i = 0; i < 4; i++)
      a[i] = *(const bf16x8*)&Asl[(wr * 64 + i * 16 + lr) * 32 + lg * 8];
#pragma unroll
    for (int j = 0; j < 4; j++)
      b[j] = *(const bf16x8*)&Bsl[(wc * 64 + j * 16 + lr) * 32 + lg * 8];
#pragma unroll
    for (int i = 0; i < 4; i++)
#pragma unroll
      for (int j = 0; j < 4; j++)
        asm volatile("v_mfma_f32_16x16x32_bf16 %0, %1, %2, %0"
                     : "+v"(acc[i][j])
                     : "v"(a[i]), "v"(b[j]));
    __syncthreads();
  }
  asm volatile("s_nop 7\n\ts_nop 7" ::);

#pragma unroll
  for (int i = 0; i < 4; i++) {
#pragma unroll
    for (int r = 0; r < 4; r++) {
      int row = m0 + wr * 64 + i * 16 + lg * 4 + r;
#pragma unroll
      for (int j = 0; j < 4; j++) {
        int col = n0 + wc * 64 + j * 16 + lr;
        Cf[(size_t)row * ldc + col] = acc[i][j][r];
      }
    }
  }
}

// Combine NS split-K partials: out = sum(parts) + bias + res. 4 elems/thread.
template <int NS>
__global__ __launch_bounds__(256) void combine_k(const float* __restrict__ p,
                                                 const float* __restrict__ bias,
                                                 const float* __restrict__ res,
                                                 float* __restrict__ out) {
  int idx = blockIdx.x * 256 + threadIdx.x;  // over 786,432
  size_t e = (size_t)idx * 4;
  float4 s = *(const float4*)(p + e);
#pragma unroll
  for (int z = 1; z < NS; z++) {
    float4 t2 = *(const float4*)(p + (size_t)z * 3145728 + e);
    s.x += t2.x; s.y += t2.y; s.z += t2.z; s.w += t2.w;
  }
  int col = (int)(e % DD);
  float4 b4 = *(const float4*)(bias + col);
  float4 r4 = *(const float4*)(res + e);
  *(float4*)(out + e) = make_float4(s.x + b4.x + r4.x, s.y + b4.y + r4.y,
                                    s.z + b4.z + r4.z, s.w + b4.w + r4.w);
}

// Fused combine_k<2> + LayerNorm (round-15-proven).
__global__ __launch_bounds__(256) void combine2_ln(
    const float* __restrict__ p, const float* __restrict__ bias,
    const float* __restrict__ res, float* __restrict__ x1,
    const float* __restrict__ w, const float* __restrict__ lb,
    u16* __restrict__ xnb) {
  __shared__ float sbuf[8];
  size_t row = blockIdx.x;
  int t = threadIdx.x;
  const float* p0 = p + row * DD;
  const float* p1 = p + 3145728 + row * DD;
  const float* rr = res + row * DD;
  float v0 = p0[t]       + p1[t]       + bias[t]       + rr[t];
  float v1 = p0[t + 256] + p1[t + 256] + bias[t + 256] + rr[t + 256];
  float v2 = p0[t + 512] + p1[t + 512] + bias[t + 512] + rr[t + 512];
  float* xr = x1 + row * DD;
  xr[t] = v0; xr[t + 256] = v1; xr[t + 512] = v2;
  float s = v0 + v1 + v2;
  float ss = v0 * v0 + v1 * v1 + v2 * v2;
  block_reduce2(s, ss, sbuf);
  float mu = s * (1.0f / DD);
  float var = ss * (1.0f / DD) - mu * mu;
  float r = rsqrtf(var + 1e-5f);
  u16* orow = xnb + row * DD;
  orow[t]       = f2bf((v0 - mu) * r * w[t]       + lb[t]);
  orow[t + 256] = f2bf((v1 - mu) * r * w[t + 256] + lb[t + 256]);
  orow[t + 512] = f2bf((v2 - mu) * r * w[t + 512] + lb[t + 512]);
}

// ---------------------------------------------------------------------------
// Streaming gather (round-13/15-proven): eout = t' + kp' + qp' + edge,
// + per-tile stats. kpl/qpl staged via async GLDS. 32KB LDS.
__global__ __launch_bounds__(256) void gather_scale2(
    const u16* __restrict__ tb,
    const u16* __restrict__ kp, const u16* __restrict__ qp,
    const u8* __restrict__ bdT, const float* __restrict__ edge,
    float* __restrict__ eout, float* __restrict__ stats) {
  int bh = blockIdx.z, b = bh / HH;
  int i0 = blockIdx.y * 64, j0 = blockIdx.x * 64, jt = blockIdx.x;
  __shared__ __align__(16) u16 kpl[64][PP];
  __shared__ __align__(16) u16 qpl[64][PP];
  int tid = threadIdx.x;
  int tx = tid & 15, ty = tid >> 4;

  const u16* kpg = kp + (size_t)bh * (LL * PP);
  const u16* qpg = qp + (size_t)bh * (LL * PP);
  u16* kflat = &kpl[0][0];
  u16* qflat = &qpl[0][0];
#pragma unroll
  for (int it = 0; it < 4; it++) {
    int c = tid + it * 256;
    int row = c >> 4, ch = (c & 15) * 8;
    GLDS(&kpg[(size_t)(j0 + row) * PP + ch], &kflat[c * 8]);
    GLDS(&qpg[(size_t)(i0 + row) * PP + ch], &qflat[c * 8]);
  }
  __syncthreads();

  const u8* bd = bdT + (size_t)b * (LL * LL);
  const float* eb = edge + (size_t)bh * (LL * LL);
  const u16* tbb = tb + (size_t)bh * (LL * LL);
  float* ob = eout + (size_t)bh * (LL * LL);

  float rowm[4], rows[4];
#pragma unroll
  for (int i2 = 0; i2 < 4; i2++) {
    int row = i0 + ty * 4 + i2;
    int col0 = j0 + tx * 4;
    uchar4 p4 = *(const uchar4*)&bd[(size_t)row * LL + col0];
    float4 e4 = *(const float4*)&eb[(size_t)row * LL + col0];
    uint2 t2 = *(const uint2*)&tbb[(size_t)row * LL + col0];
    float tv[4] = {bf2f(t2.x), bf2f(t2.x >> 16), bf2f(t2.y), bf2f(t2.y >> 16)};
    int pp[4] = {p4.x, p4.y, p4.z, p4.w};
    float ee[4] = {e4.x, e4.y, e4.z, e4.w};
    float sv[4];
#pragma unroll
    for (int j2 = 0; j2 < 4; j2++) {
      float gk = bf2f((u32)kpl[tx * 4 + j2][pp[j2]]);
      float gq = bf2f((u32)qpl[ty * 4 + i2][pp[j2]]);
      sv[j2] = tv[j2] + gk + gq + ee[j2];
    }
    *(float4*)&ob[(size_t)row * LL + col0] =
        make_float4(sv[0], sv[1], sv[2], sv[3]);
    float m = fmaxf(fmaxf(sv[0], sv[1]), fmaxf(sv[2], sv[3]));
#pragma unroll
    for (int off = 1; off < 16; off <<= 1) m = fmaxf(m, __shfl_xor(m, off, 64));
    float ss = expf(sv[0] - m) + expf(sv[1] - m) + expf(sv[2] - m) + expf(sv[3] - m);
#pragma unroll
    for (int off = 1; off < 16; off <<= 1) ss += __shfl_xor(ss, off, 64);
    rowm[i2] = m;
    rows[i2] = ss;
  }
  if (tx == 0) {
#pragma unroll
    for (int i2 = 0; i2 < 4; i2++) {
      size_t si = ((size_t)bh * LL + i0 + ty * 4 + i2) * 16 + jt;
      stats[si] = rowm[i2];
      stats[si + 8] = rows[i2];
    }
  }
}

// ---------------------------------------------------------------------------
// MFMA softmax+PV (round-14-proven): per (bh, 64-row i-tile).
__global__ __launch_bounds__(256) void softmax_pv_mfma(
    const float* __restrict__ scores, const u16* __restrict__ vbT,
    const float* __restrict__ stats, u16* __restrict__ olbd) {
  int bh = blockIdx.y;
  int i0 = blockIdx.x * 64;
  int b = bh / HH, h = bh - b * HH;
  __shared__ __align__(16) u16 PL[2][64 * 32];
  __shared__ __align__(16) u16 VL[2][64 * 32];
  __shared__ float smax[64], srs[64];
  int tid = threadIdx.x;
  int tx = tid & 15, ty = tid >> 4;
  int lane = tid & 63, w = tid >> 6;
  int wr = w >> 1, wc = w & 1;
  int lr = lane & 15, lg = lane >> 4;
  const float* sbase = scores + (size_t)bh * (LL * LL);
  const u16* vt = vbT + (size_t)bh * (DHH * LL);

  if (tid < 64) {
    size_t si = ((size_t)bh * LL + i0 + tid) * 16;
    float m = stats[si];
#pragma unroll
    for (int j = 1; j < 8; j++) m = fmaxf(m, stats[si + j]);
    float s = 0.f;
#pragma unroll
    for (int j = 0; j < 8; j++) s += stats[si + 8 + j] * expf(stats[si + j] - m);
    smax[tid] = m;
    srs[tid] = 1.0f / s;
  }
  __syncthreads();

  f32x4 acc[2][2] = {};
  int ks = tx >> 3, kk = (tx & 7) * 4;
  int vd = tid >> 2, vjo = (tid & 3) * 8;

  for (int jt = 0; jt < 8; jt++) {
    int j0 = jt * 64;
    GLDS(vt + (size_t)vd * LL + j0 + vjo, &VL[0][tid * 8]);
    GLDS(vt + (size_t)vd * LL + j0 + 32 + vjo, &VL[1][tid * 8]);
#pragma unroll
    for (int rr = 0; rr < 4; rr++) {
      int r = ty + rr * 16;
      float4 s4 = *(const float4*)(sbase + (size_t)(i0 + r) * LL + j0 + tx * 4);
      float m = smax[r], rs = srs[r];
      u16 p0 = f2bf(expf(s4.x - m) * rs);
      u16 p1 = f2bf(expf(s4.y - m) * rs);
      u16 p2 = f2bf(expf(s4.z - m) * rs);
      u16 p3 = f2bf(expf(s4.w - m) * rs);
      *(uint2*)&PL[ks][r * 32 + kk] =
          make_uint2((u32)p0 | ((u32)p1 << 16), (u32)p2 | ((u32)p3 << 16));
    }
    __syncthreads();
#pragma unroll
    for (int s2 = 0; s2 < 2; s2++) {
      bf16x8 a[2], bfr[2];
#pragma unroll
      for (int i = 0; i < 2; i++)
        a[i] = *(const bf16x8*)&PL[s2][(wr * 32 + i * 16 + lr) * 32 + lg * 8];
#pragma unroll
      for (int j = 0; j < 2; j++)
        bfr[j] = *(const bf16x8*)&VL[s2][(wc * 32 + j * 16 + lr) * 32 + lg * 8];
#pragma unroll
      for (int i = 0; i < 2; i++)
#pragma unroll
        for (int j = 0; j < 2; j++)
          asm volatile("v_mfma_f32_16x16x32_bf16 %0, %1, %2, %0"
                       : "+v"(acc[i][j])
                       : "v"(a[i]), "v"(bfr[j]));
    }
    __syncthreads();
  }
  asm volatile("s_nop 7\n\ts_nop 7" ::);

#pragma unroll
  for (int i = 0; i < 2; i++) {
#pragma unroll
    for (int r = 0; r < 4; r++) {
      int irow = i0 + wr * 32 + i * 16 + lg * 4 + r;
#pragma unroll
      for (int j = 0; j < 2; j++) {
        int d = wc * 32 + j * 16 + lr;
        olbd[((size_t)irow * BB + b) * DD + h * 64 + d] = f2bf(acc[i][j][r]);
      }
    }
  }
}

// ---------------------------------------------------------------------------
extern "C" void kernel_launch(void* const* d_in, const int* in_sizes, int n_in,
                              void* d_out, int out_size, void* d_ws, size_t ws_size,
                              hipStream_t stream) {
  const float* x      = (const float*)d_in[0];
  const float* edge   = (const float*)d_in[1];
  const int*   bdist  = (const int*)d_in[2];
  const float* W_in   = (const float*)d_in[3];
  const float* b_in   = (const float*)d_in[4];
  const float* pe_emb = (const float*)d_in[5];
  const float* W_out  = (const float*)d_in[6];
  const float* b_out  = (const float*)d_in[7];
  const float* W1     = (const float*)d_in[8];
  const float* b1     = (const float*)d_in[9];
  const float* W2     = (const float*)d_in[10];
  const float* b2     = (const float*)d_in[11];
  const float* ln1w   = (const float*)d_in[12];
  const float* ln1b   = (const float*)d_in[13];
  const float* ln2w   = (const float*)d_in[14];
  const float* ln2b   = (const float*)d_in[15];

  float* xout = (float*)d_out;                 // [L,B,D]
  float* eout = xout + (size_t)LL * BB * DD;   // [B*H,L,L] == final scores

  // Workspace layout (float units). Max used: ~37.35M floats = 149.4 MB.
  float* ws = (float*)d_ws;
  u16*   xnb    = (u16*)(ws + 0);          // [4096,768] bf16
  u16*   tb     = (u16*)(ws + 1600000);    // t' bf16 [96,512,512]
  u16*   olbdb  = (u16*)(ws + 1600000);    // bf16 O (after gather)
  u16*   ff1b   = (u16*)(ws + 3200000);    // [4096,3072] bf16 (step 10)
  float* x1     = ws + 11100000;           // (step 9)
  u16*   peemb  = (u16*)(ws + 14300000);   // [128,768] bf16
  u16*   vtmp   = (u16*)(ws + 14600000);   // [4096,768] bf16 (dead by step 9)
  float* part   = ws + 14600000;           // split-K partials (steps 8,11)
  u16*   vbT    = (u16*)(ws + 21000000);   // [96,64,512] bf16 transposed V
  float* stats  = ws + 22600000;           // [96,512,16]
  u8*    bdT    = (u8*)(ws + 23400000);    // [8,512,512] u8
  u16*   kpb    = (u16*)(ws + 24000000);   // [96,512,128] bf16
  u16*   qpb    = (u16*)(ws + 27200000);
  u16*   W1b    = (u16*)(ws + 30400000);
  u16*   W2b    = (u16*)(ws + 31600000);
  u16*   W_inb  = (u16*)(ws + 32800000);
  u16*   W_outb = (u16*)(ws + 33700000);
  u16*   qb     = (u16*)(ws + 34000000);
  u16*   kb     = (u16*)(ws + 35600000);
  u16*   peb    = (u16*)(ws + 37200000);   // [128,2304] bf16

  // 1) all prep (LN1 + 5 conversions + bdist transpose) in one launch
  prep_kernel<<<19296, 256, 0, stream>>>(x, ln1w, ln1b, xnb, W_in, W_inb,
                                         W_out, W_outb, W1, W1b, W2, W2b,
                                         pe_emb, peemb, bdist, bdT);
  // 2) qkv GEMM -> qb/kb direct [B,H,L,Dh] + vtmp linear
  gemm_mfma_qkv<<<dim3(18, 32), 256, 0, stream>>>(xnb, W_inb, b_in, qb, kb,
                                                  vtmp);
  // 3) pe_proj = pe_emb @ W_in^T + b_in (MFMA, bf16 out)
  gemm_mfma<0, 1, 0><<<dim3(18, 1), 256, 0, stream>>>(
      peemb, DD, W_inb, DD, peb, 3 * DD, b_in, nullptr, DD);
  // 4) v -> vbT transpose
  split_v<<<3072, 256, 0, stream>>>(vtmp, vbT);
  // 5) merged kp'/qp' + t' (flat 2304-block K=64 batched MFMA)
  attn_k64<<<2304, 256, 0, stream>>>(qb, kb, peb, kpb, qpb, tb);
  // 6) eout = t' + kp' + qp' + edge, + softmax tile stats
  gather_scale2<<<dim3(8, 8, 96), 256, 0, stream>>>(tb, kpb, qpb, bdT, edge,
                                                    eout, stats);
  // 7) MFMA softmax + PV -> olbd bf16 [L,B,D]
  softmax_pv_mfma<<<dim3(8, 96), 256, 0, stream>>>(eout, vbT, stats, olbdb);
  // 8) x1 = O @ W_out^T + b_out + x (split-K=2) + fused combine+LN2
  gemm_mfma_part<<<dim3(6, 32, 2), 256, 0, stream>>>(
      olbdb, DD, W_outb, DD, part, DD, 3145728L, DD / 2);
  combine2_ln<<<4096, 256, 0, stream>>>(part, b_out, x, x1, ln2w, ln2b, xnb);
  // 9) ff1 = gelu(xn @ W1^T + b1) (bf16 out)
  gemm_mfma<1, 1, 0><<<dim3(24, 32), 256, 0, stream>>>(
      xnb, DD, W1b, DD, ff1b, 4 * DD, b1, nullptr, DD);
  // 10) x_out = ff1 @ W2^T + b2 + x1  (split-K=4 + combine)
  gemm_mfma_part<<<dim3(6, 32, 4), 256, 0, stream>>>(
      ff1b, 4 * DD, W2b, 4 * DD, part, DD, 3145728L, DD);
  combine_k<4><<<3072, 256, 0, stream>>>(part, b2, x1, xout);
}

// Round 18
// 325.206 us; speedup vs baseline: 1.7291x; 1.0112x over previous
//
#include <hip/hip_runtime.h>
#include <hip/hip_bf16.h>
#include <math.h>

// Problem constants
#define LL 512
#define BB 8
#define DD 768
#define HH 12
#define DHH 64
#define PP 128

typedef unsigned char u8;
typedef unsigned short u16;
typedef unsigned int u32;
typedef __attribute__((ext_vector_type(8))) short bf16x8;
typedef __attribute__((ext_vector_type(4))) float f32x4;

__device__ __forceinline__ u16 f2bf(float f) {
  u32 u = __float_as_uint(f);
  u32 r = (u + 0x7fffu + ((u >> 16) & 1u)) >> 16;
  return (u16)r;
}
__device__ __forceinline__ float bf2f(u32 u) {
  return __uint_as_float((u & 0xffffu) << 16);
}

#define GLDS(g, l)                                                             \
  __builtin_amdgcn_global_load_lds(                                            \
      (const __attribute__((address_space(1))) void*)(g),                      \
      (__attribute__((address_space(3))) void*)(l), 16, 0, 0)

// ---------------------------------------------------------------------------
__device__ __forceinline__ void block_reduce2(float& a, float& b, float* sbuf) {
#pragma unroll
  for (int off = 32; off > 0; off >>= 1) {
    a += __shfl_down(a, off, 64);
    b += __shfl_down(b, off, 64);
  }
  int wid = threadIdx.x >> 6, lane = threadIdx.x & 63;
  __syncthreads();
  if (lane == 0) { sbuf[wid] = a; sbuf[4 + wid] = b; }
  __syncthreads();
  a = sbuf[0] + sbuf[1] + sbuf[2] + sbuf[3];
  b = sbuf[4] + sbuf[5] + sbuf[6] + sbuf[7];
}

// ---------------------------------------------------------------------------
// Mega-prep: [0,4096) LN1 rows; [4096,11008) weight f2b (4 ranges);
// [11008,11104) pe_emb f2b; [11104,19296) bdist transpose.
__global__ __launch_bounds__(256) void prep_kernel(
    const float* __restrict__ x, const float* __restrict__ ln1w,
    const float* __restrict__ ln1b, u16* __restrict__ xnb,
    const float* __restrict__ W_in, u16* __restrict__ W_inb,
    const float* __restrict__ W_out, u16* __restrict__ W_outb,
    const float* __restrict__ W1, u16* __restrict__ W1b,
    const float* __restrict__ W2, u16* __restrict__ W2b,
    const float* __restrict__ pe_emb, u16* __restrict__ peemb,
    const int* __restrict__ bdist, u8* __restrict__ bdT) {
  int blk = blockIdx.x;
  int t = threadIdx.x;
  if (blk < 4096) {
    __shared__ float sbuf[8];
    const float* xr = x + (size_t)blk * DD;
    float v0 = xr[t], v1 = xr[t + 256], v2 = xr[t + 512];
    float s = v0 + v1 + v2;
    float ss = v0 * v0 + v1 * v1 + v2 * v2;
    block_reduce2(s, ss, sbuf);
    float mu = s * (1.0f / DD);
    float var = ss * (1.0f / DD) - mu * mu;
    float r = rsqrtf(var + 1e-5f);
    u16* orow = xnb + (size_t)blk * DD;
    orow[t]       = f2bf((v0 - mu) * r * ln1w[t]       + ln1b[t]);
    orow[t + 256] = f2bf((v1 - mu) * r * ln1w[t + 256] + ln1b[t + 256]);
    orow[t + 512] = f2bf((v2 - mu) * r * ln1w[t + 512] + ln1b[t + 512]);
  } else if (blk < 11008) {
    int idx = (blk - 4096) * 256 + t;  // 0..1769471
    const float* in;
    u16* out;
    if (idx < 442368) { in = W_in; out = W_inb; }
    else if (idx < 589824) { in = W_out; out = W_outb; idx -= 442368; }
    else if (idx < 1179648) { in = W1; out = W1b; idx -= 589824; }
    else { in = W2; out = W2b; idx -= 1179648; }
    float4 v = *(const float4*)(in + (size_t)idx * 4);
    u32 lo = (u32)f2bf(v.x) | ((u32)f2bf(v.y) << 16);
    u32 hi = (u32)f2bf(v.z) | ((u32)f2bf(v.w) << 16);
    *(uint2*)(out + (size_t)idx * 4) = make_uint2(lo, hi);
  } else if (blk < 11104) {
    int idx = (blk - 11008) * 256 + t;  // 0..24575
    float4 v = *(const float4*)(pe_emb + (size_t)idx * 4);
    u32 lo = (u32)f2bf(v.x) | ((u32)f2bf(v.y) << 16);
    u32 hi = (u32)f2bf(v.z) | ((u32)f2bf(v.w) << 16);
    *(uint2*)(peemb + (size_t)idx * 4) = make_uint2(lo, hi);
  } else {
    int i = (blk - 11104) * 256 + t;  // 0..2097151
    int b = i & 7, jj = (i >> 3) & 511, ii = i >> 12;
    bdT[((size_t)b << 18) + ((size_t)ii << 9) + jj] = (u8)bdist[i];
  }
}

// ---------------------------------------------------------------------------
// bf16 MFMA GEMM (round-3-proven): C = act(A * B^T + bias) [+ residual].
template <int ACT, int OBF, int RES>
__global__ __launch_bounds__(256) void gemm_mfma(
    const u16* __restrict__ A, int lda, const u16* __restrict__ B, int ldb,
    void* __restrict__ Cv, int ldc, const float* __restrict__ bias,
    const float* __restrict__ residual, int K) {
  __shared__ __align__(16) u16 Asl[128 * 32];
  __shared__ __align__(16) u16 Bsl[128 * 32];
  int t = threadIdx.x;
  int m0 = blockIdx.y * 128, n0 = blockIdx.x * 128;
  int lane = t & 63, w = t >> 6;
  int wr = w >> 1, wc = w & 1;
  int lr = lane & 15, lg = lane >> 4;

  f32x4 acc[4][4] = {};

  const u16* Ag0 = A + (size_t)(m0 + (t >> 2)) * lda + (t & 3) * 8;
  const u16* Ag1 = A + (size_t)(m0 + 64 + (t >> 2)) * lda + (t & 3) * 8;
  const u16* Bg0 = B + (size_t)(n0 + (t >> 2)) * ldb + (t & 3) * 8;
  const u16* Bg1 = B + (size_t)(n0 + 64 + (t >> 2)) * ldb + (t & 3) * 8;
  u16* Ad0 = &Asl[t * 8];
  u16* Ad1 = &Asl[2048 + t * 8];
  u16* Bd0 = &Bsl[t * 8];
  u16* Bd1 = &Bsl[2048 + t * 8];

  for (int k0 = 0; k0 < K; k0 += 32) {
    GLDS(Ag0 + k0, Ad0);
    GLDS(Ag1 + k0, Ad1);
    GLDS(Bg0 + k0, Bd0);
    GLDS(Bg1 + k0, Bd1);
    __syncthreads();
    bf16x8 a[4], b[4];
#pragma unroll
    for (int i = 0; i < 4; i++)
      a[i] = *(const bf16x8*)&Asl[(wr * 64 + i * 16 + lr) * 32 + lg * 8];
#pragma unroll
    for (int j = 0; j < 4; j++)
      b[j] = *(const bf16x8*)&Bsl[(wc * 64 + j * 16 + lr) * 32 + lg * 8];
#pragma unroll
    for (int i = 0; i < 4; i++)
#pragma unroll
      for (int j = 0; j < 4; j++)
        asm volatile("v_mfma_f32_16x16x32_bf16 %0, %1, %2, %0"
                     : "+v"(acc[i][j])
                     : "v"(a[i]), "v"(b[j]));
    __syncthreads();
  }
  asm volatile("s_nop 7\n\ts_nop 7" ::);

  float* Cf = (float*)Cv;
  u16* Cb = (u16*)Cv;
#pragma unroll
  for (int i = 0; i < 4; i++) {
#pragma unroll
    for (int r = 0; r < 4; r++) {
      int row = m0 + wr * 64 + i * 16 + lg * 4 + r;
#pragma unroll
      for (int j = 0; j < 4; j++) {
        int col = n0 + wc * 64 + j * 16 + lr;
        float vv = acc[i][j][r];
        if (bias) vv += bias[col];
        if (ACT) vv = 0.5f * vv * (1.0f + erff(vv * 0.70710678118654752f));
        if (RES) vv += residual[(size_t)row * ldc + col];
        if (OBF) Cb[(size_t)row * ldc + col] = f2bf(vv);
        else     Cf[(size_t)row * ldc + col] = vv;
      }
    }
  }
}

// ---------------------------------------------------------------------------
// qkv GEMM with layout-transforming epilogue (round-16-proven).
__global__ __launch_bounds__(256) void gemm_mfma_qkv(
    const u16* __restrict__ A, const u16* __restrict__ B,
    const float* __restrict__ bias, u16* __restrict__ qb,
    u16* __restrict__ kb, u16* __restrict__ vtmp) {
  __shared__ __align__(16) u16 Asl[128 * 32];
  __shared__ __align__(16) u16 Bsl[128 * 32];
  const int lda = DD, ldb = DD, K = DD;
  int t = threadIdx.x;
  int m0 = blockIdx.y * 128, n0 = blockIdx.x * 128;
  int lane = t & 63, w = t >> 6;
  int wr = w >> 1, wc = w & 1;
  int lr = lane & 15, lg = lane >> 4;

  f32x4 acc[4][4] = {};

  const u16* Ag0 = A + (size_t)(m0 + (t >> 2)) * lda + (t & 3) * 8;
  const u16* Ag1 = A + (size_t)(m0 + 64 + (t >> 2)) * lda + (t & 3) * 8;
  const u16* Bg0 = B + (size_t)(n0 + (t >> 2)) * ldb + (t & 3) * 8;
  const u16* Bg1 = B + (size_t)(n0 + 64 + (t >> 2)) * ldb + (t & 3) * 8;
  u16* Ad0 = &Asl[t * 8];
  u16* Ad1 = &Asl[2048 + t * 8];
  u16* Bd0 = &Bsl[t * 8];
  u16* Bd1 = &Bsl[2048 + t * 8];

  for (int k0 = 0; k0 < K; k0 += 32) {
    GLDS(Ag0 + k0, Ad0);
    GLDS(Ag1 + k0, Ad1);
    GLDS(Bg0 + k0, Bd0);
    GLDS(Bg1 + k0, Bd1);
    __syncthreads();
    bf16x8 a[4], b[4];
#pragma unroll
    for (int i = 0; i < 4; i++)
      a[i] = *(const bf16x8*)&Asl[(wr * 64 + i * 16 + lr) * 32 + lg * 8];
#pragma unroll
    for (int j = 0; j < 4; j++)
      b[j] = *(const bf16x8*)&Bsl[(wc * 64 + j * 16 + lr) * 32 + lg * 8];
#pragma unroll
    for (int i = 0; i < 4; i++)
#pragma unroll
      for (int j = 0; j < 4; j++)
        asm volatile("v_mfma_f32_16x16x32_bf16 %0, %1, %2, %0"
                     : "+v"(acc[i][j])
                     : "v"(a[i]), "v"(b[j]));
    __syncthreads();
  }
  asm volatile("s_nop 7\n\ts_nop 7" ::);

#pragma unroll
  for (int i = 0; i < 4; i++) {
#pragma unroll
    for (int r = 0; r < 4; r++) {
      int row = m0 + wr * 64 + i * 16 + lg * 4 + r;
      int l = row >> 3, b = row & 7;
#pragma unroll
      for (int j = 0; j < 4; j++) {
        int col = n0 + wc * 64 + j * 16 + lr;
        u16 vv = f2bf(acc[i][j][r] + bias[col]);
        int which = col / DD, hd = col - which * DD;
        if (which == 0) {
          int h = hd >> 6, d = hd & 63;
          qb[(((size_t)(b * HH + h)) * LL + l) * DHH + d] = vv;
        } else if (which == 1) {
          int h = hd >> 6, d = hd & 63;
          kb[(((size_t)(b * HH + h)) * LL + l) * DHH + d] = vv;
        } else {
          vtmp[(size_t)row * DD + hd] = vv;
        }
      }
    }
  }
}

// ---------------------------------------------------------------------------
// vtmp [4096,768] bf16 -> vbT [B*H, Dh, L] bf16
__global__ __launch_bounds__(256) void split_v(const u16* __restrict__ vtmp,
                                               u16* __restrict__ vbT) {
  int idx = blockIdx.x * 256 + threadIdx.x;  // over 786,432 groups of 4
  int d4 = idx & 15;
  int l = (idx >> 4) & 511;
  int bh = idx >> 13;
  int b = bh / HH, h = bh - b * HH;
  size_t src = ((size_t)(l * BB + b)) * DD + h * 64 + d4 * 4;
  uint2 vv = *(const uint2*)(vtmp + src);
  u16 v0 = (u16)(vv.x & 0xffff), v1 = (u16)(vv.x >> 16);
  u16 v2 = (u16)(vv.y & 0xffff), v3 = (u16)(vv.y >> 16);
  size_t vtb = ((size_t)bh * DHH + d4 * 4) * LL + l;
  vbT[vtb]          = v0;
  vbT[vtb + LL]     = v1;
  vbT[vtb + 2 * LL] = v2;
  vbT[vtb + 3 * LL] = v3;
}

// ---------------------------------------------------------------------------
// Merged K=64 batched MFMA (round-16-proven): flat grid 2304 blocks.
__global__ __launch_bounds__(256) void attn_k64(
    const u16* __restrict__ qb, const u16* __restrict__ kb,
    const u16* __restrict__ peb, u16* __restrict__ kpb,
    u16* __restrict__ qpb, u16* __restrict__ tb) {
  __shared__ __align__(16) u16 Asl[128 * 32];
  __shared__ __align__(16) u16 Bsl[128 * 32];
  int id = blockIdx.x;
  const u16 *A, *B;
  u16* Cb;
  int lda, ldb, ldc, m0, n0;
  if (id < 768) {
    int my = id & 3, z = id >> 2;
    int sel = z / 96, zz = z - sel * 96;
    A = (sel ? qb : kb) + (size_t)zz * (LL * DHH);
    B = peb + sel * DD + (size_t)(zz % HH) * 64;
    Cb = (sel ? qpb : kpb) + (size_t)zz * (LL * PP);
    lda = DHH; ldb = 3 * DD; ldc = PP; m0 = my * 128; n0 = 0;
  } else {
    int id2 = id - 768;
    int jx = id2 & 3, my = (id2 >> 2) & 3, bh = id2 >> 4;
    A = qb + (size_t)bh * (LL * DHH);
    B = kb + (size_t)bh * (LL * DHH);
    Cb = tb + (size_t)bh * (LL * LL);
    lda = DHH; ldb = DHH; ldc = LL; m0 = my * 128; n0 = jx * 128;
  }
  int t = threadIdx.x;
  int lane = t & 63, w = t >> 6;
  int wr = w >> 1, wc = w & 1;
  int lr = lane & 15, lg = lane >> 4;

  f32x4 acc[4][4] = {};

  const u16* Ag0 = A + (size_t)(m0 + (t >> 2)) * lda + (t & 3) * 8;
  const u16* Ag1 = A + (size_t)(m0 + 64 + (t >> 2)) * lda + (t & 3) * 8;
  const u16* Bg0 = B + (size_t)(n0 + (t >> 2)) * ldb + (t & 3) * 8;
  const u16* Bg1 = B + (size_t)(n0 + 64 + (t >> 2)) * ldb + (t & 3) * 8;
  u16* Ad0 = &Asl[t * 8];
  u16* Ad1 = &Asl[2048 + t * 8];
  u16* Bd0 = &Bsl[t * 8];
  u16* Bd1 = &Bsl[2048 + t * 8];

  for (int k0 = 0; k0 < DHH; k0 += 32) {
    GLDS(Ag0 + k0, Ad0);
    GLDS(Ag1 + k0, Ad1);
    GLDS(Bg0 + k0, Bd0);
    GLDS(Bg1 + k0, Bd1);
    __syncthreads();
    bf16x8 a[4], b[4];
#pragma unroll
    for (int i = 0; i < 4; i++)
      a[i] = *(const bf16x8*)&Asl[(wr * 64 + i * 16 + lr) * 32 + lg * 8];
#pragma unroll
    for (int j = 0; j < 4; j++)
      b[j] = *(const bf16x8*)&Bsl[(wc * 64 + j * 16 + lr) * 32 + lg * 8];
#pragma unroll
    for (int i = 0; i < 4; i++)
#pragma unroll
      for (int j = 0; j < 4; j++)
        asm volatile("v_mfma_f32_16x16x32_bf16 %0, %1, %2, %0"
                     : "+v"(acc[i][j])
                     : "v"(a[i]), "v"(b[j]));
    __syncthreads();
  }
  asm volatile("s_nop 7\n\ts_nop 7" ::);

#pragma unroll
  for (int i = 0; i < 4; i++) {
#pragma unroll
    for (int r = 0; r < 4; r++) {
      int row = m0 + wr * 64 + i * 16 + lg * 4 + r;
#pragma unroll
      for (int j = 0; j < 4; j++) {
        int col = n0 + wc * 64 + j * 16 + lr;
        Cb[(size_t)row * ldc + col] = f2bf(acc[i][j][r] * 0.125f);
      }
    }
  }
}

// ---------------------------------------------------------------------------
// Streaming gather (round-16-proven): eout = t' + kp' + qp' + edge,
// + per-tile stats. kpl/qpl staged via async GLDS. 32KB LDS.
__global__ __launch_bounds__(256) void gather_scale2(
    const u16* __restrict__ tb,
    const u16* __restrict__ kp, const u16* __restrict__ qp,
    const u8* __restrict__ bdT, const float* __restrict__ edge,
    float* __restrict__ eout, float* __restrict__ stats) {
  int bh = blockIdx.z, b = bh / HH;
  int i0 = blockIdx.y * 64, j0 = blockIdx.x * 64, jt = blockIdx.x;
  __shared__ __align__(16) u16 kpl[64][PP];
  __shared__ __align__(16) u16 qpl[64][PP];
  int tid = threadIdx.x;
  int tx = tid & 15, ty = tid >> 4;

  const u16* kpg = kp + (size_t)bh * (LL * PP);
  const u16* qpg = qp + (size_t)bh * (LL * PP);
  u16* kflat = &kpl[0][0];
  u16* qflat = &qpl[0][0];
#pragma unroll
  for (int it = 0; it < 4; it++) {
    int c = tid + it * 256;
    int row = c >> 4, ch = (c & 15) * 8;
    GLDS(&kpg[(size_t)(j0 + row) * PP + ch], &kflat[c * 8]);
    GLDS(&qpg[(size_t)(i0 + row) * PP + ch], &qflat[c * 8]);
  }
  __syncthreads();

  const u8* bd = bdT + (size_t)b * (LL * LL);
  const float* eb = edge + (size_t)bh * (LL * LL);
  const u16* tbb = tb + (size_t)bh * (LL * LL);
  float* ob = eout + (size_t)bh * (LL * LL);

  float rowm[4], rows[4];
#pragma unroll
  for (int i2 = 0; i2 < 4; i2++) {
    int row = i0 + ty * 4 + i2;
    int col0 = j0 + tx * 4;
    uchar4 p4 = *(const uchar4*)&bd[(size_t)row * LL + col0];
    float4 e4 = *(const float4*)&eb[(size_t)row * LL + col0];
    uint2 t2 = *(const uint2*)&tbb[(size_t)row * LL + col0];
    float tv[4] = {bf2f(t2.x), bf2f(t2.x >> 16), bf2f(t2.y), bf2f(t2.y >> 16)};
    int pp[4] = {p4.x, p4.y, p4.z, p4.w};
    float ee[4] = {e4.x, e4.y, e4.z, e4.w};
    float sv[4];
#pragma unroll
    for (int j2 = 0; j2 < 4; j2++) {
      float gk = bf2f((u32)kpl[tx * 4 + j2][pp[j2]]);
      float gq = bf2f((u32)qpl[ty * 4 + i2][pp[j2]]);
      sv[j2] = tv[j2] + gk + gq + ee[j2];
    }
    *(float4*)&ob[(size_t)row * LL + col0] =
        make_float4(sv[0], sv[1], sv[2], sv[3]);
    float m = fmaxf(fmaxf(sv[0], sv[1]), fmaxf(sv[2], sv[3]));
#pragma unroll
    for (int off = 1; off < 16; off <<= 1) m = fmaxf(m, __shfl_xor(m, off, 64));
    float ss = __expf(sv[0] - m) + __expf(sv[1] - m) + __expf(sv[2] - m) +
               __expf(sv[3] - m);
#pragma unroll
    for (int off = 1; off < 16; off <<= 1) ss += __shfl_xor(ss, off, 64);
    rowm[i2] = m;
    rows[i2] = ss;
  }
  if (tx == 0) {
#pragma unroll
    for (int i2 = 0; i2 < 4; i2++) {
      size_t si = ((size_t)bh * LL + i0 + ty * 4 + i2) * 16 + jt;
      stats[si] = rowm[i2];
      stats[si + 8] = rows[i2];
    }
  }
}

// ---------------------------------------------------------------------------
// MFMA softmax+PV (round-14-proven): per (bh, 64-row i-tile).
__global__ __launch_bounds__(256) void softmax_pv_mfma(
    const float* __restrict__ scores, const u16* __restrict__ vbT,
    const float* __restrict__ stats, u16* __restrict__ olbd) {
  int bh = blockIdx.y;
  int i0 = blockIdx.x * 64;
  int b = bh / HH, h = bh - b * HH;
  __shared__ __align__(16) u16 PL[2][64 * 32];
  __shared__ __align__(16) u16 VL[2][64 * 32];
  __shared__ float smax[64], srs[64];
  int tid = threadIdx.x;
  int tx = tid & 15, ty = tid >> 4;
  int lane = tid & 63, w = tid >> 6;
  int wr = w >> 1, wc = w & 1;
  int lr = lane & 15, lg = lane >> 4;
  const float* sbase = scores + (size_t)bh * (LL * LL);
  const u16* vt = vbT + (size_t)bh * (DHH * LL);

  if (tid < 64) {
    size_t si = ((size_t)bh * LL + i0 + tid) * 16;
    float m = stats[si];
#pragma unroll
    for (int j = 1; j < 8; j++) m = fmaxf(m, stats[si + j]);
    float s = 0.f;
#pragma unroll
    for (int j = 0; j < 8; j++) s += stats[si + 8 + j] * __expf(stats[si + j] - m);
    smax[tid] = m;
    srs[tid] = 1.0f / s;
  }
  __syncthreads();

  f32x4 acc[2][2] = {};
  int ks = tx >> 3, kk = (tx & 7) * 4;
  int vd = tid >> 2, vjo = (tid & 3) * 8;

  for (int jt = 0; jt < 8; jt++) {
    int j0 = jt * 64;
    GLDS(vt + (size_t)vd * LL + j0 + vjo, &VL[0][tid * 8]);
    GLDS(vt + (size_t)vd * LL + j0 + 32 + vjo, &VL[1][tid * 8]);
#pragma unroll
    for (int rr = 0; rr < 4; rr++) {
      int r = ty + rr * 16;
      float4 s4 = *(const float4*)(sbase + (size_t)(i0 + r) * LL + j0 + tx * 4);
      float m = smax[r], rs = srs[r];
      u16 p0 = f2bf(__expf(s4.x - m) * rs);
      u16 p1 = f2bf(__expf(s4.y - m) * rs);
      u16 p2 = f2bf(__expf(s4.z - m) * rs);
      u16 p3 = f2bf(__expf(s4.w - m) * rs);
      *(uint2*)&PL[ks][r * 32 + kk] =
          make_uint2((u32)p0 | ((u32)p1 << 16), (u32)p2 | ((u32)p3 << 16));
    }
    __syncthreads();
#pragma unroll
    for (int s2 = 0; s2 < 2; s2++) {
      bf16x8 a[2], bfr[2];
#pragma unroll
      for (int i = 0; i < 2; i++)
        a[i] = *(const bf16x8*)&PL[s2][(wr * 32 + i * 16 + lr) * 32 + lg * 8];
#pragma unroll
      for (int j = 0; j < 2; j++)
        bfr[j] = *(const bf16x8*)&VL[s2][(wc * 32 + j * 16 + lr) * 32 + lg * 8];
#pragma unroll
      for (int i = 0; i < 2; i++)
#pragma unroll
        for (int j = 0; j < 2; j++)
          asm volatile("v_mfma_f32_16x16x32_bf16 %0, %1, %2, %0"
                       : "+v"(acc[i][j])
                       : "v"(a[i]), "v"(bfr[j]));
    }
    __syncthreads();
  }
  asm volatile("s_nop 7\n\ts_nop 7" ::);

#pragma unroll
  for (int i = 0; i < 2; i++) {
#pragma unroll
    for (int r = 0; r < 4; r++) {
      int irow = i0 + wr * 32 + i * 16 + lg * 4 + r;
#pragma unroll
      for (int j = 0; j < 2; j++) {
        int d = wc * 32 + j * 16 + lr;
        olbd[((size_t)irow * BB + b) * DD + h * 64 + d] = f2bf(acc[i][j][r]);
      }
    }
  }
}

// ---------------------------------------------------------------------------
// Split-K partial MFMA GEMM (round-11-proven).
__global__ __launch_bounds__(256) void gemm_mfma_part(
    const u16* __restrict__ A, int lda, const u16* __restrict__ B, int ldb,
    float* __restrict__ Cf, int ldc, long partStride, int Kper) {
  __shared__ __align__(16) u16 Asl[128 * 32];
  __shared__ __align__(16) u16 Bsl[128 * 32];
  int z = blockIdx.z;
  A += (size_t)z * Kper;
  B += (size_t)z * Kper;
  Cf += (size_t)z * partStride;
  int t = threadIdx.x;
  int m0 = blockIdx.y * 128, n0 = blockIdx.x * 128;
  int lane = t & 63, w = t >> 6;
  int wr = w >> 1, wc = w & 1;
  int lr = lane & 15, lg = lane >> 4;

  f32x4 acc[4][4] = {};

  const u16* Ag0 = A + (size_t)(m0 + (t >> 2)) * lda + (t & 3) * 8;
  const u16* Ag1 = A + (size_t)(m0 + 64 + (t >> 2)) * lda + (t & 3) * 8;
  const u16* Bg0 = B + (size_t)(n0 + (t >> 2)) * ldb + (t & 3) * 8;
  const u16* Bg1 = B + (size_t)(n0 + 64 + (t >> 2)) * ldb + (t & 3) * 8;
  u16* Ad0 = &Asl[t * 8];
  u16* Ad1 = &Asl[2048 + t * 8];
  u16* Bd0 = &Bsl[t * 8];
  u16* Bd1 = &Bsl[2048 + t * 8];

  for (int k0 = 0; k0 < Kper; k0 += 32) {
    GLDS(Ag0 + k0, Ad0);
    GLDS(Ag1 + k0, Ad1);
    GLDS(Bg0 + k0, Bd0);
    GLDS(Bg1 + k0, Bd1);
    __syncthreads();
    bf16x8 a[4], b[4];
#pragma unroll
    for (int i = 0; i < 4; i++)
      a[i] = *(const bf16x8*)&Asl[(wr * 64 + i * 16 + lr) * 32 + lg * 8];
#pragma unroll
    for (int j = 0; j < 4; j++)
      b[j] = *(const bf16x8*)&Bsl[(wc * 64 + j * 16 + lr) * 32 + lg * 8];
#pragma unroll
    for (int i = 0; i < 4; i++)
#pragma unroll
      for (int j = 0; j < 4; j++)
        asm volatile("v_mfma_f32_16x16x32_bf16 %0, %1, %2, %0"
                     : "+v"(acc[i][j])
                     : "v"(a[i]), "v"(b[j]));
    __syncthreads();
  }
  asm volatile("s_nop 7\n\ts_nop 7" ::);

#pragma unroll
  for (int i = 0; i < 4; i++) {
#pragma unroll
    for (int r = 0; r < 4; r++) {
      int row = m0 + wr * 64 + i * 16 + lg * 4 + r;
#pragma unroll
      for (int j = 0; j < 4; j++) {
        int col = n0 + wc * 64 + j * 16 + lr;
        Cf[(size_t)row * ldc + col] = acc[i][j][r];
      }
    }
  }
}

// Combine NS split-K partials: out = sum(parts) + bias + res. 4 elems/thread.
template <int NS>
__global__ __launch_bounds__(256) void combine_k(const float* __restrict__ p,
                                                 const float* __restrict__ bias,
                                                 const float* __restrict__ res,
                                                 float* __restrict__ out) {
  int idx = blockIdx.x * 256 + threadIdx.x;  // over 786,432
  size_t e = (size_t)idx * 4;
  float4 s = *(const float4*)(p + e);
#pragma unroll
  for (int z = 1; z < NS; z++) {
    float4 t2 = *(const float4*)(p + (size_t)z * 3145728 + e);
    s.x += t2.x; s.y += t2.y; s.z += t2.z; s.w += t2.w;
  }
  int col = (int)(e % DD);
  float4 b4 = *(const float4*)(bias + col);
  float4 r4 = *(const float4*)(res + e);
  *(float4*)(out + e) = make_float4(s.x + b4.x + r4.x, s.y + b4.y + r4.y,
                                    s.z + b4.z + r4.z, s.w + b4.w + r4.w);
}

// Fused combine_k<2> + LayerNorm (round-15-proven).
__global__ __launch_bounds__(256) void combine2_ln(
    const float* __restrict__ p, const float* __restrict__ bias,
    const float* __restrict__ res, float* __restrict__ x1,
    const float* __restrict__ w, const float* __restrict__ lb,
    u16* __restrict__ xnb) {
  __shared__ float sbuf[8];
  size_t row = blockIdx.x;
  int t = threadIdx.x;
  const float* p0 = p + row * DD;
  const float* p1 = p + 3145728 + row * DD;
  const float* rr = res + row * DD;
  float v0 = p0[t]       + p1[t]       + bias[t]       + rr[t];
  float v1 = p0[t + 256] + p1[t + 256] + bias[t + 256] + rr[t + 256];
  float v2 = p0[t + 512] + p1[t + 512] + bias[t + 512] + rr[t + 512];
  float* xr = x1 + row * DD;
  xr[t] = v0; xr[t + 256] = v1; xr[t + 512] = v2;
  float s = v0 + v1 + v2;
  float ss = v0 * v0 + v1 * v1 + v2 * v2;
  block_reduce2(s, ss, sbuf);
  float mu = s * (1.0f / DD);
  float var = ss * (1.0f / DD) - mu * mu;
  float r = rsqrtf(var + 1e-5f);
  u16* orow = xnb + row * DD;
  orow[t]       = f2bf((v0 - mu) * r * w[t]       + lb[t]);
  orow[t + 256] = f2bf((v1 - mu) * r * w[t + 256] + lb[t + 256]);
  orow[t + 512] = f2bf((v2 - mu) * r * w[t + 512] + lb[t + 512]);
}

// ---------------------------------------------------------------------------
extern "C" void kernel_launch(void* const* d_in, const int* in_sizes, int n_in,
                              void* d_out, int out_size, void* d_ws, size_t ws_size,
                              hipStream_t stream) {
  const float* x      = (const float*)d_in[0];
  const float* edge   = (const float*)d_in[1];
  const int*   bdist  = (const int*)d_in[2];
  const float* W_in   = (const float*)d_in[3];
  const float* b_in   = (const float*)d_in[4];
  const float* pe_emb = (const float*)d_in[5];
  const float* W_out  = (const float*)d_in[6];
  const float* b_out  = (const float*)d_in[7];
  const float* W1     = (const float*)d_in[8];
  const float* b1     = (const float*)d_in[9];
  const float* W2     = (const float*)d_in[10];
  const float* b2     = (const float*)d_in[11];
  const float* ln1w   = (const float*)d_in[12];
  const float* ln1b   = (const float*)d_in[13];
  const float* ln2w   = (const float*)d_in[14];
  const float* ln2b   = (const float*)d_in[15];

  float* xout = (float*)d_out;                 // [L,B,D]
  float* eout = xout + (size_t)LL * BB * DD;   // [B*H,L,L] == final scores

  // Workspace layout (float units) — round-16-proven.
  float* ws = (float*)d_ws;
  u16*   xnb    = (u16*)(ws + 0);          // [4096,768] bf16
  u16*   tb     = (u16*)(ws + 1600000);    // t' bf16 [96,512,512]
  u16*   olbdb  = (u16*)(ws + 1600000);    // bf16 O (after gather; tb dead)
  u16*   ff1b   = (u16*)(ws + 3200000);    // [4096,3072] bf16 (step 9)
  float* x1     = ws + 11100000;           // (step 8)
  u16*   peemb  = (u16*)(ws + 14300000);   // [128,768] bf16
  u16*   vtmp   = (u16*)(ws + 14600000);   // [4096,768] bf16 (dead by step 8)
  float* part   = ws + 14600000;           // split-K partials (steps 8,10)
  u16*   vbT    = (u16*)(ws + 21000000);   // [96,64,512] bf16 transposed V
  float* stats  = ws + 22600000;           // [96,512,16]
  u8*    bdT    = (u8*)(ws + 23400000);    // [8,512,512] u8
  u16*   kpb    = (u16*)(ws + 24000000);   // [96,512,128] bf16
  u16*   qpb    = (u16*)(ws + 27200000);
  u16*   W1b    = (u16*)(ws + 30400000);
  u16*   W2b    = (u16*)(ws + 31600000);
  u16*   W_inb  = (u16*)(ws + 32800000);
  u16*   W_outb = (u16*)(ws + 33700000);
  u16*   qb     = (u16*)(ws + 34000000);
  u16*   kb     = (u16*)(ws + 35600000);
  u16*   peb    = (u16*)(ws + 37200000);   // [128,2304] bf16

  // 1) all prep (LN1 + 5 conversions + bdist transpose) in one launch
  prep_kernel<<<19296, 256, 0, stream>>>(x, ln1w, ln1b, xnb, W_in, W_inb,
                                         W_out, W_outb, W1, W1b, W2, W2b,
                                         pe_emb, peemb, bdist, bdT);
  // 2) qkv GEMM -> qb/kb direct [B,H,L,Dh] + vtmp linear
  gemm_mfma_qkv<<<dim3(18, 32), 256, 0, stream>>>(xnb, W_inb, b_in, qb, kb,
                                                  vtmp);
  // 3) pe_proj = pe_emb @ W_in^T + b_in (MFMA, bf16 out)
  gemm_mfma<0, 1, 0><<<dim3(18, 1), 256, 0, stream>>>(
      peemb, DD, W_inb, DD, peb, 3 * DD, b_in, nullptr, DD);
  // 4) v -> vbT transpose
  split_v<<<3072, 256, 0, stream>>>(vtmp, vbT);
  // 5) merged kp'/qp' + t' (flat 2304-block K=64 batched MFMA)
  attn_k64<<<2304, 256, 0, stream>>>(qb, kb, peb, kpb, qpb, tb);
  // 6) eout = t' + kp' + qp' + edge, + softmax tile stats
  gather_scale2<<<dim3(8, 8, 96), 256, 0, stream>>>(tb, kpb, qpb, bdT, edge,
                                                    eout, stats);
  // 7) MFMA softmax + PV -> olbd bf16 [L,B,D]
  softmax_pv_mfma<<<dim3(8, 96), 256, 0, stream>>>(eout, vbT, stats, olbdb);
  // 8) x1 = O @ W_out^T + b_out + x (split-K=2) + fused combine+LN2
  gemm_mfma_part<<<dim3(6, 32, 2), 256, 0, stream>>>(
      olbdb, DD, W_outb, DD, part, DD, 3145728L, DD / 2);
  combine2_ln<<<4096, 256, 0, stream>>>(part, b_out, x, x1, ln2w, ln2b, xnb);
  // 9) ff1 = gelu(xn @ W1^T + b1) (bf16 out)
  gemm_mfma<1, 1, 0><<<dim3(24, 32), 256, 0, stream>>>(
      xnb, DD, W1b, DD, ff1b, 4 * DD, b1, nullptr, DD);
  // 10) x_out = ff1 @ W2^T + b2 + x1  (split-K=4 + combine)
  gemm_mfma_part<<<dim3(6, 32, 4), 256, 0, stream>>>(
      ff1b, 4 * DD, W2b, 4 * DD, part, DD, 3145728L, DD);
  combine_k<4><<<3072, 256, 0, stream>>>(part, b2, x1, xout);
}

// Round 19
// 315.784 us; speedup vs baseline: 1.7807x; 1.0298x over previous
//
#include <hip/hip_runtime.h>
#include <hip/hip_bf16.h>
#include <math.h>

// Problem constants
#define LL 512
#define BB 8
#define DD 768
#define HH 12
#define DHH 64
#define PP 128

typedef unsigned char u8;
typedef unsigned short u16;
typedef unsigned int u32;
typedef __attribute__((ext_vector_type(8))) short bf16x8;
typedef __attribute__((ext_vector_type(4))) float f32x4;

__device__ __forceinline__ u16 f2bf(float f) {
  u32 u = __float_as_uint(f);
  u32 r = (u + 0x7fffu + ((u >> 16) & 1u)) >> 16;
  return (u16)r;
}
__device__ __forceinline__ float bf2f(u32 u) {
  return __uint_as_float((u & 0xffffu) << 16);
}

#define GLDS(g, l)                                                             \
  __builtin_amdgcn_global_load_lds(                                            \
      (const __attribute__((address_space(1))) void*)(g),                      \
      (__attribute__((address_space(3))) void*)(l), 16, 0, 0)

// ---------------------------------------------------------------------------
__device__ __forceinline__ void block_reduce2(float& a, float& b, float* sbuf) {
#pragma unroll
  for (int off = 32; off > 0; off >>= 1) {
    a += __shfl_down(a, off, 64);
    b += __shfl_down(b, off, 64);
  }
  int wid = threadIdx.x >> 6, lane = threadIdx.x & 63;
  __syncthreads();
  if (lane == 0) { sbuf[wid] = a; sbuf[4 + wid] = b; }
  __syncthreads();
  a = sbuf[0] + sbuf[1] + sbuf[2] + sbuf[3];
  b = sbuf[4] + sbuf[5] + sbuf[6] + sbuf[7];
}

// ---------------------------------------------------------------------------
// Mega-prep: [0,4096) LN1 rows; [4096,11008) weight f2b (4 ranges);
// [11008,11104) pe_emb f2b; [11104,19296) bdist transpose.
__global__ __launch_bounds__(256) void prep_kernel(
    const float* __restrict__ x, const float* __restrict__ ln1w,
    const float* __restrict__ ln1b, u16* __restrict__ xnb,
    const float* __restrict__ W_in, u16* __restrict__ W_inb,
    const float* __restrict__ W_out, u16* __restrict__ W_outb,
    const float* __restrict__ W1, u16* __restrict__ W1b,
    const float* __restrict__ W2, u16* __restrict__ W2b,
    const float* __restrict__ pe_emb, u16* __restrict__ peemb,
    const int* __restrict__ bdist, u8* __restrict__ bdT) {
  int blk = blockIdx.x;
  int t = threadIdx.x;
  if (blk < 4096) {
    __shared__ float sbuf[8];
    const float* xr = x + (size_t)blk * DD;
    float v0 = xr[t], v1 = xr[t + 256], v2 = xr[t + 512];
    float s = v0 + v1 + v2;
    float ss = v0 * v0 + v1 * v1 + v2 * v2;
    block_reduce2(s, ss, sbuf);
    float mu = s * (1.0f / DD);
    float var = ss * (1.0f / DD) - mu * mu;
    float r = rsqrtf(var + 1e-5f);
    u16* orow = xnb + (size_t)blk * DD;
    orow[t]       = f2bf((v0 - mu) * r * ln1w[t]       + ln1b[t]);
    orow[t + 256] = f2bf((v1 - mu) * r * ln1w[t + 256] + ln1b[t + 256]);
    orow[t + 512] = f2bf((v2 - mu) * r * ln1w[t + 512] + ln1b[t + 512]);
  } else if (blk < 11008) {
    int idx = (blk - 4096) * 256 + t;  // 0..1769471
    const float* in;
    u16* out;
    if (idx < 442368) { in = W_in; out = W_inb; }
    else if (idx < 589824) { in = W_out; out = W_outb; idx -= 442368; }
    else if (idx < 1179648) { in = W1; out = W1b; idx -= 589824; }
    else { in = W2; out = W2b; idx -= 1179648; }
    float4 v = *(const float4*)(in + (size_t)idx * 4);
    u32 lo = (u32)f2bf(v.x) | ((u32)f2bf(v.y) << 16);
    u32 hi = (u32)f2bf(v.z) | ((u32)f2bf(v.w) << 16);
    *(uint2*)(out + (size_t)idx * 4) = make_uint2(lo, hi);
  } else if (blk < 11104) {
    int idx = (blk - 11008) * 256 + t;  // 0..24575
    float4 v = *(const float4*)(pe_emb + (size_t)idx * 4);
    u32 lo = (u32)f2bf(v.x) | ((u32)f2bf(v.y) << 16);
    u32 hi = (u32)f2bf(v.z) | ((u32)f2bf(v.w) << 16);
    *(uint2*)(peemb + (size_t)idx * 4) = make_uint2(lo, hi);
  } else {
    int i = (blk - 11104) * 256 + t;  // 0..2097151
    int b = i & 7, jj = (i >> 3) & 511, ii = i >> 12;
    bdT[((size_t)b << 18) + ((size_t)ii << 9) + jj] = (u8)bdist[i];
  }
}

// ---------------------------------------------------------------------------
// bf16 MFMA GEMM (round-3-proven): C = act(A * B^T + bias) [+ residual].
template <int ACT, int OBF, int RES>
__global__ __launch_bounds__(256) void gemm_mfma(
    const u16* __restrict__ A, int lda, const u16* __restrict__ B, int ldb,
    void* __restrict__ Cv, int ldc, const float* __restrict__ bias,
    const float* __restrict__ residual, int K) {
  __shared__ __align__(16) u16 Asl[128 * 32];
  __shared__ __align__(16) u16 Bsl[128 * 32];
  int t = threadIdx.x;
  int m0 = blockIdx.y * 128, n0 = blockIdx.x * 128;
  int lane = t & 63, w = t >> 6;
  int wr = w >> 1, wc = w & 1;
  int lr = lane & 15, lg = lane >> 4;

  f32x4 acc[4][4] = {};

  const u16* Ag0 = A + (size_t)(m0 + (t >> 2)) * lda + (t & 3) * 8;
  const u16* Ag1 = A + (size_t)(m0 + 64 + (t >> 2)) * lda + (t & 3) * 8;
  const u16* Bg0 = B + (size_t)(n0 + (t >> 2)) * ldb + (t & 3) * 8;
  const u16* Bg1 = B + (size_t)(n0 + 64 + (t >> 2)) * ldb + (t & 3) * 8;
  u16* Ad0 = &Asl[t * 8];
  u16* Ad1 = &Asl[2048 + t * 8];
  u16* Bd0 = &Bsl[t * 8];
  u16* Bd1 = &Bsl[2048 + t * 8];

  for (int k0 = 0; k0 < K; k0 += 32) {
    GLDS(Ag0 + k0, Ad0);
    GLDS(Ag1 + k0, Ad1);
    GLDS(Bg0 + k0, Bd0);
    GLDS(Bg1 + k0, Bd1);
    __syncthreads();
    bf16x8 a[4], b[4];
#pragma unroll
    for (int i = 0; i < 4; i++)
      a[i] = *(const bf16x8*)&Asl[(wr * 64 + i * 16 + lr) * 32 + lg * 8];
#pragma unroll
    for (int j = 0; j < 4; j++)
      b[j] = *(const bf16x8*)&Bsl[(wc * 64 + j * 16 + lr) * 32 + lg * 8];
#pragma unroll
    for (int i = 0; i < 4; i++)
#pragma unroll
      for (int j = 0; j < 4; j++)
        asm volatile("v_mfma_f32_16x16x32_bf16 %0, %1, %2, %0"
                     : "+v"(acc[i][j])
                     : "v"(a[i]), "v"(b[j]));
    __syncthreads();
  }
  asm volatile("s_nop 7\n\ts_nop 7" ::);

  float* Cf = (float*)Cv;
  u16* Cb = (u16*)Cv;
#pragma unroll
  for (int i = 0; i < 4; i++) {
#pragma unroll
    for (int r = 0; r < 4; r++) {
      int row = m0 + wr * 64 + i * 16 + lg * 4 + r;
#pragma unroll
      for (int j = 0; j < 4; j++) {
        int col = n0 + wc * 64 + j * 16 + lr;
        float vv = acc[i][j][r];
        if (bias) vv += bias[col];
        if (ACT) vv = 0.5f * vv * (1.0f + erff(vv * 0.70710678118654752f));
        if (RES) vv += residual[(size_t)row * ldc + col];
        if (OBF) Cb[(size_t)row * ldc + col] = f2bf(vv);
        else     Cf[(size_t)row * ldc + col] = vv;
      }
    }
  }
}

// ---------------------------------------------------------------------------
// qkv GEMM with layout-transforming epilogue (round-16-proven).
__global__ __launch_bounds__(256) void gemm_mfma_qkv(
    const u16* __restrict__ A, const u16* __restrict__ B,
    const float* __restrict__ bias, u16* __restrict__ qb,
    u16* __restrict__ kb, u16* __restrict__ vtmp) {
  __shared__ __align__(16) u16 Asl[128 * 32];
  __shared__ __align__(16) u16 Bsl[128 * 32];
  const int lda = DD, ldb = DD, K = DD;
  int t = threadIdx.x;
  int m0 = blockIdx.y * 128, n0 = blockIdx.x * 128;
  int lane = t & 63, w = t >> 6;
  int wr = w >> 1, wc = w & 1;
  int lr = lane & 15, lg = lane >> 4;

  f32x4 acc[4][4] = {};

  const u16* Ag0 = A + (size_t)(m0 + (t >> 2)) * lda + (t & 3) * 8;
  const u16* Ag1 = A + (size_t)(m0 + 64 + (t >> 2)) * lda + (t & 3) * 8;
  const u16* Bg0 = B + (size_t)(n0 + (t >> 2)) * ldb + (t & 3) * 8;
  const u16* Bg1 = B + (size_t)(n0 + 64 + (t >> 2)) * ldb + (t & 3) * 8;
  u16* Ad0 = &Asl[t * 8];
  u16* Ad1 = &Asl[2048 + t * 8];
  u16* Bd0 = &Bsl[t * 8];
  u16* Bd1 = &Bsl[2048 + t * 8];

  for (int k0 = 0; k0 < K; k0 += 32) {
    GLDS(Ag0 + k0, Ad0);
    GLDS(Ag1 + k0, Ad1);
    GLDS(Bg0 + k0, Bd0);
    GLDS(Bg1 + k0, Bd1);
    __syncthreads();
    bf16x8 a[4], b[4];
#pragma unroll
    for (int i = 0; i < 4; i++)
      a[i] = *(const bf16x8*)&Asl[(wr * 64 + i * 16 + lr) * 32 + lg * 8];
#pragma unroll
    for (int j = 0; j < 4; j++)
      b[j] = *(const bf16x8*)&Bsl[(wc * 64 + j * 16 + lr) * 32 + lg * 8];
#pragma unroll
    for (int i = 0; i < 4; i++)
#pragma unroll
      for (int j = 0; j < 4; j++)
        asm volatile("v_mfma_f32_16x16x32_bf16 %0, %1, %2, %0"
                     : "+v"(acc[i][j])
                     : "v"(a[i]), "v"(b[j]));
    __syncthreads();
  }
  asm volatile("s_nop 7\n\ts_nop 7" ::);

#pragma unroll
  for (int i = 0; i < 4; i++) {
#pragma unroll
    for (int r = 0; r < 4; r++) {
      int row = m0 + wr * 64 + i * 16 + lg * 4 + r;
      int l = row >> 3, b = row & 7;
#pragma unroll
      for (int j = 0; j < 4; j++) {
        int col = n0 + wc * 64 + j * 16 + lr;
        u16 vv = f2bf(acc[i][j][r] + bias[col]);
        int which = col / DD, hd = col - which * DD;
        if (which == 0) {
          int h = hd >> 6, d = hd & 63;
          qb[(((size_t)(b * HH + h)) * LL + l) * DHH + d] = vv;
        } else if (which == 1) {
          int h = hd >> 6, d = hd & 63;
          kb[(((size_t)(b * HH + h)) * LL + l) * DHH + d] = vv;
        } else {
          vtmp[(size_t)row * DD + hd] = vv;
        }
      }
    }
  }
}

// ---------------------------------------------------------------------------
// vtmp [4096,768] bf16 -> vbT [B*H, Dh, L] bf16
__global__ __launch_bounds__(256) void split_v(const u16* __restrict__ vtmp,
                                               u16* __restrict__ vbT) {
  int idx = blockIdx.x * 256 + threadIdx.x;  // over 786,432 groups of 4
  int d4 = idx & 15;
  int l = (idx >> 4) & 511;
  int bh = idx >> 13;
  int b = bh / HH, h = bh - b * HH;
  size_t src = ((size_t)(l * BB + b)) * DD + h * 64 + d4 * 4;
  uint2 vv = *(const uint2*)(vtmp + src);
  u16 v0 = (u16)(vv.x & 0xffff), v1 = (u16)(vv.x >> 16);
  u16 v2 = (u16)(vv.y & 0xffff), v3 = (u16)(vv.y >> 16);
  size_t vtb = ((size_t)bh * DHH + d4 * 4) * LL + l;
  vbT[vtb]          = v0;
  vbT[vtb + LL]     = v1;
  vbT[vtb + 2 * LL] = v2;
  vbT[vtb + 3 * LL] = v3;
}

// ---------------------------------------------------------------------------
// Merged K=64 batched MFMA (round-16-proven): flat grid 2304 blocks.
__global__ __launch_bounds__(256) void attn_k64(
    const u16* __restrict__ qb, const u16* __restrict__ kb,
    const u16* __restrict__ peb, u16* __restrict__ kpb,
    u16* __restrict__ qpb, u16* __restrict__ tb) {
  __shared__ __align__(16) u16 Asl[128 * 32];
  __shared__ __align__(16) u16 Bsl[128 * 32];
  int id = blockIdx.x;
  const u16 *A, *B;
  u16* Cb;
  int lda, ldb, ldc, m0, n0;
  if (id < 768) {
    int my = id & 3, z = id >> 2;
    int sel = z / 96, zz = z - sel * 96;
    A = (sel ? qb : kb) + (size_t)zz * (LL * DHH);
    B = peb + sel * DD + (size_t)(zz % HH) * 64;
    Cb = (sel ? qpb : kpb) + (size_t)zz * (LL * PP);
    lda = DHH; ldb = 3 * DD; ldc = PP; m0 = my * 128; n0 = 0;
  } else {
    int id2 = id - 768;
    int jx = id2 & 3, my = (id2 >> 2) & 3, bh = id2 >> 4;
    A = qb + (size_t)bh * (LL * DHH);
    B = kb + (size_t)bh * (LL * DHH);
    Cb = tb + (size_t)bh * (LL * LL);
    lda = DHH; ldb = DHH; ldc = LL; m0 = my * 128; n0 = jx * 128;
  }
  int t = threadIdx.x;
  int lane = t & 63, w = t >> 6;
  int wr = w >> 1, wc = w & 1;
  int lr = lane & 15, lg = lane >> 4;

  f32x4 acc[4][4] = {};

  const u16* Ag0 = A + (size_t)(m0 + (t >> 2)) * lda + (t & 3) * 8;
  const u16* Ag1 = A + (size_t)(m0 + 64 + (t >> 2)) * lda + (t & 3) * 8;
  const u16* Bg0 = B + (size_t)(n0 + (t >> 2)) * ldb + (t & 3) * 8;
  const u16* Bg1 = B + (size_t)(n0 + 64 + (t >> 2)) * ldb + (t & 3) * 8;
  u16* Ad0 = &Asl[t * 8];
  u16* Ad1 = &Asl[2048 + t * 8];
  u16* Bd0 = &Bsl[t * 8];
  u16* Bd1 = &Bsl[2048 + t * 8];

  for (int k0 = 0; k0 < DHH; k0 += 32) {
    GLDS(Ag0 + k0, Ad0);
    GLDS(Ag1 + k0, Ad1);
    GLDS(Bg0 + k0, Bd0);
    GLDS(Bg1 + k0, Bd1);
    __syncthreads();
    bf16x8 a[4], b[4];
#pragma unroll
    for (int i = 0; i < 4; i++)
      a[i] = *(const bf16x8*)&Asl[(wr * 64 + i * 16 + lr) * 32 + lg * 8];
#pragma unroll
    for (int j = 0; j < 4; j++)
      b[j] = *(const bf16x8*)&Bsl[(wc * 64 + j * 16 + lr) * 32 + lg * 8];
#pragma unroll
    for (int i = 0; i < 4; i++)
#pragma unroll
      for (int j = 0; j < 4; j++)
        asm volatile("v_mfma_f32_16x16x32_bf16 %0, %1, %2, %0"
                     : "+v"(acc[i][j])
                     : "v"(a[i]), "v"(b[j]));
    __syncthreads();
  }
  asm volatile("s_nop 7\n\ts_nop 7" ::);

#pragma unroll
  for (int i = 0; i < 4; i++) {
#pragma unroll
    for (int r = 0; r < 4; r++) {
      int row = m0 + wr * 64 + i * 16 + lg * 4 + r;
#pragma unroll
      for (int j = 0; j < 4; j++) {
        int col = n0 + wc * 64 + j * 16 + lr;
        Cb[(size_t)row * ldc + col] = f2bf(acc[i][j][r] * 0.125f);
      }
    }
  }
}

// ---------------------------------------------------------------------------
// Streaming gather (round-16-proven): eout = t' + kp' + qp' + edge,
// + per-tile stats. kpl/qpl staged via async GLDS. 32KB LDS.
__global__ __launch_bounds__(256) void gather_scale2(
    const u16* __restrict__ tb,
    const u16* __restrict__ kp, const u16* __restrict__ qp,
    const u8* __restrict__ bdT, const float* __restrict__ edge,
    float* __restrict__ eout, float* __restrict__ stats) {
  int bh = blockIdx.z, b = bh / HH;
  int i0 = blockIdx.y * 64, j0 = blockIdx.x * 64, jt = blockIdx.x;
  __shared__ __align__(16) u16 kpl[64][PP];
  __shared__ __align__(16) u16 qpl[64][PP];
  int tid = threadIdx.x;
  int tx = tid & 15, ty = tid >> 4;

  const u16* kpg = kp + (size_t)bh * (LL * PP);
  const u16* qpg = qp + (size_t)bh * (LL * PP);
  u16* kflat = &kpl[0][0];
  u16* qflat = &qpl[0][0];
#pragma unroll
  for (int it = 0; it < 4; it++) {
    int c = tid + it * 256;
    int row = c >> 4, ch = (c & 15) * 8;
    GLDS(&kpg[(size_t)(j0 + row) * PP + ch], &kflat[c * 8]);
    GLDS(&qpg[(size_t)(i0 + row) * PP + ch], &qflat[c * 8]);
  }
  __syncthreads();

  const u8* bd = bdT + (size_t)b * (LL * LL);
  const float* eb = edge + (size_t)bh * (LL * LL);
  const u16* tbb = tb + (size_t)bh * (LL * LL);
  float* ob = eout + (size_t)bh * (LL * LL);

  float rowm[4], rows[4];
#pragma unroll
  for (int i2 = 0; i2 < 4; i2++) {
    int row = i0 + ty * 4 + i2;
    int col0 = j0 + tx * 4;
    uchar4 p4 = *(const uchar4*)&bd[(size_t)row * LL + col0];
    float4 e4 = *(const float4*)&eb[(size_t)row * LL + col0];
    uint2 t2 = *(const uint2*)&tbb[(size_t)row * LL + col0];
    float tv[4] = {bf2f(t2.x), bf2f(t2.x >> 16), bf2f(t2.y), bf2f(t2.y >> 16)};
    int pp[4] = {p4.x, p4.y, p4.z, p4.w};
    float ee[4] = {e4.x, e4.y, e4.z, e4.w};
    float sv[4];
#pragma unroll
    for (int j2 = 0; j2 < 4; j2++) {
      float gk = bf2f((u32)kpl[tx * 4 + j2][pp[j2]]);
      float gq = bf2f((u32)qpl[ty * 4 + i2][pp[j2]]);
      sv[j2] = tv[j2] + gk + gq + ee[j2];
    }
    *(float4*)&ob[(size_t)row * LL + col0] =
        make_float4(sv[0], sv[1], sv[2], sv[3]);
    float m = fmaxf(fmaxf(sv[0], sv[1]), fmaxf(sv[2], sv[3]));
#pragma unroll
    for (int off = 1; off < 16; off <<= 1) m = fmaxf(m, __shfl_xor(m, off, 64));
    float ss = __expf(sv[0] - m) + __expf(sv[1] - m) + __expf(sv[2] - m) +
               __expf(sv[3] - m);
#pragma unroll
    for (int off = 1; off < 16; off <<= 1) ss += __shfl_xor(ss, off, 64);
    rowm[i2] = m;
    rows[i2] = ss;
  }
  if (tx == 0) {
#pragma unroll
    for (int i2 = 0; i2 < 4; i2++) {
      size_t si = ((size_t)bh * LL + i0 + ty * 4 + i2) * 16 + jt;
      stats[si] = rowm[i2];
      stats[si + 8] = rows[i2];
    }
  }
}

// ---------------------------------------------------------------------------
// MFMA softmax+PV (round-14-proven): per (bh, 64-row i-tile).
__global__ __launch_bounds__(256) void softmax_pv_mfma(
    const float* __restrict__ scores, const u16* __restrict__ vbT,
    const float* __restrict__ stats, u16* __restrict__ olbd) {
  int bh = blockIdx.y;
  int i0 = blockIdx.x * 64;
  int b = bh / HH, h = bh - b * HH;
  __shared__ __align__(16) u16 PL[2][64 * 32];
  __shared__ __align__(16) u16 VL[2][64 * 32];
  __shared__ float smax[64], srs[64];
  int tid = threadIdx.x;
  int tx = tid & 15, ty = tid >> 4;
  int lane = tid & 63, w = tid >> 6;
  int wr = w >> 1, wc = w & 1;
  int lr = lane & 15, lg = lane >> 4;
  const float* sbase = scores + (size_t)bh * (LL * LL);
  const u16* vt = vbT + (size_t)bh * (DHH * LL);

  if (tid < 64) {
    size_t si = ((size_t)bh * LL + i0 + tid) * 16;
    float m = stats[si];
#pragma unroll
    for (int j = 1; j < 8; j++) m = fmaxf(m, stats[si + j]);
    float s = 0.f;
#pragma unroll
    for (int j = 0; j < 8; j++) s += stats[si + 8 + j] * __expf(stats[si + j] - m);
    smax[tid] = m;
    srs[tid] = 1.0f / s;
  }
  __syncthreads();

  f32x4 acc[2][2] = {};
  int ks = tx >> 3, kk = (tx & 7) * 4;
  int vd = tid >> 2, vjo = (tid & 3) * 8;

  for (int jt = 0; jt < 8; jt++) {
    int j0 = jt * 64;
    GLDS(vt + (size_t)vd * LL + j0 + vjo, &VL[0][tid * 8]);
    GLDS(vt + (size_t)vd * LL + j0 + 32 + vjo, &VL[1][tid * 8]);
#pragma unroll
    for (int rr = 0; rr < 4; rr++) {
      int r = ty + rr * 16;
      float4 s4 = *(const float4*)(sbase + (size_t)(i0 + r) * LL + j0 + tx * 4);
      float m = smax[r], rs = srs[r];
      u16 p0 = f2bf(__expf(s4.x - m) * rs);
      u16 p1 = f2bf(__expf(s4.y - m) * rs);
      u16 p2 = f2bf(__expf(s4.z - m) * rs);
      u16 p3 = f2bf(__expf(s4.w - m) * rs);
      *(uint2*)&PL[ks][r * 32 + kk] =
          make_uint2((u32)p0 | ((u32)p1 << 16), (u32)p2 | ((u32)p3 << 16));
    }
    __syncthreads();
#pragma unroll
    for (int s2 = 0; s2 < 2; s2++) {
      bf16x8 a[2], bfr[2];
#pragma unroll
      for (int i = 0; i < 2; i++)
        a[i] = *(const bf16x8*)&PL[s2][(wr * 32 + i * 16 + lr) * 32 + lg * 8];
#pragma unroll
      for (int j = 0; j < 2; j++)
        bfr[j] = *(const bf16x8*)&VL[s2][(wc * 32 + j * 16 + lr) * 32 + lg * 8];
#pragma unroll
      for (int i = 0; i < 2; i++)
#pragma unroll
        for (int j = 0; j < 2; j++)
          asm volatile("v_mfma_f32_16x16x32_bf16 %0, %1, %2, %0"
                       : "+v"(acc[i][j])
                       : "v"(a[i]), "v"(bfr[j]));
    }
    __syncthreads();
  }
  asm volatile("s_nop 7\n\ts_nop 7" ::);

#pragma unroll
  for (int i = 0; i < 2; i++) {
#pragma unroll
    for (int r = 0; r < 4; r++) {
      int irow = i0 + wr * 32 + i * 16 + lg * 4 + r;
#pragma unroll
      for (int j = 0; j < 2; j++) {
        int d = wc * 32 + j * 16 + lr;
        olbd[((size_t)irow * BB + b) * DD + h * 64 + d] = f2bf(acc[i][j][r]);
      }
    }
  }
}

// ---------------------------------------------------------------------------
// Split-K partial MFMA GEMM — bf16 partial output (halved partial traffic).
__global__ __launch_bounds__(256) void gemm_mfma_part(
    const u16* __restrict__ A, int lda, const u16* __restrict__ B, int ldb,
    u16* __restrict__ Cb, int ldc, long partStride, int Kper) {
  __shared__ __align__(16) u16 Asl[128 * 32];
  __shared__ __align__(16) u16 Bsl[128 * 32];
  int z = blockIdx.z;
  A += (size_t)z * Kper;
  B += (size_t)z * Kper;
  Cb += (size_t)z * partStride;
  int t = threadIdx.x;
  int m0 = blockIdx.y * 128, n0 = blockIdx.x * 128;
  int lane = t & 63, w = t >> 6;
  int wr = w >> 1, wc = w & 1;
  int lr = lane & 15, lg = lane >> 4;

  f32x4 acc[4][4] = {};

  const u16* Ag0 = A + (size_t)(m0 + (t >> 2)) * lda + (t & 3) * 8;
  const u16* Ag1 = A + (size_t)(m0 + 64 + (t >> 2)) * lda + (t & 3) * 8;
  const u16* Bg0 = B + (size_t)(n0 + (t >> 2)) * ldb + (t & 3) * 8;
  const u16* Bg1 = B + (size_t)(n0 + 64 + (t >> 2)) * ldb + (t & 3) * 8;
  u16* Ad0 = &Asl[t * 8];
  u16* Ad1 = &Asl[2048 + t * 8];
  u16* Bd0 = &Bsl[t * 8];
  u16* Bd1 = &Bsl[2048 + t * 8];

  for (int k0 = 0; k0 < Kper; k0 += 32) {
    GLDS(Ag0 + k0, Ad0);
    GLDS(Ag1 + k0, Ad1);
    GLDS(Bg0 + k0, Bd0);
    GLDS(Bg1 + k0, Bd1);
    __syncthreads();
    bf16x8 a[4], b[4];
#pragma unroll
    for (int i = 0; i < 4; i++)
      a[i] = *(const bf16x8*)&Asl[(wr * 64 + i * 16 + lr) * 32 + lg * 8];
#pragma unroll
    for (int j = 0; j < 4; j++)
      b[j] = *(const bf16x8*)&Bsl[(wc * 64 + j * 16 + lr) * 32 + lg * 8];
#pragma unroll
    for (int i = 0; i < 4; i++)
#pragma unroll
      for (int j = 0; j < 4; j++)
        asm volatile("v_mfma_f32_16x16x32_bf16 %0, %1, %2, %0"
                     : "+v"(acc[i][j])
                     : "v"(a[i]), "v"(b[j]));
    __syncthreads();
  }
  asm volatile("s_nop 7\n\ts_nop 7" ::);

#pragma unroll
  for (int i = 0; i < 4; i++) {
#pragma unroll
    for (int r = 0; r < 4; r++) {
      int row = m0 + wr * 64 + i * 16 + lg * 4 + r;
#pragma unroll
      for (int j = 0; j < 4; j++) {
        int col = n0 + wc * 64 + j * 16 + lr;
        Cb[(size_t)row * ldc + col] = f2bf(acc[i][j][r]);
      }
    }
  }
}

// Combine NS bf16 split-K partials: out = sum(parts) + bias + res.
template <int NS>
__global__ __launch_bounds__(256) void combine_k(const u16* __restrict__ p,
                                                 const float* __restrict__ bias,
                                                 const float* __restrict__ res,
                                                 float* __restrict__ out) {
  int idx = blockIdx.x * 256 + threadIdx.x;  // over 786,432
  size_t e = (size_t)idx * 4;
  uint2 pv = *(const uint2*)(p + e);
  float s0 = bf2f(pv.x), s1 = bf2f(pv.x >> 16);
  float s2 = bf2f(pv.y), s3 = bf2f(pv.y >> 16);
#pragma unroll
  for (int z = 1; z < NS; z++) {
    uint2 t2 = *(const uint2*)(p + (size_t)z * 3145728 + e);
    s0 += bf2f(t2.x); s1 += bf2f(t2.x >> 16);
    s2 += bf2f(t2.y); s3 += bf2f(t2.y >> 16);
  }
  int col = (int)(e % DD);
  float4 b4 = *(const float4*)(bias + col);
  float4 r4 = *(const float4*)(res + e);
  *(float4*)(out + e) = make_float4(s0 + b4.x + r4.x, s1 + b4.y + r4.y,
                                    s2 + b4.z + r4.z, s3 + b4.w + r4.w);
}

// Fused combine2 (bf16 partials) + LayerNorm.
__global__ __launch_bounds__(256) void combine2_ln(
    const u16* __restrict__ p, const float* __restrict__ bias,
    const float* __restrict__ res, float* __restrict__ x1,
    const float* __restrict__ w, const float* __restrict__ lb,
    u16* __restrict__ xnb) {
  __shared__ float sbuf[8];
  size_t row = blockIdx.x;
  int t = threadIdx.x;
  const u16* p0 = p + row * DD;
  const u16* p1 = p + 3145728 + row * DD;
  const float* rr = res + row * DD;
  float v0 = bf2f((u32)p0[t])       + bf2f((u32)p1[t])       + bias[t]       + rr[t];
  float v1 = bf2f((u32)p0[t + 256]) + bf2f((u32)p1[t + 256]) + bias[t + 256] + rr[t + 256];
  float v2 = bf2f((u32)p0[t + 512]) + bf2f((u32)p1[t + 512]) + bias[t + 512] + rr[t + 512];
  float* xr = x1 + row * DD;
  xr[t] = v0; xr[t + 256] = v1; xr[t + 512] = v2;
  float s = v0 + v1 + v2;
  float ss = v0 * v0 + v1 * v1 + v2 * v2;
  block_reduce2(s, ss, sbuf);
  float mu = s * (1.0f / DD);
  float var = ss * (1.0f / DD) - mu * mu;
  float r = rsqrtf(var + 1e-5f);
  u16* orow = xnb + row * DD;
  orow[t]       = f2bf((v0 - mu) * r * w[t]       + lb[t]);
  orow[t + 256] = f2bf((v1 - mu) * r * w[t + 256] + lb[t + 256]);
  orow[t + 512] = f2bf((v2 - mu) * r * w[t + 512] + lb[t + 512]);
}

// ---------------------------------------------------------------------------
extern "C" void kernel_launch(void* const* d_in, const int* in_sizes, int n_in,
                              void* d_out, int out_size, void* d_ws, size_t ws_size,
                              hipStream_t stream) {
  const float* x      = (const float*)d_in[0];
  const float* edge   = (const float*)d_in[1];
  const int*   bdist  = (const int*)d_in[2];
  const float* W_in   = (const float*)d_in[3];
  const float* b_in   = (const float*)d_in[4];
  const float* pe_emb = (const float*)d_in[5];
  const float* W_out  = (const float*)d_in[6];
  const float* b_out  = (const float*)d_in[7];
  const float* W1     = (const float*)d_in[8];
  const float* b1     = (const float*)d_in[9];
  const float* W2     = (const float*)d_in[10];
  const float* b2     = (const float*)d_in[11];
  const float* ln1w   = (const float*)d_in[12];
  const float* ln1b   = (const float*)d_in[13];
  const float* ln2w   = (const float*)d_in[14];
  const float* ln2b   = (const float*)d_in[15];

  float* xout = (float*)d_out;                 // [L,B,D]
  float* eout = xout + (size_t)LL * BB * DD;   // [B*H,L,L] == final scores

  // Workspace layout (float units) — round-16-proven (part now bf16).
  float* ws = (float*)d_ws;
  u16*   xnb    = (u16*)(ws + 0);          // [4096,768] bf16
  u16*   tb     = (u16*)(ws + 1600000);    // t' bf16 [96,512,512]
  u16*   olbdb  = (u16*)(ws + 1600000);    // bf16 O (after gather; tb dead)
  u16*   ff1b   = (u16*)(ws + 3200000);    // [4096,3072] bf16 (step 9)
  float* x1     = ws + 11100000;           // (step 8)
  u16*   peemb  = (u16*)(ws + 14300000);   // [128,768] bf16
  u16*   vtmp   = (u16*)(ws + 14600000);   // [4096,768] bf16 (dead by step 8)
  u16*   part   = (u16*)(ws + 14600000);   // bf16 split-K partials (8,10)
  u16*   vbT    = (u16*)(ws + 21000000);   // [96,64,512] bf16 transposed V
  float* stats  = ws + 22600000;           // [96,512,16]
  u8*    bdT    = (u8*)(ws + 23400000);    // [8,512,512] u8
  u16*   kpb    = (u16*)(ws + 24000000);   // [96,512,128] bf16
  u16*   qpb    = (u16*)(ws + 27200000);
  u16*   W1b    = (u16*)(ws + 30400000);
  u16*   W2b    = (u16*)(ws + 31600000);
  u16*   W_inb  = (u16*)(ws + 32800000);
  u16*   W_outb = (u16*)(ws + 33700000);
  u16*   qb     = (u16*)(ws + 34000000);
  u16*   kb     = (u16*)(ws + 35600000);
  u16*   peb    = (u16*)(ws + 37200000);   // [128,2304] bf16

  // 1) all prep (LN1 + 5 conversions + bdist transpose) in one launch
  prep_kernel<<<19296, 256, 0, stream>>>(x, ln1w, ln1b, xnb, W_in, W_inb,
                                         W_out, W_outb, W1, W1b, W2, W2b,
                                         pe_emb, peemb, bdist, bdT);
  // 2) qkv GEMM -> qb/kb direct [B,H,L,Dh] + vtmp linear
  gemm_mfma_qkv<<<dim3(18, 32), 256, 0, stream>>>(xnb, W_inb, b_in, qb, kb,
                                                  vtmp);
  // 3) pe_proj = pe_emb @ W_in^T + b_in (MFMA, bf16 out)
  gemm_mfma<0, 1, 0><<<dim3(18, 1), 256, 0, stream>>>(
      peemb, DD, W_inb, DD, peb, 3 * DD, b_in, nullptr, DD);
  // 4) v -> vbT transpose
  split_v<<<3072, 256, 0, stream>>>(vtmp, vbT);
  // 5) merged kp'/qp' + t' (flat 2304-block K=64 batched MFMA)
  attn_k64<<<2304, 256, 0, stream>>>(qb, kb, peb, kpb, qpb, tb);
  // 6) eout = t' + kp' + qp' + edge, + softmax tile stats
  gather_scale2<<<dim3(8, 8, 96), 256, 0, stream>>>(tb, kpb, qpb, bdT, edge,
                                                    eout, stats);
  // 7) MFMA softmax + PV -> olbd bf16 [L,B,D]
  softmax_pv_mfma<<<dim3(8, 96), 256, 0, stream>>>(eout, vbT, stats, olbdb);
  // 8) x1 = O @ W_out^T + b_out + x (split-K=2, bf16 parts) + combine+LN2
  gemm_mfma_part<<<dim3(6, 32, 2), 256, 0, stream>>>(
      olbdb, DD, W_outb, DD, part, DD, 3145728L, DD / 2);
  combine2_ln<<<4096, 256, 0, stream>>>(part, b_out, x, x1, ln2w, ln2b, xnb);
  // 9) ff1 = gelu(xn @ W1^T + b1) (bf16 out)
  gemm_mfma<1, 1, 0><<<dim3(24, 32), 256, 0, stream>>>(
      xnb, DD, W1b, DD, ff1b, 4 * DD, b1, nullptr, DD);
  // 10) x_out = ff1 @ W2^T + b2 + x1  (split-K=4, bf16 parts + combine)
  gemm_mfma_part<<<dim3(6, 32, 4), 256, 0, stream>>>(
      ff1b, 4 * DD, W2b, 4 * DD, part, DD, 3145728L, DD);
  combine_k<4><<<3072, 256, 0, stream>>>(part, b2, x1, xout);
}

// Round 20
// 293.794 us; speedup vs baseline: 1.9140x; 1.0748x over previous
//
#include <hip/hip_runtime.h>
#include <hip/hip_bf16.h>
#include <math.h>

// Problem constants
#define LL 512
#define BB 8
#define DD 768
#define HH 12
#define DHH 64
#define PP 128

typedef unsigned char u8;
typedef unsigned short u16;
typedef unsigned int u32;
typedef __attribute__((ext_vector_type(8))) short bf16x8;
typedef __attribute__((ext_vector_type(4))) float f32x4;

__device__ __forceinline__ u16 f2bf(float f) {
  u32 u = __float_as_uint(f);
  u32 r = (u + 0x7fffu + ((u >> 16) & 1u)) >> 16;
  return (u16)r;
}
__device__ __forceinline__ float bf2f(u32 u) {
  return __uint_as_float((u & 0xffffu) << 16);
}

#define GLDS(g, l)                                                             \
  __builtin_amdgcn_global_load_lds(                                            \
      (const __attribute__((address_space(1))) void*)(g),                      \
      (__attribute__((address_space(3))) void*)(l), 16, 0, 0)

// ---------------------------------------------------------------------------
__device__ __forceinline__ void block_reduce2(float& a, float& b, float* sbuf) {
#pragma unroll
  for (int off = 32; off > 0; off >>= 1) {
    a += __shfl_down(a, off, 64);
    b += __shfl_down(b, off, 64);
  }
  int wid = threadIdx.x >> 6, lane = threadIdx.x & 63;
  __syncthreads();
  if (lane == 0) { sbuf[wid] = a; sbuf[4 + wid] = b; }
  __syncthreads();
  a = sbuf[0] + sbuf[1] + sbuf[2] + sbuf[3];
  b = sbuf[4] + sbuf[5] + sbuf[6] + sbuf[7];
}

// ---------------------------------------------------------------------------
// Mega-prep: [0,4096) LN1 rows; [4096,11008) weight f2b (4 ranges);
// [11008,11104) pe_emb f2b; [11104,19296) bdist transpose.
__global__ __launch_bounds__(256) void prep_kernel(
    const float* __restrict__ x, const float* __restrict__ ln1w,
    const float* __restrict__ ln1b, u16* __restrict__ xnb,
    const float* __restrict__ W_in, u16* __restrict__ W_inb,
    const float* __restrict__ W_out, u16* __restrict__ W_outb,
    const float* __restrict__ W1, u16* __restrict__ W1b,
    const float* __restrict__ W2, u16* __restrict__ W2b,
    const float* __restrict__ pe_emb, u16* __restrict__ peemb,
    const int* __restrict__ bdist, u8* __restrict__ bdT) {
  int blk = blockIdx.x;
  int t = threadIdx.x;
  if (blk < 4096) {
    __shared__ float sbuf[8];
    const float* xr = x + (size_t)blk * DD;
    float v0 = xr[t], v1 = xr[t + 256], v2 = xr[t + 512];
    float s = v0 + v1 + v2;
    float ss = v0 * v0 + v1 * v1 + v2 * v2;
    block_reduce2(s, ss, sbuf);
    float mu = s * (1.0f / DD);
    float var = ss * (1.0f / DD) - mu * mu;
    float r = rsqrtf(var + 1e-5f);
    u16* orow = xnb + (size_t)blk * DD;
    orow[t]       = f2bf((v0 - mu) * r * ln1w[t]       + ln1b[t]);
    orow[t + 256] = f2bf((v1 - mu) * r * ln1w[t + 256] + ln1b[t + 256]);
    orow[t + 512] = f2bf((v2 - mu) * r * ln1w[t + 512] + ln1b[t + 512]);
  } else if (blk < 11008) {
    int idx = (blk - 4096) * 256 + t;  // 0..1769471
    const float* in;
    u16* out;
    if (idx < 442368) { in = W_in; out = W_inb; }
    else if (idx < 589824) { in = W_out; out = W_outb; idx -= 442368; }
    else if (idx < 1179648) { in = W1; out = W1b; idx -= 589824; }
    else { in = W2; out = W2b; idx -= 1179648; }
    float4 v = *(const float4*)(in + (size_t)idx * 4);
    u32 lo = (u32)f2bf(v.x) | ((u32)f2bf(v.y) << 16);
    u32 hi = (u32)f2bf(v.z) | ((u32)f2bf(v.w) << 16);
    *(uint2*)(out + (size_t)idx * 4) = make_uint2(lo, hi);
  } else if (blk < 11104) {
    int idx = (blk - 11008) * 256 + t;  // 0..24575
    float4 v = *(const float4*)(pe_emb + (size_t)idx * 4);
    u32 lo = (u32)f2bf(v.x) | ((u32)f2bf(v.y) << 16);
    u32 hi = (u32)f2bf(v.z) | ((u32)f2bf(v.w) << 16);
    *(uint2*)(peemb + (size_t)idx * 4) = make_uint2(lo, hi);
  } else {
    int i = (blk - 11104) * 256 + t;  // 0..2097151
    int b = i & 7, jj = (i >> 3) & 511, ii = i >> 12;
    bdT[((size_t)b << 18) + ((size_t)ii << 9) + jj] = (u8)bdist[i];
  }
}

// ---------------------------------------------------------------------------
// bf16 MFMA GEMM (round-3-proven): C = act(A * B^T + bias) [+ residual].
template <int ACT, int OBF, int RES>
__global__ __launch_bounds__(256) void gemm_mfma(
    const u16* __restrict__ A, int lda, const u16* __restrict__ B, int ldb,
    void* __restrict__ Cv, int ldc, const float* __restrict__ bias,
    const float* __restrict__ residual, int K) {
  __shared__ __align__(16) u16 Asl[128 * 32];
  __shared__ __align__(16) u16 Bsl[128 * 32];
  int t = threadIdx.x;
  int m0 = blockIdx.y * 128, n0 = blockIdx.x * 128;
  int lane = t & 63, w = t >> 6;
  int wr = w >> 1, wc = w & 1;
  int lr = lane & 15, lg = lane >> 4;

  f32x4 acc[4][4] = {};

  const u16* Ag0 = A + (size_t)(m0 + (t >> 2)) * lda + (t & 3) * 8;
  const u16* Ag1 = A + (size_t)(m0 + 64 + (t >> 2)) * lda + (t & 3) * 8;
  const u16* Bg0 = B + (size_t)(n0 + (t >> 2)) * ldb + (t & 3) * 8;
  const u16* Bg1 = B + (size_t)(n0 + 64 + (t >> 2)) * ldb + (t & 3) * 8;
  u16* Ad0 = &Asl[t * 8];
  u16* Ad1 = &Asl[2048 + t * 8];
  u16* Bd0 = &Bsl[t * 8];
  u16* Bd1 = &Bsl[2048 + t * 8];

  for (int k0 = 0; k0 < K; k0 += 32) {
    GLDS(Ag0 + k0, Ad0);
    GLDS(Ag1 + k0, Ad1);
    GLDS(Bg0 + k0, Bd0);
    GLDS(Bg1 + k0, Bd1);
    __syncthreads();
    bf16x8 a[4], b[4];
#pragma unroll
    for (int i = 0; i < 4; i++)
      a[i] = *(const bf16x8*)&Asl[(wr * 64 + i * 16 + lr) * 32 + lg * 8];
#pragma unroll
    for (int j = 0; j < 4; j++)
      b[j] = *(const bf16x8*)&Bsl[(wc * 64 + j * 16 + lr) * 32 + lg * 8];
#pragma unroll
    for (int i = 0; i < 4; i++)
#pragma unroll
      for (int j = 0; j < 4; j++)
        asm volatile("v_mfma_f32_16x16x32_bf16 %0, %1, %2, %0"
                     : "+v"(acc[i][j])
                     : "v"(a[i]), "v"(b[j]));
    __syncthreads();
  }
  asm volatile("s_nop 7\n\ts_nop 7" ::);

  float* Cf = (float*)Cv;
  u16* Cb = (u16*)Cv;
#pragma unroll
  for (int i = 0; i < 4; i++) {
#pragma unroll
    for (int r = 0; r < 4; r++) {
      int row = m0 + wr * 64 + i * 16 + lg * 4 + r;
#pragma unroll
      for (int j = 0; j < 4; j++) {
        int col = n0 + wc * 64 + j * 16 + lr;
        float vv = acc[i][j][r];
        if (bias) vv += bias[col];
        if (ACT) vv = 0.5f * vv * (1.0f + erff(vv * 0.70710678118654752f));
        if (RES) vv += residual[(size_t)row * ldc + col];
        if (OBF) Cb[(size_t)row * ldc + col] = f2bf(vv);
        else     Cf[(size_t)row * ldc + col] = vv;
      }
    }
  }
}

// ---------------------------------------------------------------------------
// qkv + pe_proj GEMM (proven core): grid (18, 33).
// blockIdx.y < 32: A=xnb rows, epilogue scatters q/k to [B,H,L,Dh] and V
//   directly to vbT [B*H,Dh,L] (replaces vtmp + split_v).
// blockIdx.y == 32: A=peemb (M=128), epilogue writes peb linear bf16.
__global__ __launch_bounds__(256) void gemm_mfma_qkv(
    const u16* __restrict__ xnb, const u16* __restrict__ peemb,
    const u16* __restrict__ B, const float* __restrict__ bias,
    u16* __restrict__ qb, u16* __restrict__ kb, u16* __restrict__ vbT,
    u16* __restrict__ peb) {
  __shared__ __align__(16) u16 Asl[128 * 32];
  __shared__ __align__(16) u16 Bsl[128 * 32];
  const int lda = DD, ldb = DD, K = DD;
  int t = threadIdx.x;
  int isPE = (blockIdx.y == 32);
  const u16* A = isPE ? peemb : xnb;
  int m0 = isPE ? 0 : blockIdx.y * 128;
  int n0 = blockIdx.x * 128;
  int lane = t & 63, w = t >> 6;
  int wr = w >> 1, wc = w & 1;
  int lr = lane & 15, lg = lane >> 4;

  f32x4 acc[4][4] = {};

  const u16* Ag0 = A + (size_t)(m0 + (t >> 2)) * lda + (t & 3) * 8;
  const u16* Ag1 = A + (size_t)(m0 + 64 + (t >> 2)) * lda + (t & 3) * 8;
  const u16* Bg0 = B + (size_t)(n0 + (t >> 2)) * ldb + (t & 3) * 8;
  const u16* Bg1 = B + (size_t)(n0 + 64 + (t >> 2)) * ldb + (t & 3) * 8;
  u16* Ad0 = &Asl[t * 8];
  u16* Ad1 = &Asl[2048 + t * 8];
  u16* Bd0 = &Bsl[t * 8];
  u16* Bd1 = &Bsl[2048 + t * 8];

  for (int k0 = 0; k0 < K; k0 += 32) {
    GLDS(Ag0 + k0, Ad0);
    GLDS(Ag1 + k0, Ad1);
    GLDS(Bg0 + k0, Bd0);
    GLDS(Bg1 + k0, Bd1);
    __syncthreads();
    bf16x8 a[4], b[4];
#pragma unroll
    for (int i = 0; i < 4; i++)
      a[i] = *(const bf16x8*)&Asl[(wr * 64 + i * 16 + lr) * 32 + lg * 8];
#pragma unroll
    for (int j = 0; j < 4; j++)
      b[j] = *(const bf16x8*)&Bsl[(wc * 64 + j * 16 + lr) * 32 + lg * 8];
#pragma unroll
    for (int i = 0; i < 4; i++)
#pragma unroll
      for (int j = 0; j < 4; j++)
        asm volatile("v_mfma_f32_16x16x32_bf16 %0, %1, %2, %0"
                     : "+v"(acc[i][j])
                     : "v"(a[i]), "v"(b[j]));
    __syncthreads();
  }
  asm volatile("s_nop 7\n\ts_nop 7" ::);

#pragma unroll
  for (int i = 0; i < 4; i++) {
#pragma unroll
    for (int r = 0; r < 4; r++) {
      int row = m0 + wr * 64 + i * 16 + lg * 4 + r;
      int l = row >> 3, b = row & 7;
#pragma unroll
      for (int j = 0; j < 4; j++) {
        int col = n0 + wc * 64 + j * 16 + lr;
        u16 vv = f2bf(acc[i][j][r] + bias[col]);
        if (isPE) {
          peb[(size_t)row * (3 * DD) + col] = vv;
        } else {
          int which = col / DD, hd = col - which * DD;
          int h = hd >> 6, d = hd & 63;
          if (which == 0) {
            qb[(((size_t)(b * HH + h)) * LL + l) * DHH + d] = vv;
          } else if (which == 1) {
            kb[(((size_t)(b * HH + h)) * LL + l) * DHH + d] = vv;
          } else {
            vbT[(((size_t)(b * HH + h)) * DHH + d) * LL + l] = vv;
          }
        }
      }
    }
  }
}

// ---------------------------------------------------------------------------
// Merged K=64 batched MFMA (round-16-proven): flat grid 2304 blocks.
__global__ __launch_bounds__(256) void attn_k64(
    const u16* __restrict__ qb, const u16* __restrict__ kb,
    const u16* __restrict__ peb, u16* __restrict__ kpb,
    u16* __restrict__ qpb, u16* __restrict__ tb) {
  __shared__ __align__(16) u16 Asl[128 * 32];
  __shared__ __align__(16) u16 Bsl[128 * 32];
  int id = blockIdx.x;
  const u16 *A, *B;
  u16* Cb;
  int lda, ldb, ldc, m0, n0;
  if (id < 768) {
    int my = id & 3, z = id >> 2;
    int sel = z / 96, zz = z - sel * 96;
    A = (sel ? qb : kb) + (size_t)zz * (LL * DHH);
    B = peb + sel * DD + (size_t)(zz % HH) * 64;
    Cb = (sel ? qpb : kpb) + (size_t)zz * (LL * PP);
    lda = DHH; ldb = 3 * DD; ldc = PP; m0 = my * 128; n0 = 0;
  } else {
    int id2 = id - 768;
    int jx = id2 & 3, my = (id2 >> 2) & 3, bh = id2 >> 4;
    A = qb + (size_t)bh * (LL * DHH);
    B = kb + (size_t)bh * (LL * DHH);
    Cb = tb + (size_t)bh * (LL * LL);
    lda = DHH; ldb = DHH; ldc = LL; m0 = my * 128; n0 = jx * 128;
  }
  int t = threadIdx.x;
  int lane = t & 63, w = t >> 6;
  int wr = w >> 1, wc = w & 1;
  int lr = lane & 15, lg = lane >> 4;

  f32x4 acc[4][4] = {};

  const u16* Ag0 = A + (size_t)(m0 + (t >> 2)) * lda + (t & 3) * 8;
  const u16* Ag1 = A + (size_t)(m0 + 64 + (t >> 2)) * lda + (t & 3) * 8;
  const u16* Bg0 = B + (size_t)(n0 + (t >> 2)) * ldb + (t & 3) * 8;
  const u16* Bg1 = B + (size_t)(n0 + 64 + (t >> 2)) * ldb + (t & 3) * 8;
  u16* Ad0 = &Asl[t * 8];
  u16* Ad1 = &Asl[2048 + t * 8];
  u16* Bd0 = &Bsl[t * 8];
  u16* Bd1 = &Bsl[2048 + t * 8];

  for (int k0 = 0; k0 < DHH; k0 += 32) {
    GLDS(Ag0 + k0, Ad0);
    GLDS(Ag1 + k0, Ad1);
    GLDS(Bg0 + k0, Bd0);
    GLDS(Bg1 + k0, Bd1);
    __syncthreads();
    bf16x8 a[4], b[4];
#pragma unroll
    for (int i = 0; i < 4; i++)
      a[i] = *(const bf16x8*)&Asl[(wr * 64 + i * 16 + lr) * 32 + lg * 8];
#pragma unroll
    for (int j = 0; j < 4; j++)
      b[j] = *(const bf16x8*)&Bsl[(wc * 64 + j * 16 + lr) * 32 + lg * 8];
#pragma unroll
    for (int i = 0; i < 4; i++)
#pragma unroll
      for (int j = 0; j < 4; j++)
        asm volatile("v_mfma_f32_16x16x32_bf16 %0, %1, %2, %0"
                     : "+v"(acc[i][j])
                     : "v"(a[i]), "v"(b[j]));
    __syncthreads();
  }
  asm volatile("s_nop 7\n\ts_nop 7" ::);

#pragma unroll
  for (int i = 0; i < 4; i++) {
#pragma unroll
    for (int r = 0; r < 4; r++) {
      int row = m0 + wr * 64 + i * 16 + lg * 4 + r;
#pragma unroll
      for (int j = 0; j < 4; j++) {
        int col = n0 + wc * 64 + j * 16 + lr;
        Cb[(size_t)row * ldc + col] = f2bf(acc[i][j][r] * 0.125f);
      }
    }
  }
}

// ---------------------------------------------------------------------------
// Streaming gather (round-16-proven): eout = t' + kp' + qp' + edge,
// + per-tile stats. kpl/qpl staged via async GLDS. 32KB LDS.
__global__ __launch_bounds__(256) void gather_scale2(
    const u16* __restrict__ tb,
    const u16* __restrict__ kp, const u16* __restrict__ qp,
    const u8* __restrict__ bdT, const float* __restrict__ edge,
    float* __restrict__ eout, float* __restrict__ stats) {
  int bh = blockIdx.z, b = bh / HH;
  int i0 = blockIdx.y * 64, j0 = blockIdx.x * 64, jt = blockIdx.x;
  __shared__ __align__(16) u16 kpl[64][PP];
  __shared__ __align__(16) u16 qpl[64][PP];
  int tid = threadIdx.x;
  int tx = tid & 15, ty = tid >> 4;

  const u16* kpg = kp + (size_t)bh * (LL * PP);
  const u16* qpg = qp + (size_t)bh * (LL * PP);
  u16* kflat = &kpl[0][0];
  u16* qflat = &qpl[0][0];
#pragma unroll
  for (int it = 0; it < 4; it++) {
    int c = tid + it * 256;
    int row = c >> 4, ch = (c & 15) * 8;
    GLDS(&kpg[(size_t)(j0 + row) * PP + ch], &kflat[c * 8]);
    GLDS(&qpg[(size_t)(i0 + row) * PP + ch], &qflat[c * 8]);
  }
  __syncthreads();

  const u8* bd = bdT + (size_t)b * (LL * LL);
  const float* eb = edge + (size_t)bh * (LL * LL);
  const u16* tbb = tb + (size_t)bh * (LL * LL);
  float* ob = eout + (size_t)bh * (LL * LL);

  float rowm[4], rows[4];
#pragma unroll
  for (int i2 = 0; i2 < 4; i2++) {
    int row = i0 + ty * 4 + i2;
    int col0 = j0 + tx * 4;
    uchar4 p4 = *(const uchar4*)&bd[(size_t)row * LL + col0];
    float4 e4 = *(const float4*)&eb[(size_t)row * LL + col0];
    uint2 t2 = *(const uint2*)&tbb[(size_t)row * LL + col0];
    float tv[4] = {bf2f(t2.x), bf2f(t2.x >> 16), bf2f(t2.y), bf2f(t2.y >> 16)};
    int pp[4] = {p4.x, p4.y, p4.z, p4.w};
    float ee[4] = {e4.x, e4.y, e4.z, e4.w};
    float sv[4];
#pragma unroll
    for (int j2 = 0; j2 < 4; j2++) {
      float gk = bf2f((u32)kpl[tx * 4 + j2][pp[j2]]);
      float gq = bf2f((u32)qpl[ty * 4 + i2][pp[j2]]);
      sv[j2] = tv[j2] + gk + gq + ee[j2];
    }
    *(float4*)&ob[(size_t)row * LL + col0] =
        make_float4(sv[0], sv[1], sv[2], sv[3]);
    float m = fmaxf(fmaxf(sv[0], sv[1]), fmaxf(sv[2], sv[3]));
#pragma unroll
    for (int off = 1; off < 16; off <<= 1) m = fmaxf(m, __shfl_xor(m, off, 64));
    float ss = __expf(sv[0] - m) + __expf(sv[1] - m) + __expf(sv[2] - m) +
               __expf(sv[3] - m);
#pragma unroll
    for (int off = 1; off < 16; off <<= 1) ss += __shfl_xor(ss, off, 64);
    rowm[i2] = m;
    rows[i2] = ss;
  }
  if (tx == 0) {
#pragma unroll
    for (int i2 = 0; i2 < 4; i2++) {
      size_t si = ((size_t)bh * LL + i0 + ty * 4 + i2) * 16 + jt;
      stats[si] = rowm[i2];
      stats[si + 8] = rows[i2];
    }
  }
}

// ---------------------------------------------------------------------------
// MFMA softmax+PV (round-14-proven): per (bh, 64-row i-tile).
__global__ __launch_bounds__(256) void softmax_pv_mfma(
    const float* __restrict__ scores, const u16* __restrict__ vbT,
    const float* __restrict__ stats, u16* __restrict__ olbd) {
  int bh = blockIdx.y;
  int i0 = blockIdx.x * 64;
  int b = bh / HH, h = bh - b * HH;
  __shared__ __align__(16) u16 PL[2][64 * 32];
  __shared__ __align__(16) u16 VL[2][64 * 32];
  __shared__ float smax[64], srs[64];
  int tid = threadIdx.x;
  int tx = tid & 15, ty = tid >> 4;
  int lane = tid & 63, w = tid >> 6;
  int wr = w >> 1, wc = w & 1;
  int lr = lane & 15, lg = lane >> 4;
  const float* sbase = scores + (size_t)bh * (LL * LL);
  const u16* vt = vbT + (size_t)bh * (DHH * LL);

  if (tid < 64) {
    size_t si = ((size_t)bh * LL + i0 + tid) * 16;
    float m = stats[si];
#pragma unroll
    for (int j = 1; j < 8; j++) m = fmaxf(m, stats[si + j]);
    float s = 0.f;
#pragma unroll
    for (int j = 0; j < 8; j++) s += stats[si + 8 + j] * __expf(stats[si + j] - m);
    smax[tid] = m;
    srs[tid] = 1.0f / s;
  }
  __syncthreads();

  f32x4 acc[2][2] = {};
  int ks = tx >> 3, kk = (tx & 7) * 4;
  int vd = tid >> 2, vjo = (tid & 3) * 8;

  for (int jt = 0; jt < 8; jt++) {
    int j0 = jt * 64;
    GLDS(vt + (size_t)vd * LL + j0 + vjo, &VL[0][tid * 8]);
    GLDS(vt + (size_t)vd * LL + j0 + 32 + vjo, &VL[1][tid * 8]);
#pragma unroll
    for (int rr = 0; rr < 4; rr++) {
      int r = ty + rr * 16;
      float4 s4 = *(const float4*)(sbase + (size_t)(i0 + r) * LL + j0 + tx * 4);
      float m = smax[r], rs = srs[r];
      u16 p0 = f2bf(__expf(s4.x - m) * rs);
      u16 p1 = f2bf(__expf(s4.y - m) * rs);
      u16 p2 = f2bf(__expf(s4.z - m) * rs);
      u16 p3 = f2bf(__expf(s4.w - m) * rs);
      *(uint2*)&PL[ks][r * 32 + kk] =
          make_uint2((u32)p0 | ((u32)p1 << 16), (u32)p2 | ((u32)p3 << 16));
    }
    __syncthreads();
#pragma unroll
    for (int s2 = 0; s2 < 2; s2++) {
      bf16x8 a[2], bfr[2];
#pragma unroll
      for (int i = 0; i < 2; i++)
        a[i] = *(const bf16x8*)&PL[s2][(wr * 32 + i * 16 + lr) * 32 + lg * 8];
#pragma unroll
      for (int j = 0; j < 2; j++)
        bfr[j] = *(const bf16x8*)&VL[s2][(wc * 32 + j * 16 + lr) * 32 + lg * 8];
#pragma unroll
      for (int i = 0; i < 2; i++)
#pragma unroll
        for (int j = 0; j < 2; j++)
          asm volatile("v_mfma_f32_16x16x32_bf16 %0, %1, %2, %0"
                       : "+v"(acc[i][j])
                       : "v"(a[i]), "v"(bfr[j]));
    }
    __syncthreads();
  }
  asm volatile("s_nop 7\n\ts_nop 7" ::);

#pragma unroll
  for (int i = 0; i < 2; i++) {
#pragma unroll
    for (int r = 0; r < 4; r++) {
      int irow = i0 + wr * 32 + i * 16 + lg * 4 + r;
#pragma unroll
      for (int j = 0; j < 2; j++) {
        int d = wc * 32 + j * 16 + lr;
        olbd[((size_t)irow * BB + b) * DD + h * 64 + d] = f2bf(acc[i][j][r]);
      }
    }
  }
}

// ---------------------------------------------------------------------------
// Split-K partial MFMA GEMM — bf16 partial output (round-19-proven).
__global__ __launch_bounds__(256) void gemm_mfma_part(
    const u16* __restrict__ A, int lda, const u16* __restrict__ B, int ldb,
    u16* __restrict__ Cb, int ldc, long partStride, int Kper) {
  __shared__ __align__(16) u16 Asl[128 * 32];
  __shared__ __align__(16) u16 Bsl[128 * 32];
  int z = blockIdx.z;
  A += (size_t)z * Kper;
  B += (size_t)z * Kper;
  Cb += (size_t)z * partStride;
  int t = threadIdx.x;
  int m0 = blockIdx.y * 128, n0 = blockIdx.x * 128;
  int lane = t & 63, w = t >> 6;
  int wr = w >> 1, wc = w & 1;
  int lr = lane & 15, lg = lane >> 4;

  f32x4 acc[4][4] = {};

  const u16* Ag0 = A + (size_t)(m0 + (t >> 2)) * lda + (t & 3) * 8;
  const u16* Ag1 = A + (size_t)(m0 + 64 + (t >> 2)) * lda + (t & 3) * 8;
  const u16* Bg0 = B + (size_t)(n0 + (t >> 2)) * ldb + (t & 3) * 8;
  const u16* Bg1 = B + (size_t)(n0 + 64 + (t >> 2)) * ldb + (t & 3) * 8;
  u16* Ad0 = &Asl[t * 8];
  u16* Ad1 = &Asl[2048 + t * 8];
  u16* Bd0 = &Bsl[t * 8];
  u16* Bd1 = &Bsl[2048 + t * 8];

  for (int k0 = 0; k0 < Kper; k0 += 32) {
    GLDS(Ag0 + k0, Ad0);
    GLDS(Ag1 + k0, Ad1);
    GLDS(Bg0 + k0, Bd0);
    GLDS(Bg1 + k0, Bd1);
    __syncthreads();
    bf16x8 a[4], b[4];
#pragma unroll
    for (int i = 0; i < 4; i++)
      a[i] = *(const bf16x8*)&Asl[(wr * 64 + i * 16 + lr) * 32 + lg * 8];
#pragma unroll
    for (int j = 0; j < 4; j++)
      b[j] = *(const bf16x8*)&Bsl[(wc * 64 + j * 16 + lr) * 32 + lg * 8];
#pragma unroll
    for (int i = 0; i < 4; i++)
#pragma unroll
      for (int j = 0; j < 4; j++)
        asm volatile("v_mfma_f32_16x16x32_bf16 %0, %1, %2, %0"
                     : "+v"(acc[i][j])
                     : "v"(a[i]), "v"(b[j]));
    __syncthreads();
  }
  asm volatile("s_nop 7\n\ts_nop 7" ::);

#pragma unroll
  for (int i = 0; i < 4; i++) {
#pragma unroll
    for (int r = 0; r < 4; r++) {
      int row = m0 + wr * 64 + i * 16 + lg * 4 + r;
#pragma unroll
      for (int j = 0; j < 4; j++) {
        int col = n0 + wc * 64 + j * 16 + lr;
        Cb[(size_t)row * ldc + col] = f2bf(acc[i][j][r]);
      }
    }
  }
}

// Combine NS bf16 split-K partials: out = sum(parts) + bias + res.
template <int NS>
__global__ __launch_bounds__(256) void combine_k(const u16* __restrict__ p,
                                                 const float* __restrict__ bias,
                                                 const float* __restrict__ res,
                                                 float* __restrict__ out) {
  int idx = blockIdx.x * 256 + threadIdx.x;  // over 786,432
  size_t e = (size_t)idx * 4;
  uint2 pv = *(const uint2*)(p + e);
  float s0 = bf2f(pv.x), s1 = bf2f(pv.x >> 16);
  float s2 = bf2f(pv.y), s3 = bf2f(pv.y >> 16);
#pragma unroll
  for (int z = 1; z < NS; z++) {
    uint2 t2 = *(const uint2*)(p + (size_t)z * 3145728 + e);
    s0 += bf2f(t2.x); s1 += bf2f(t2.x >> 16);
    s2 += bf2f(t2.y); s3 += bf2f(t2.y >> 16);
  }
  int col = (int)(e % DD);
  float4 b4 = *(const float4*)(bias + col);
  float4 r4 = *(const float4*)(res + e);
  *(float4*)(out + e) = make_float4(s0 + b4.x + r4.x, s1 + b4.y + r4.y,
                                    s2 + b4.z + r4.z, s3 + b4.w + r4.w);
}

// Fused combine2 (bf16 partials) + LayerNorm (round-19-proven).
__global__ __launch_bounds__(256) void combine2_ln(
    const u16* __restrict__ p, const float* __restrict__ bias,
    const float* __restrict__ res, float* __restrict__ x1,
    const float* __restrict__ w, const float* __restrict__ lb,
    u16* __restrict__ xnb) {
  __shared__ float sbuf[8];
  size_t row = blockIdx.x;
  int t = threadIdx.x;
  const u16* p0 = p + row * DD;
  const u16* p1 = p + 3145728 + row * DD;
  const float* rr = res + row * DD;
  float v0 = bf2f((u32)p0[t])       + bf2f((u32)p1[t])       + bias[t]       + rr[t];
  float v1 = bf2f((u32)p0[t + 256]) + bf2f((u32)p1[t + 256]) + bias[t + 256] + rr[t + 256];
  float v2 = bf2f((u32)p0[t + 512]) + bf2f((u32)p1[t + 512]) + bias[t + 512] + rr[t + 512];
  float* xr = x1 + row * DD;
  xr[t] = v0; xr[t + 256] = v1; xr[t + 512] = v2;
  float s = v0 + v1 + v2;
  float ss = v0 * v0 + v1 * v1 + v2 * v2;
  block_reduce2(s, ss, sbuf);
  float mu = s * (1.0f / DD);
  float var = ss * (1.0f / DD) - mu * mu;
  float r = rsqrtf(var + 1e-5f);
  u16* orow = xnb + row * DD;
  orow[t]       = f2bf((v0 - mu) * r * w[t]       + lb[t]);
  orow[t + 256] = f2bf((v1 - mu) * r * w[t + 256] + lb[t + 256]);
  orow[t + 512] = f2bf((v2 - mu) * r * w[t + 512] + lb[t + 512]);
}

// ---------------------------------------------------------------------------
extern "C" void kernel_launch(void* const* d_in, const int* in_sizes, int n_in,
                              void* d_out, int out_size, void* d_ws, size_t ws_size,
                              hipStream_t stream) {
  const float* x      = (const float*)d_in[0];
  const float* edge   = (const float*)d_in[1];
  const int*   bdist  = (const int*)d_in[2];
  const float* W_in   = (const float*)d_in[3];
  const float* b_in   = (const float*)d_in[4];
  const float* pe_emb = (const float*)d_in[5];
  const float* W_out  = (const float*)d_in[6];
  const float* b_out  = (const float*)d_in[7];
  const float* W1     = (const float*)d_in[8];
  const float* b1     = (const float*)d_in[9];
  const float* W2     = (const float*)d_in[10];
  const float* b2     = (const float*)d_in[11];
  const float* ln1w   = (const float*)d_in[12];
  const float* ln1b   = (const float*)d_in[13];
  const float* ln2w   = (const float*)d_in[14];
  const float* ln2b   = (const float*)d_in[15];

  float* xout = (float*)d_out;                 // [L,B,D]
  float* eout = xout + (size_t)LL * BB * DD;   // [B*H,L,L] == final scores

  // Workspace layout (float units) — round-19-proven (vtmp removed).
  float* ws = (float*)d_ws;
  u16*   xnb    = (u16*)(ws + 0);          // [4096,768] bf16
  u16*   tb     = (u16*)(ws + 1600000);    // t' bf16 [96,512,512]
  u16*   olbdb  = (u16*)(ws + 1600000);    // bf16 O (after gather; tb dead)
  u16*   ff1b   = (u16*)(ws + 3200000);    // [4096,3072] bf16 (step 8)
  float* x1     = ws + 11100000;           // (step 7)
  u16*   peemb  = (u16*)(ws + 14300000);   // [128,768] bf16
  u16*   part   = (u16*)(ws + 14600000);   // bf16 split-K partials (7,9)
  u16*   vbT    = (u16*)(ws + 21000000);   // [96,64,512] bf16 transposed V
  float* stats  = ws + 22600000;           // [96,512,16]
  u8*    bdT    = (u8*)(ws + 23400000);    // [8,512,512] u8
  u16*   kpb    = (u16*)(ws + 24000000);   // [96,512,128] bf16
  u16*   qpb    = (u16*)(ws + 27200000);
  u16*   W1b    = (u16*)(ws + 30400000);
  u16*   W2b    = (u16*)(ws + 31600000);
  u16*   W_inb  = (u16*)(ws + 32800000);
  u16*   W_outb = (u16*)(ws + 33700000);
  u16*   qb     = (u16*)(ws + 34000000);
  u16*   kb     = (u16*)(ws + 35600000);
  u16*   peb    = (u16*)(ws + 37200000);   // [128,2304] bf16

  // 1) all prep (LN1 + 5 conversions + bdist transpose) in one launch
  prep_kernel<<<19296, 256, 0, stream>>>(x, ln1w, ln1b, xnb, W_in, W_inb,
                                         W_out, W_outb, W1, W1b, W2, W2b,
                                         pe_emb, peemb, bdist, bdT);
  // 2) qkv + pe_proj GEMM -> qb/kb [B,H,L,Dh], V direct -> vbT, peb
  gemm_mfma_qkv<<<dim3(18, 33), 256, 0, stream>>>(xnb, peemb, W_inb, b_in,
                                                  qb, kb, vbT, peb);
  // 3) merged kp'/qp' + t' (flat 2304-block K=64 batched MFMA)
  attn_k64<<<2304, 256, 0, stream>>>(qb, kb, peb, kpb, qpb, tb);
  // 4) eout = t' + kp' + qp' + edge, + softmax tile stats
  gather_scale2<<<dim3(8, 8, 96), 256, 0, stream>>>(tb, kpb, qpb, bdT, edge,
                                                    eout, stats);
  // 5) MFMA softmax + PV -> olbd bf16 [L,B,D]
  softmax_pv_mfma<<<dim3(8, 96), 256, 0, stream>>>(eout, vbT, stats, olbdb);
  // 6) x1 = O @ W_out^T + b_out + x (split-K=2, bf16 parts)
  gemm_mfma_part<<<dim3(6, 32, 2), 256, 0, stream>>>(
      olbdb, DD, W_outb, DD, part, DD, 3145728L, DD / 2);
  // 7) fused combine + LN2
  combine2_ln<<<4096, 256, 0, stream>>>(part, b_out, x, x1, ln2w, ln2b, xnb);
  // 8) ff1 = gelu(xn @ W1^T + b1) (bf16 out)
  gemm_mfma<1, 1, 0><<<dim3(24, 32), 256, 0, stream>>>(
      xnb, DD, W1b, DD, ff1b, 4 * DD, b1, nullptr, DD);
  // 9) x_out = ff1 @ W2^T + b2 + x1  (split-K=4, bf16 parts + combine)
  gemm_mfma_part<<<dim3(6, 32, 4), 256, 0, stream>>>(
      ff1b, 4 * DD, W2b, 4 * DD, part, DD, 3145728L, DD);
  combine_k<4><<<3072, 256, 0, stream>>>(part, b2, x1, xout);
}

// Round 21
// 292.088 us; speedup vs baseline: 1.9251x; 1.0058x over previous
//
#include <hip/hip_runtime.h>
#include <hip/hip_bf16.h>
#include <math.h>

// Problem constants
#define LL 512
#define BB 8
#define DD 768
#define HH 12
#define DHH 64
#define PP 128

typedef unsigned char u8;
typedef unsigned short u16;
typedef unsigned int u32;
typedef __attribute__((ext_vector_type(8))) short bf16x8;
typedef __attribute__((ext_vector_type(4))) float f32x4;

__device__ __forceinline__ u16 f2bf(float f) {
  u32 u = __float_as_uint(f);
  u32 r = (u + 0x7fffu + ((u >> 16) & 1u)) >> 16;
  return (u16)r;
}
__device__ __forceinline__ float bf2f(u32 u) {
  return __uint_as_float((u & 0xffffu) << 16);
}

#define GLDS(g, l)                                                             \
  __builtin_amdgcn_global_load_lds(                                            \
      (const __attribute__((address_space(1))) void*)(g),                      \
      (__attribute__((address_space(3))) void*)(l), 16, 0, 0)

// ---------------------------------------------------------------------------
__device__ __forceinline__ void block_reduce2(float& a, float& b, float* sbuf) {
#pragma unroll
  for (int off = 32; off > 0; off >>= 1) {
    a += __shfl_down(a, off, 64);
    b += __shfl_down(b, off, 64);
  }
  int wid = threadIdx.x >> 6, lane = threadIdx.x & 63;
  __syncthreads();
  if (lane == 0) { sbuf[wid] = a; sbuf[4 + wid] = b; }
  __syncthreads();
  a = sbuf[0] + sbuf[1] + sbuf[2] + sbuf[3];
  b = sbuf[4] + sbuf[5] + sbuf[6] + sbuf[7];
}

// ---------------------------------------------------------------------------
// Mega-prep: [0,4096) LN1 rows; [4096,11008) weight f2b (4 ranges);
// [11008,11104) pe_emb f2b; [11104,19296) bdist transpose.
__global__ __launch_bounds__(256) void prep_kernel(
    const float* __restrict__ x, const float* __restrict__ ln1w,
    const float* __restrict__ ln1b, u16* __restrict__ xnb,
    const float* __restrict__ W_in, u16* __restrict__ W_inb,
    const float* __restrict__ W_out, u16* __restrict__ W_outb,
    const float* __restrict__ W1, u16* __restrict__ W1b,
    const float* __restrict__ W2, u16* __restrict__ W2b,
    const float* __restrict__ pe_emb, u16* __restrict__ peemb,
    const int* __restrict__ bdist, u8* __restrict__ bdT) {
  int blk = blockIdx.x;
  int t = threadIdx.x;
  if (blk < 4096) {
    __shared__ float sbuf[8];
    const float* xr = x + (size_t)blk * DD;
    float v0 = xr[t], v1 = xr[t + 256], v2 = xr[t + 512];
    float s = v0 + v1 + v2;
    float ss = v0 * v0 + v1 * v1 + v2 * v2;
    block_reduce2(s, ss, sbuf);
    float mu = s * (1.0f / DD);
    float var = ss * (1.0f / DD) - mu * mu;
    float r = rsqrtf(var + 1e-5f);
    u16* orow = xnb + (size_t)blk * DD;
    orow[t]       = f2bf((v0 - mu) * r * ln1w[t]       + ln1b[t]);
    orow[t + 256] = f2bf((v1 - mu) * r * ln1w[t + 256] + ln1b[t + 256]);
    orow[t + 512] = f2bf((v2 - mu) * r * ln1w[t + 512] + ln1b[t + 512]);
  } else if (blk < 11008) {
    int idx = (blk - 4096) * 256 + t;  // 0..1769471
    const float* in;
    u16* out;
    if (idx < 442368) { in = W_in; out = W_inb; }
    else if (idx < 589824) { in = W_out; out = W_outb; idx -= 442368; }
    else if (idx < 1179648) { in = W1; out = W1b; idx -= 589824; }
    else { in = W2; out = W2b; idx -= 1179648; }
    float4 v = *(const float4*)(in + (size_t)idx * 4);
    u32 lo = (u32)f2bf(v.x) | ((u32)f2bf(v.y) << 16);
    u32 hi = (u32)f2bf(v.z) | ((u32)f2bf(v.w) << 16);
    *(uint2*)(out + (size_t)idx * 4) = make_uint2(lo, hi);
  } else if (blk < 11104) {
    int idx = (blk - 11008) * 256 + t;  // 0..24575
    float4 v = *(const float4*)(pe_emb + (size_t)idx * 4);
    u32 lo = (u32)f2bf(v.x) | ((u32)f2bf(v.y) << 16);
    u32 hi = (u32)f2bf(v.z) | ((u32)f2bf(v.w) << 16);
    *(uint2*)(peemb + (size_t)idx * 4) = make_uint2(lo, hi);
  } else {
    int i = (blk - 11104) * 256 + t;  // 0..2097151
    int b = i & 7, jj = (i >> 3) & 511, ii = i >> 12;
    bdT[((size_t)b << 18) + ((size_t)ii << 9) + jj] = (u8)bdist[i];
  }
}

// ---------------------------------------------------------------------------
// bf16 MFMA GEMM (round-3-proven): C = act(A * B^T + bias) [+ residual].
template <int ACT, int OBF, int RES>
__global__ __launch_bounds__(256) void gemm_mfma(
    const u16* __restrict__ A, int lda, const u16* __restrict__ B, int ldb,
    void* __restrict__ Cv, int ldc, const float* __restrict__ bias,
    const float* __restrict__ residual, int K) {
  __shared__ __align__(16) u16 Asl[128 * 32];
  __shared__ __align__(16) u16 Bsl[128 * 32];
  int t = threadIdx.x;
  int m0 = blockIdx.y * 128, n0 = blockIdx.x * 128;
  int lane = t & 63, w = t >> 6;
  int wr = w >> 1, wc = w & 1;
  int lr = lane & 15, lg = lane >> 4;

  f32x4 acc[4][4] = {};

  const u16* Ag0 = A + (size_t)(m0 + (t >> 2)) * lda + (t & 3) * 8;
  const u16* Ag1 = A + (size_t)(m0 + 64 + (t >> 2)) * lda + (t & 3) * 8;
  const u16* Bg0 = B + (size_t)(n0 + (t >> 2)) * ldb + (t & 3) * 8;
  const u16* Bg1 = B + (size_t)(n0 + 64 + (t >> 2)) * ldb + (t & 3) * 8;
  u16* Ad0 = &Asl[t * 8];
  u16* Ad1 = &Asl[2048 + t * 8];
  u16* Bd0 = &Bsl[t * 8];
  u16* Bd1 = &Bsl[2048 + t * 8];

  for (int k0 = 0; k0 < K; k0 += 32) {
    GLDS(Ag0 + k0, Ad0);
    GLDS(Ag1 + k0, Ad1);
    GLDS(Bg0 + k0, Bd0);
    GLDS(Bg1 + k0, Bd1);
    __syncthreads();
    bf16x8 a[4], b[4];
#pragma unroll
    for (int i = 0; i < 4; i++)
      a[i] = *(const bf16x8*)&Asl[(wr * 64 + i * 16 + lr) * 32 + lg * 8];
#pragma unroll
    for (int j = 0; j < 4; j++)
      b[j] = *(const bf16x8*)&Bsl[(wc * 64 + j * 16 + lr) * 32 + lg * 8];
#pragma unroll
    for (int i = 0; i < 4; i++)
#pragma unroll
      for (int j = 0; j < 4; j++)
        asm volatile("v_mfma_f32_16x16x32_bf16 %0, %1, %2, %0"
                     : "+v"(acc[i][j])
                     : "v"(a[i]), "v"(b[j]));
    __syncthreads();
  }
  asm volatile("s_nop 7\n\ts_nop 7" ::);

  float* Cf = (float*)Cv;
  u16* Cb = (u16*)Cv;
#pragma unroll
  for (int i = 0; i < 4; i++) {
#pragma unroll
    for (int r = 0; r < 4; r++) {
      int row = m0 + wr * 64 + i * 16 + lg * 4 + r;
#pragma unroll
      for (int j = 0; j < 4; j++) {
        int col = n0 + wc * 64 + j * 16 + lr;
        float vv = acc[i][j][r];
        if (bias) vv += bias[col];
        if (ACT) vv = 0.5f * vv * (1.0f + erff(vv * 0.70710678118654752f));
        if (RES) vv += residual[(size_t)row * ldc + col];
        if (OBF) Cb[(size_t)row * ldc + col] = f2bf(vv);
        else     Cf[(size_t)row * ldc + col] = vv;
      }
    }
  }
}

// ---------------------------------------------------------------------------
// qkv + pe_proj GEMM (round-20-proven): grid (18, 33).
__global__ __launch_bounds__(256) void gemm_mfma_qkv(
    const u16* __restrict__ xnb, const u16* __restrict__ peemb,
    const u16* __restrict__ B, const float* __restrict__ bias,
    u16* __restrict__ qb, u16* __restrict__ kb, u16* __restrict__ vbT,
    u16* __restrict__ peb) {
  __shared__ __align__(16) u16 Asl[128 * 32];
  __shared__ __align__(16) u16 Bsl[128 * 32];
  const int lda = DD, ldb = DD, K = DD;
  int t = threadIdx.x;
  int isPE = (blockIdx.y == 32);
  const u16* A = isPE ? peemb : xnb;
  int m0 = isPE ? 0 : blockIdx.y * 128;
  int n0 = blockIdx.x * 128;
  int lane = t & 63, w = t >> 6;
  int wr = w >> 1, wc = w & 1;
  int lr = lane & 15, lg = lane >> 4;

  f32x4 acc[4][4] = {};

  const u16* Ag0 = A + (size_t)(m0 + (t >> 2)) * lda + (t & 3) * 8;
  const u16* Ag1 = A + (size_t)(m0 + 64 + (t >> 2)) * lda + (t & 3) * 8;
  const u16* Bg0 = B + (size_t)(n0 + (t >> 2)) * ldb + (t & 3) * 8;
  const u16* Bg1 = B + (size_t)(n0 + 64 + (t >> 2)) * ldb + (t & 3) * 8;
  u16* Ad0 = &Asl[t * 8];
  u16* Ad1 = &Asl[2048 + t * 8];
  u16* Bd0 = &Bsl[t * 8];
  u16* Bd1 = &Bsl[2048 + t * 8];

  for (int k0 = 0; k0 < K; k0 += 32) {
    GLDS(Ag0 + k0, Ad0);
    GLDS(Ag1 + k0, Ad1);
    GLDS(Bg0 + k0, Bd0);
    GLDS(Bg1 + k0, Bd1);
    __syncthreads();
    bf16x8 a[4], b[4];
#pragma unroll
    for (int i = 0; i < 4; i++)
      a[i] = *(const bf16x8*)&Asl[(wr * 64 + i * 16 + lr) * 32 + lg * 8];
#pragma unroll
    for (int j = 0; j < 4; j++)
      b[j] = *(const bf16x8*)&Bsl[(wc * 64 + j * 16 + lr) * 32 + lg * 8];
#pragma unroll
    for (int i = 0; i < 4; i++)
#pragma unroll
      for (int j = 0; j < 4; j++)
        asm volatile("v_mfma_f32_16x16x32_bf16 %0, %1, %2, %0"
                     : "+v"(acc[i][j])
                     : "v"(a[i]), "v"(b[j]));
    __syncthreads();
  }
  asm volatile("s_nop 7\n\ts_nop 7" ::);

#pragma unroll
  for (int i = 0; i < 4; i++) {
#pragma unroll
    for (int r = 0; r < 4; r++) {
      int row = m0 + wr * 64 + i * 16 + lg * 4 + r;
      int l = row >> 3, b = row & 7;
#pragma unroll
      for (int j = 0; j < 4; j++) {
        int col = n0 + wc * 64 + j * 16 + lr;
        u16 vv = f2bf(acc[i][j][r] + bias[col]);
        if (isPE) {
          peb[(size_t)row * (3 * DD) + col] = vv;
        } else {
          int which = col / DD, hd = col - which * DD;
          int h = hd >> 6, d = hd & 63;
          if (which == 0) {
            qb[(((size_t)(b * HH + h)) * LL + l) * DHH + d] = vv;
          } else if (which == 1) {
            kb[(((size_t)(b * HH + h)) * LL + l) * DHH + d] = vv;
          } else {
            vbT[(((size_t)(b * HH + h)) * DHH + d) * LL + l] = vv;
          }
        }
      }
    }
  }
}

// ---------------------------------------------------------------------------
// Merged K=64 batched MFMA (round-16-proven): flat grid 2304 blocks.
__global__ __launch_bounds__(256) void attn_k64(
    const u16* __restrict__ qb, const u16* __restrict__ kb,
    const u16* __restrict__ peb, u16* __restrict__ kpb,
    u16* __restrict__ qpb, u16* __restrict__ tb) {
  __shared__ __align__(16) u16 Asl[128 * 32];
  __shared__ __align__(16) u16 Bsl[128 * 32];
  int id = blockIdx.x;
  const u16 *A, *B;
  u16* Cb;
  int lda, ldb, ldc, m0, n0;
  if (id < 768) {
    int my = id & 3, z = id >> 2;
    int sel = z / 96, zz = z - sel * 96;
    A = (sel ? qb : kb) + (size_t)zz * (LL * DHH);
    B = peb + sel * DD + (size_t)(zz % HH) * 64;
    Cb = (sel ? qpb : kpb) + (size_t)zz * (LL * PP);
    lda = DHH; ldb = 3 * DD; ldc = PP; m0 = my * 128; n0 = 0;
  } else {
    int id2 = id - 768;
    int jx = id2 & 3, my = (id2 >> 2) & 3, bh = id2 >> 4;
    A = qb + (size_t)bh * (LL * DHH);
    B = kb + (size_t)bh * (LL * DHH);
    Cb = tb + (size_t)bh * (LL * LL);
    lda = DHH; ldb = DHH; ldc = LL; m0 = my * 128; n0 = jx * 128;
  }
  int t = threadIdx.x;
  int lane = t & 63, w = t >> 6;
  int wr = w >> 1, wc = w & 1;
  int lr = lane & 15, lg = lane >> 4;

  f32x4 acc[4][4] = {};

  const u16* Ag0 = A + (size_t)(m0 + (t >> 2)) * lda + (t & 3) * 8;
  const u16* Ag1 = A + (size_t)(m0 + 64 + (t >> 2)) * lda + (t & 3) * 8;
  const u16* Bg0 = B + (size_t)(n0 + (t >> 2)) * ldb + (t & 3) * 8;
  const u16* Bg1 = B + (size_t)(n0 + 64 + (t >> 2)) * ldb + (t & 3) * 8;
  u16* Ad0 = &Asl[t * 8];
  u16* Ad1 = &Asl[2048 + t * 8];
  u16* Bd0 = &Bsl[t * 8];
  u16* Bd1 = &Bsl[2048 + t * 8];

  for (int k0 = 0; k0 < DHH; k0 += 32) {
    GLDS(Ag0 + k0, Ad0);
    GLDS(Ag1 + k0, Ad1);
    GLDS(Bg0 + k0, Bd0);
    GLDS(Bg1 + k0, Bd1);
    __syncthreads();
    bf16x8 a[4], b[4];
#pragma unroll
    for (int i = 0; i < 4; i++)
      a[i] = *(const bf16x8*)&Asl[(wr * 64 + i * 16 + lr) * 32 + lg * 8];
#pragma unroll
    for (int j = 0; j < 4; j++)
      b[j] = *(const bf16x8*)&Bsl[(wc * 64 + j * 16 + lr) * 32 + lg * 8];
#pragma unroll
    for (int i = 0; i < 4; i++)
#pragma unroll
      for (int j = 0; j < 4; j++)
        asm volatile("v_mfma_f32_16x16x32_bf16 %0, %1, %2, %0"
                     : "+v"(acc[i][j])
                     : "v"(a[i]), "v"(b[j]));
    __syncthreads();
  }
  asm volatile("s_nop 7\n\ts_nop 7" ::);

#pragma unroll
  for (int i = 0; i < 4; i++) {
#pragma unroll
    for (int r = 0; r < 4; r++) {
      int row = m0 + wr * 64 + i * 16 + lg * 4 + r;
#pragma unroll
      for (int j = 0; j < 4; j++) {
        int col = n0 + wc * 64 + j * 16 + lr;
        Cb[(size_t)row * ldc + col] = f2bf(acc[i][j][r] * 0.125f);
      }
    }
  }
}

// ---------------------------------------------------------------------------
// Streaming gather v3: one block per (bh, 64-row i-tile); loops 8 j-tiles.
// Per-tile score/gather/eout code byte-identical to round-16-proven
// gather_scale2; qpl staged ONCE; running (m,s) kept in registers (each
// thread owns rows ty*4+i2 for all j-tiles). Final stats: [row][2] = {m, 1/s}.
__global__ __launch_bounds__(256) void gather_scale3(
    const u16* __restrict__ tb,
    const u16* __restrict__ kp, const u16* __restrict__ qp,
    const u8* __restrict__ bdT, const float* __restrict__ edge,
    float* __restrict__ eout, float* __restrict__ stats) {
  int bh = blockIdx.y, b = bh / HH;
  int i0 = blockIdx.x * 64;
  __shared__ __align__(16) u16 kpl[64][PP];
  __shared__ __align__(16) u16 qpl[64][PP];
  int tid = threadIdx.x;
  int tx = tid & 15, ty = tid >> 4;

  const u16* kpg = kp + (size_t)bh * (LL * PP);
  const u16* qpg = qp + (size_t)bh * (LL * PP);
  u16* kflat = &kpl[0][0];
  u16* qflat = &qpl[0][0];
#pragma unroll
  for (int it = 0; it < 4; it++) {
    int c = tid + it * 256;
    int row = c >> 4, ch = (c & 15) * 8;
    GLDS(&qpg[(size_t)(i0 + row) * PP + ch], &qflat[c * 8]);
    GLDS(&kpg[(size_t)row * PP + ch], &kflat[c * 8]);
  }
  __syncthreads();

  const u8* bd = bdT + (size_t)b * (LL * LL);
  const float* eb = edge + (size_t)bh * (LL * LL);
  const u16* tbb = tb + (size_t)bh * (LL * LL);
  float* ob = eout + (size_t)bh * (LL * LL);

  float runm[4], runs[4];
#pragma unroll
  for (int i2 = 0; i2 < 4; i2++) { runm[i2] = -3e38f; runs[i2] = 0.f; }

  for (int jt = 0; jt < 8; jt++) {
    int j0 = jt * 64;
#pragma unroll
    for (int i2 = 0; i2 < 4; i2++) {
      int row = i0 + ty * 4 + i2;
      int col0 = j0 + tx * 4;
      uchar4 p4 = *(const uchar4*)&bd[(size_t)row * LL + col0];
      float4 e4 = *(const float4*)&eb[(size_t)row * LL + col0];
      uint2 t2 = *(const uint2*)&tbb[(size_t)row * LL + col0];
      float tv[4] = {bf2f(t2.x), bf2f(t2.x >> 16), bf2f(t2.y),
                     bf2f(t2.y >> 16)};
      int pp[4] = {p4.x, p4.y, p4.z, p4.w};
      float ee[4] = {e4.x, e4.y, e4.z, e4.w};
      float sv[4];
#pragma unroll
      for (int j2 = 0; j2 < 4; j2++) {
        float gk = bf2f((u32)kpl[tx * 4 + j2][pp[j2]]);
        float gq = bf2f((u32)qpl[ty * 4 + i2][pp[j2]]);
        sv[j2] = tv[j2] + gk + gq + ee[j2];
      }
      *(float4*)&ob[(size_t)row * LL + col0] =
          make_float4(sv[0], sv[1], sv[2], sv[3]);
      float m = fmaxf(fmaxf(sv[0], sv[1]), fmaxf(sv[2], sv[3]));
#pragma unroll
      for (int off = 1; off < 16; off <<= 1)
        m = fmaxf(m, __shfl_xor(m, off, 64));
      float ss = __expf(sv[0] - m) + __expf(sv[1] - m) + __expf(sv[2] - m) +
                 __expf(sv[3] - m);
#pragma unroll
      for (int off = 1; off < 16; off <<= 1) ss += __shfl_xor(ss, off, 64);
      // fold into running stats (identical associativity to old 8-way combine)
      float mn = fmaxf(runm[i2], m);
      runs[i2] = runs[i2] * __expf(runm[i2] - mn) + ss * __expf(m - mn);
      runm[i2] = mn;
    }
    if (jt < 7) {
      __syncthreads();  // all kpl reads for this j-tile done
#pragma unroll
      for (int it = 0; it < 4; it++) {
        int c = tid + it * 256;
        int row = c >> 4, ch = (c & 15) * 8;
        GLDS(&kpg[(size_t)((jt + 1) * 64 + row) * PP + ch], &kflat[c * 8]);
      }
      __syncthreads();  // vmcnt(0) drained before barrier -> writes visible
    }
  }
  if (tx == 0) {
#pragma unroll
    for (int i2 = 0; i2 < 4; i2++) {
      size_t si = ((size_t)bh * LL + i0 + ty * 4 + i2) * 2;
      stats[si] = runm[i2];
      stats[si + 1] = 1.0f / runs[i2];
    }
  }
}

// ---------------------------------------------------------------------------
// MFMA softmax+PV (round-14-proven core; stats now direct {m, 1/s}).
__global__ __launch_bounds__(256) void softmax_pv_mfma(
    const float* __restrict__ scores, const u16* __restrict__ vbT,
    const float* __restrict__ stats, u16* __restrict__ olbd) {
  int bh = blockIdx.y;
  int i0 = blockIdx.x * 64;
  int b = bh / HH, h = bh - b * HH;
  __shared__ __align__(16) u16 PL[2][64 * 32];
  __shared__ __align__(16) u16 VL[2][64 * 32];
  __shared__ float smax[64], srs[64];
  int tid = threadIdx.x;
  int tx = tid & 15, ty = tid >> 4;
  int lane = tid & 63, w = tid >> 6;
  int wr = w >> 1, wc = w & 1;
  int lr = lane & 15, lg = lane >> 4;
  const float* sbase = scores + (size_t)bh * (LL * LL);
  const u16* vt = vbT + (size_t)bh * (DHH * LL);

  if (tid < 64) {
    size_t si = ((size_t)bh * LL + i0 + tid) * 2;
    smax[tid] = stats[si];
    srs[tid] = stats[si + 1];
  }
  __syncthreads();

  f32x4 acc[2][2] = {};
  int ks = tx >> 3, kk = (tx & 7) * 4;
  int vd = tid >> 2, vjo = (tid & 3) * 8;

  for (int jt = 0; jt < 8; jt++) {
    int j0 = jt * 64;
    GLDS(vt + (size_t)vd * LL + j0 + vjo, &VL[0][tid * 8]);
    GLDS(vt + (size_t)vd * LL + j0 + 32 + vjo, &VL[1][tid * 8]);
#pragma unroll
    for (int rr = 0; rr < 4; rr++) {
      int r = ty + rr * 16;
      float4 s4 = *(const float4*)(sbase + (size_t)(i0 + r) * LL + j0 + tx * 4);
      float m = smax[r], rs = srs[r];
      u16 p0 = f2bf(__expf(s4.x - m) * rs);
      u16 p1 = f2bf(__expf(s4.y - m) * rs);
      u16 p2 = f2bf(__expf(s4.z - m) * rs);
      u16 p3 = f2bf(__expf(s4.w - m) * rs);
      *(uint2*)&PL[ks][r * 32 + kk] =
          make_uint2((u32)p0 | ((u32)p1 << 16), (u32)p2 | ((u32)p3 << 16));
    }
    __syncthreads();
#pragma unroll
    for (int s2 = 0; s2 < 2; s2++) {
      bf16x8 a[2], bfr[2];
#pragma unroll
      for (int i = 0; i < 2; i++)
        a[i] = *(const bf16x8*)&PL[s2][(wr * 32 + i * 16 + lr) * 32 + lg * 8];
#pragma unroll
      for (int j = 0; j < 2; j++)
        bfr[j] = *(const bf16x8*)&VL[s2][(wc * 32 + j * 16 + lr) * 32 + lg * 8];
#pragma unroll
      for (int i = 0; i < 2; i++)
#pragma unroll
        for (int j = 0; j < 2; j++)
          asm volatile("v_mfma_f32_16x16x32_bf16 %0, %1, %2, %0"
                       : "+v"(acc[i][j])
                       : "v"(a[i]), "v"(bfr[j]));
    }
    __syncthreads();
  }
  asm volatile("s_nop 7\n\ts_nop 7" ::);

#pragma unroll
  for (int i = 0; i < 2; i++) {
#pragma unroll
    for (int r = 0; r < 4; r++) {
      int irow = i0 + wr * 32 + i * 16 + lg * 4 + r;
#pragma unroll
      for (int j = 0; j < 2; j++) {
        int d = wc * 32 + j * 16 + lr;
        olbd[((size_t)irow * BB + b) * DD + h * 64 + d] = f2bf(acc[i][j][r]);
      }
    }
  }
}

// ---------------------------------------------------------------------------
// Split-K partial MFMA GEMM — bf16 partial output (round-19-proven).
__global__ __launch_bounds__(256) void gemm_mfma_part(
    const u16* __restrict__ A, int lda, const u16* __restrict__ B, int ldb,
    u16* __restrict__ Cb, int ldc, long partStride, int Kper) {
  __shared__ __align__(16) u16 Asl[128 * 32];
  __shared__ __align__(16) u16 Bsl[128 * 32];
  int z = blockIdx.z;
  A += (size_t)z * Kper;
  B += (size_t)z * Kper;
  Cb += (size_t)z * partStride;
  int t = threadIdx.x;
  int m0 = blockIdx.y * 128, n0 = blockIdx.x * 128;
  int lane = t & 63, w = t >> 6;
  int wr = w >> 1, wc = w & 1;
  int lr = lane & 15, lg = lane >> 4;

  f32x4 acc[4][4] = {};

  const u16* Ag0 = A + (size_t)(m0 + (t >> 2)) * lda + (t & 3) * 8;
  const u16* Ag1 = A + (size_t)(m0 + 64 + (t >> 2)) * lda + (t & 3) * 8;
  const u16* Bg0 = B + (size_t)(n0 + (t >> 2)) * ldb + (t & 3) * 8;
  const u16* Bg1 = B + (size_t)(n0 + 64 + (t >> 2)) * ldb + (t & 3) * 8;
  u16* Ad0 = &Asl[t * 8];
  u16* Ad1 = &Asl[2048 + t * 8];
  u16* Bd0 = &Bsl[t * 8];
  u16* Bd1 = &Bsl[2048 + t * 8];

  for (int k0 = 0; k0 < Kper; k0 += 32) {
    GLDS(Ag0 + k0, Ad0);
    GLDS(Ag1 + k0, Ad1);
    GLDS(Bg0 + k0, Bd0);
    GLDS(Bg1 + k0, Bd1);
    __syncthreads();
    bf16x8 a[4], b[4];
#pragma unroll
    for (int i = 0; i < 4; i++)
      a[i] = *(const bf16x8*)&Asl[(wr * 64 + i * 16 + lr) * 32 + lg * 8];
#pragma unroll
    for (int j = 0; j < 4; j++)
      b[j] = *(const bf16x8*)&Bsl[(wc * 64 + j * 16 + lr) * 32 + lg * 8];
#pragma unroll
    for (int i = 0; i < 4; i++)
#pragma unroll
      for (int j = 0; j < 4; j++)
        asm volatile("v_mfma_f32_16x16x32_bf16 %0, %1, %2, %0"
                     : "+v"(acc[i][j])
                     : "v"(a[i]), "v"(b[j]));
    __syncthreads();
  }
  asm volatile("s_nop 7\n\ts_nop 7" ::);

#pragma unroll
  for (int i = 0; i < 4; i++) {
#pragma unroll
    for (int r = 0; r < 4; r++) {
      int row = m0 + wr * 64 + i * 16 + lg * 4 + r;
#pragma unroll
      for (int j = 0; j < 4; j++) {
        int col = n0 + wc * 64 + j * 16 + lr;
        Cb[(size_t)row * ldc + col] = f2bf(acc[i][j][r]);
      }
    }
  }
}

// Combine NS bf16 split-K partials: out = sum(parts) + bias + res.
template <int NS>
__global__ __launch_bounds__(256) void combine_k(const u16* __restrict__ p,
                                                 const float* __restrict__ bias,
                                                 const float* __restrict__ res,
                                                 float* __restrict__ out) {
  int idx = blockIdx.x * 256 + threadIdx.x;  // over 786,432
  size_t e = (size_t)idx * 4;
  uint2 pv = *(const uint2*)(p + e);
  float s0 = bf2f(pv.x), s1 = bf2f(pv.x >> 16);
  float s2 = bf2f(pv.y), s3 = bf2f(pv.y >> 16);
#pragma unroll
  for (int z = 1; z < NS; z++) {
    uint2 t2 = *(const uint2*)(p + (size_t)z * 3145728 + e);
    s0 += bf2f(t2.x); s1 += bf2f(t2.x >> 16);
    s2 += bf2f(t2.y); s3 += bf2f(t2.y >> 16);
  }
  int col = (int)(e % DD);
  float4 b4 = *(const float4*)(bias + col);
  float4 r4 = *(const float4*)(res + e);
  *(float4*)(out + e) = make_float4(s0 + b4.x + r4.x, s1 + b4.y + r4.y,
                                    s2 + b4.z + r4.z, s3 + b4.w + r4.w);
}

// Fused combine2 (bf16 partials) + LayerNorm (round-19-proven).
__global__ __launch_bounds__(256) void combine2_ln(
    const u16* __restrict__ p, const float* __restrict__ bias,
    const float* __restrict__ res, float* __restrict__ x1,
    const float* __restrict__ w, const float* __restrict__ lb,
    u16* __restrict__ xnb) {
  __shared__ float sbuf[8];
  size_t row = blockIdx.x;
  int t = threadIdx.x;
  const u16* p0 = p + row * DD;
  const u16* p1 = p + 3145728 + row * DD;
  const float* rr = res + row * DD;
  float v0 = bf2f((u32)p0[t])       + bf2f((u32)p1[t])       + bias[t]       + rr[t];
  float v1 = bf2f((u32)p0[t + 256]) + bf2f((u32)p1[t + 256]) + bias[t + 256] + rr[t + 256];
  float v2 = bf2f((u32)p0[t + 512]) + bf2f((u32)p1[t + 512]) + bias[t + 512] + rr[t + 512];
  float* xr = x1 + row * DD;
  xr[t] = v0; xr[t + 256] = v1; xr[t + 512] = v2;
  float s = v0 + v1 + v2;
  float ss = v0 * v0 + v1 * v1 + v2 * v2;
  block_reduce2(s, ss, sbuf);
  float mu = s * (1.0f / DD);
  float var = ss * (1.0f / DD) - mu * mu;
  float r = rsqrtf(var + 1e-5f);
  u16* orow = xnb + row * DD;
  orow[t]       = f2bf((v0 - mu) * r * w[t]       + lb[t]);
  orow[t + 256] = f2bf((v1 - mu) * r * w[t + 256] + lb[t + 256]);
  orow[t + 512] = f2bf((v2 - mu) * r * w[t + 512] + lb[t + 512]);
}

// ---------------------------------------------------------------------------
extern "C" void kernel_launch(void* const* d_in, const int* in_sizes, int n_in,
                              void* d_out, int out_size, void* d_ws, size_t ws_size,
                              hipStream_t stream) {
  const float* x      = (const float*)d_in[0];
  const float* edge   = (const float*)d_in[1];
  const int*   bdist  = (const int*)d_in[2];
  const float* W_in   = (const float*)d_in[3];
  const float* b_in   = (const float*)d_in[4];
  const float* pe_emb = (const float*)d_in[5];
  const float* W_out  = (const float*)d_in[6];
  const float* b_out  = (const float*)d_in[7];
  const float* W1     = (const float*)d_in[8];
  const float* b1     = (const float*)d_in[9];
  const float* W2     = (const float*)d_in[10];
  const float* b2     = (const float*)d_in[11];
  const float* ln1w   = (const float*)d_in[12];
  const float* ln1b   = (const float*)d_in[13];
  const float* ln2w   = (const float*)d_in[14];
  const float* ln2b   = (const float*)d_in[15];

  float* xout = (float*)d_out;                 // [L,B,D]
  float* eout = xout + (size_t)LL * BB * DD;   // [B*H,L,L] == final scores

  // Workspace layout (float units) — round-20-proven (stats now [.,512,2]).
  float* ws = (float*)d_ws;
  u16*   xnb    = (u16*)(ws + 0);          // [4096,768] bf16
  u16*   tb     = (u16*)(ws + 1600000);    // t' bf16 [96,512,512]
  u16*   olbdb  = (u16*)(ws + 1600000);    // bf16 O (after gather; tb dead)
  u16*   ff1b   = (u16*)(ws + 3200000);    // [4096,3072] bf16 (step 8)
  float* x1     = ws + 11100000;           // (step 7)
  u16*   peemb  = (u16*)(ws + 14300000);   // [128,768] bf16
  u16*   part   = (u16*)(ws + 14600000);   // bf16 split-K partials (6,9)
  u16*   vbT    = (u16*)(ws + 21000000);   // [96,64,512] bf16 transposed V
  float* stats  = ws + 22600000;           // [96,512,2]
  u8*    bdT    = (u8*)(ws + 23400000);    // [8,512,512] u8
  u16*   kpb    = (u16*)(ws + 24000000);   // [96,512,128] bf16
  u16*   qpb    = (u16*)(ws + 27200000);
  u16*   W1b    = (u16*)(ws + 30400000);
  u16*   W2b    = (u16*)(ws + 31600000);
  u16*   W_inb  = (u16*)(ws + 32800000);
  u16*   W_outb = (u16*)(ws + 33700000);
  u16*   qb     = (u16*)(ws + 34000000);
  u16*   kb     = (u16*)(ws + 35600000);
  u16*   peb    = (u16*)(ws + 37200000);   // [128,2304] bf16

  // 1) all prep (LN1 + 5 conversions + bdist transpose) in one launch
  prep_kernel<<<19296, 256, 0, stream>>>(x, ln1w, ln1b, xnb, W_in, W_inb,
                                         W_out, W_outb, W1, W1b, W2, W2b,
                                         pe_emb, peemb, bdist, bdT);
  // 2) qkv + pe_proj GEMM -> qb/kb [B,H,L,Dh], V direct -> vbT, peb
  gemm_mfma_qkv<<<dim3(18, 33), 256, 0, stream>>>(xnb, peemb, W_inb, b_in,
                                                  qb, kb, vbT, peb);
  // 3) merged kp'/qp' + t' (flat 2304-block K=64 batched MFMA)
  attn_k64<<<2304, 256, 0, stream>>>(qb, kb, peb, kpb, qpb, tb);
  // 4) eout = t' + kp' + qp' + edge, + running softmax stats (per i-row block)
  gather_scale3<<<dim3(8, 96), 256, 0, stream>>>(tb, kpb, qpb, bdT, edge,
                                                 eout, stats);
  // 5) MFMA softmax + PV -> olbd bf16 [L,B,D]
  softmax_pv_mfma<<<dim3(8, 96), 256, 0, stream>>>(eout, vbT, stats, olbdb);
  // 6) x1 = O @ W_out^T + b_out + x (split-K=2, bf16 parts)
  gemm_mfma_part<<<dim3(6, 32, 2), 256, 0, stream>>>(
      olbdb, DD, W_outb, DD, part, DD, 3145728L, DD / 2);
  // 7) fused combine + LN2
  combine2_ln<<<4096, 256, 0, stream>>>(part, b_out, x, x1, ln2w, ln2b, xnb);
  // 8) ff1 = gelu(xn @ W1^T + b1) (bf16 out)
  gemm_mfma<1, 1, 0><<<dim3(24, 32), 256, 0, stream>>>(
      xnb, DD, W1b, DD, ff1b, 4 * DD, b1, nullptr, DD);
  // 9) x_out = ff1 @ W2^T + b2 + x1  (split-K=4, bf16 parts + combine)
  gemm_mfma_part<<<dim3(6, 32, 4), 256, 0, stream>>>(
      ff1b, 4 * DD, W2b, 4 * DD, part, DD, 3145728L, DD);
  combine_k<4><<<3072, 256, 0, stream>>>(part, b2, x1, xout);
}